// Round 2
// baseline (7728.342 us; speedup 1.0000x reference)
//
#include <hip/hip_runtime.h>
#include <math.h>

namespace {

constexpr int Bq   = 4;
constexpr int N0   = 6000;
constexpr int KIN  = 1024;
constexpr int E    = 512;
constexpr int HH   = 78;
constexpr int HWp  = 6084;        // 78*78
constexpr int N1   = 6085;        // 1 + HWp
constexpr int NH   = 8;
constexpr int DH   = 64;
constexpr int LM   = 256;         // landmarks
constexpr int NP   = 6144;        // padded seq
constexpr int LCH  = 24;          // chunk len per landmark
constexpr int PADS = 59;          // front zero-pad
constexpr int BH   = Bq * NH;     // 32
constexpr int QKV  = 3 * E;       // 1536
constexpr int CH   = 4;           // head-chunk for a3/a1 streaming
constexpr int NSPLIT = 8;         // K-split for PV gemm

// per-bh strides
constexpr long long sLD = (long long)LM * DH;   // 16384
constexpr long long sND = (long long)NP * DH;   // 393216
constexpr long long sMM = (long long)LM * LM;   // 65536

__host__ __device__ inline int gblocks_i(long long n) { return (int)((n + 255) / 256); }

// ---------------------------------------------------------------------------
// gemm128: C[M,N] = A[M,K] @ B[K,N], 128x128 tile, 256 thr, 8x8 micro, BK=16.
// Flags: BIAS, RELU, ACCUM(+=), SCATTER(qkv->q/k/v padded per-head),
// SHIFT(fc1: row r -> b*N1+1+rr), GATHER(A from heads layout), LNA(LN on A).
// N mult of 128, K mult of 16; M guarded.
// ---------------------------------------------------------------------------
template<bool BIAS, bool RELU, bool ACCUM, bool SCATTER, bool SHIFT, bool GATHER, bool LNA>
__global__ __launch_bounds__(256)
void gemm128(const float* __restrict__ A, const float* __restrict__ Bw,
             const float* __restrict__ bias, float* __restrict__ C,
             float* __restrict__ qp, float* __restrict__ kp, float* __restrict__ vp,
             const float* __restrict__ Ag, const float* __restrict__ lng,
             const float* __restrict__ lnb, const float* __restrict__ stats,
             int Mrows, int N, int K)
{
  __shared__ float As[16][132];
  __shared__ float Bs[16][132];
  const int tid = threadIdx.x;
  const int tx = tid & 15, ty = tid >> 4;
  const int rowBase = blockIdx.y * 128;
  const int colBase = blockIdx.x * 128;
  float acc[8][8];
  #pragma unroll
  for (int i = 0; i < 8; i++)
    #pragma unroll
    for (int j = 0; j < 8; j++) acc[i][j] = 0.f;

  const int arow = tid >> 2;          // 0..63
  const int acol = (tid & 3) << 2;    // 0,4,8,12
  const int brow = tid >> 5;          // 0..7
  const int bcol = (tid & 31) << 2;   // 0..124

  for (int k0 = 0; k0 < K; k0 += 16) {
    #pragma unroll
    for (int i = 0; i < 2; i++) {
      const int r = rowBase + arow + i * 64;
      float4 va = make_float4(0.f, 0.f, 0.f, 0.f);
      if (r < Mrows) {
        const int kk0 = k0 + acol;
        if (GATHER) {
          const int b = r / N1, rr = r % N1;
          va = *reinterpret_cast<const float4*>(
              Ag + (((size_t)(b * NH + (kk0 >> 6))) * NP + PADS + rr) * DH + (kk0 & 63));
        } else if (LNA) {
          float4 hx = *reinterpret_cast<const float4*>(A + (size_t)r * K + kk0);
          const float mu = stats[2 * r], inv = stats[2 * r + 1];
          float4 gg = *reinterpret_cast<const float4*>(lng + kk0);
          float4 bb = *reinterpret_cast<const float4*>(lnb + kk0);
          va.x = (hx.x - mu) * inv * gg.x + bb.x;
          va.y = (hx.y - mu) * inv * gg.y + bb.y;
          va.z = (hx.z - mu) * inv * gg.z + bb.z;
          va.w = (hx.w - mu) * inv * gg.w + bb.w;
        } else {
          va = *reinterpret_cast<const float4*>(A + (size_t)r * K + kk0);
        }
      }
      As[acol + 0][arow + i * 64] = va.x;
      As[acol + 1][arow + i * 64] = va.y;
      As[acol + 2][arow + i * 64] = va.z;
      As[acol + 3][arow + i * 64] = va.w;
    }
    #pragma unroll
    for (int i = 0; i < 2; i++) {
      const int kr = brow + i * 8;
      *reinterpret_cast<float4*>(&Bs[kr][bcol]) =
          *reinterpret_cast<const float4*>(Bw + (size_t)(k0 + kr) * N + (colBase + bcol));
    }
    __syncthreads();
    #pragma unroll
    for (int kk = 0; kk < 16; kk++) {
      float a[8], b[8];
      *reinterpret_cast<float4*>(&a[0]) = *reinterpret_cast<const float4*>(&As[kk][ty * 8]);
      *reinterpret_cast<float4*>(&a[4]) = *reinterpret_cast<const float4*>(&As[kk][ty * 8 + 4]);
      *reinterpret_cast<float4*>(&b[0]) = *reinterpret_cast<const float4*>(&Bs[kk][tx * 8]);
      *reinterpret_cast<float4*>(&b[4]) = *reinterpret_cast<const float4*>(&Bs[kk][tx * 8 + 4]);
      #pragma unroll
      for (int i = 0; i < 8; i++)
        #pragma unroll
        for (int j = 0; j < 8; j++)
          acc[i][j] = fmaf(a[i], b[j], acc[i][j]);
    }
    __syncthreads();
  }

  #pragma unroll
  for (int i = 0; i < 8; i++) {
    const int r = rowBase + ty * 8 + i;
    if (r >= Mrows) continue;
    #pragma unroll
    for (int j = 0; j < 8; j++) {
      const int c = colBase + tx * 8 + j;
      float v = acc[i][j];
      if (BIAS) v += bias[c];
      if (RELU) v = fmaxf(v, 0.f);
      if (SCATTER) {
        const int b   = r / N1;
        const int p   = (r % N1) + PADS;
        const int wch = c >> 9;
        const int hd  = (c >> 6) & 7;
        const int d   = c & 63;
        if (wch == 0) v *= 0.125f;  // q * DH^-0.5
        float* dst = (wch == 0) ? qp : (wch == 1) ? kp : vp;
        dst[(((size_t)(b * NH + hd)) * NP + p) * DH + d] = v;
      } else if (SHIFT) {
        C[((size_t)(r / N0) * N1 + 1 + (r % N0)) * N + c] = v;
      } else if (ACCUM) {
        C[(size_t)r * N + c] += v;
      } else {
        C[(size_t)r * N + c] = v;
      }
    }
  }
}

// ---------------------------------------------------------------------------
// bgemm64: batched C = alpha * A @ Beff, 64x64 tile, 4x4 micro, BK=16.
// TRANSB: B as [N][K]. DIAG: Beff = c0*I - B. NS: K-split, one C slab per
// (batch,split). M,N mult of 64; K/NS mult of 16. grid (N/64, M/64, batch*NS)
// ---------------------------------------------------------------------------
template<bool TRANSB, bool DIAG>
__global__ __launch_bounds__(256)
void bgemm64(const float* __restrict__ A, const float* __restrict__ Bw,
             float* __restrict__ C, int N, int K,
             long long sA, long long sB, long long sC,
             int NS, float alpha, float c0)
{
  const int batch = blockIdx.z / NS;
  const int split = blockIdx.z % NS;
  const int Ks = K / NS;
  const int kbeg = split * Ks;
  const float* Ab = A + (size_t)batch * sA;
  const float* Bb = Bw + (size_t)batch * sB;
  float* Cb = C + (size_t)blockIdx.z * sC;

  __shared__ float As[16][68];
  __shared__ float Bs[16][68];
  const int tid = threadIdx.x;
  const int tx = tid & 15, ty = tid >> 4;
  const int rowBase = blockIdx.y * 64;
  const int colBase = blockIdx.x * 64;
  const int lrow = tid >> 2;
  const int lcol = (tid & 3) << 2;

  float acc[4][4];
  #pragma unroll
  for (int i = 0; i < 4; i++)
    #pragma unroll
    for (int j = 0; j < 4; j++) acc[i][j] = 0.f;

  for (int kb = kbeg; kb < kbeg + Ks; kb += 16) {
    {
      float4 va = *reinterpret_cast<const float4*>(Ab + (size_t)(rowBase + lrow) * K + kb + lcol);
      As[lcol + 0][lrow] = va.x;
      As[lcol + 1][lrow] = va.y;
      As[lcol + 2][lrow] = va.z;
      As[lcol + 3][lrow] = va.w;
    }
    if (TRANSB) {
      float4 vb = *reinterpret_cast<const float4*>(Bb + (size_t)(colBase + lrow) * K + kb + lcol);
      Bs[lcol + 0][lrow] = vb.x;
      Bs[lcol + 1][lrow] = vb.y;
      Bs[lcol + 2][lrow] = vb.z;
      Bs[lcol + 3][lrow] = vb.w;
    } else {
      const int kr = tid >> 4;
      const int bc = (tid & 15) << 2;
      float4 vb = *reinterpret_cast<const float4*>(Bb + (size_t)(kb + kr) * N + colBase + bc);
      if (DIAG) {
        const int gk = kb + kr;
        const int gn = colBase + bc;
        vb.x = ((gk == gn + 0) ? c0 : 0.f) - vb.x;
        vb.y = ((gk == gn + 1) ? c0 : 0.f) - vb.y;
        vb.z = ((gk == gn + 2) ? c0 : 0.f) - vb.z;
        vb.w = ((gk == gn + 3) ? c0 : 0.f) - vb.w;
      }
      *reinterpret_cast<float4*>(&Bs[kr][bc]) = vb;
    }
    __syncthreads();
    #pragma unroll
    for (int kk = 0; kk < 16; kk++) {
      float a[4], b[4];
      *reinterpret_cast<float4*>(&a[0]) = *reinterpret_cast<const float4*>(&As[kk][ty * 4]);
      *reinterpret_cast<float4*>(&b[0]) = *reinterpret_cast<const float4*>(&Bs[kk][tx * 4]);
      #pragma unroll
      for (int i = 0; i < 4; i++)
        #pragma unroll
        for (int j = 0; j < 4; j++)
          acc[i][j] = fmaf(a[i], b[j], acc[i][j]);
    }
    __syncthreads();
  }

  #pragma unroll
  for (int i = 0; i < 4; i++)
    #pragma unroll
    for (int j = 0; j < 4; j++)
      Cb[(size_t)(rowBase + ty * 4 + i) * N + colBase + tx * 4 + j] = alpha * acc[i][j];
}

// ---------------------------------------------------------------------------
__global__ __launch_bounds__(256)
void ln_stats(const float* __restrict__ X, float* __restrict__ stats)
{
  const size_t row = blockIdx.x;
  const float* x = X + row * E;
  const int tid = threadIdx.x;
  float2 v = *reinterpret_cast<const float2*>(x + tid * 2);
  __shared__ float red[256];
  red[tid] = v.x + v.y;
  __syncthreads();
  for (int s = 128; s > 0; s >>= 1) { if (tid < s) red[tid] += red[tid + s]; __syncthreads(); }
  const float mu = red[0] * (1.f / E);
  __syncthreads();
  const float dx = v.x - mu, dy = v.y - mu;
  red[tid] = dx * dx + dy * dy;
  __syncthreads();
  for (int s = 128; s > 0; s >>= 1) { if (tid < s) red[tid] += red[tid + s]; __syncthreads(); }
  if (tid == 0) {
    stats[2 * row]     = mu;
    stats[2 * row + 1] = 1.f / sqrtf(red[0] * (1.f / E) + 1e-5f);
  }
}

__global__ void fill_cls_wrap(const float* __restrict__ cls, float* __restrict__ h)
{
  int idx = blockIdx.x * 256 + threadIdx.x;
  const int total = Bq * 85 * (E / 4);
  if (idx >= total) return;
  const int e4 = idx % (E / 4);
  int t = idx / (E / 4);
  const int rr = t % 85;
  const int b = t / 85;
  float4* H = reinterpret_cast<float4*>(h);
  if (rr == 0) {
    H[((size_t)b * N1) * (E / 4) + e4] = reinterpret_cast<const float4*>(cls)[e4];
  } else {
    const int i = rr - 1;  // wrap rows: dest 1+N0+i <- src 1+i
    H[((size_t)b * N1 + 1 + N0 + i) * (E / 4) + e4] =
        H[((size_t)b * N1 + 1 + i) * (E / 4) + e4];
  }
}

// landmark means of LN(h) with zero front-pad: xl = (g*sum((x-mu)*inv) + b*nreal)/24
__global__ __launch_bounds__(256)
void landmark_mean(const float* __restrict__ h, const float* __restrict__ stats,
                   const float* __restrict__ g, const float* __restrict__ bta,
                   float* __restrict__ xl)
{
  const int bm = blockIdx.x;
  const int b = bm / LM, i = bm % LM;
  const int tid = threadIdx.x;
  float2 acc = make_float2(0.f, 0.f);
  float cnt = 0.f;
  for (int j = 0; j < LCH; j++) {
    const int real = i * LCH + j - PADS;
    if (real < 0) continue;
    const size_t row = (size_t)b * N1 + real;
    float2 hv = *reinterpret_cast<const float2*>(h + row * E + tid * 2);
    const float mu = stats[2 * row], inv = stats[2 * row + 1];
    acc.x += (hv.x - mu) * inv;
    acc.y += (hv.y - mu) * inv;
    cnt += 1.f;
  }
  float2 gg = *reinterpret_cast<const float2*>(g + tid * 2);
  float2 bb = *reinterpret_cast<const float2*>(bta + tid * 2);
  float2 o;
  o.x = (gg.x * acc.x + bb.x * cnt) * (1.f / LCH);
  o.y = (gg.y * acc.y + bb.y * cnt) * (1.f / LCH);
  *reinterpret_cast<float2*>(xl + (size_t)bm * E + tid * 2) = o;
}

__global__ void zero_pad_rows(float* __restrict__ q, float* __restrict__ k, float* __restrict__ v)
{
  const int idx = blockIdx.x * 256 + threadIdx.x;
  const int total = BH * PADS * DH;
  if (idx >= total) return;
  const int d = idx % DH;
  int t = idx / DH;
  const int p = t % PADS;
  const int bh = t / PADS;
  const size_t o = ((size_t)bh * NP + p) * DH + d;
  q[o] = 0.f; k[o] = 0.f; v[o] = 0.f;
}

__global__ void scatter_qk_l(const float* __restrict__ qkvf, float* __restrict__ ql,
                             float* __restrict__ kl)
{
  long long idx = (long long)blockIdx.x * 256 + threadIdx.x;
  const long long total = (long long)Bq * LM * (QKV / 4);
  if (idx >= total) return;
  const int c4 = (int)(idx % (QKV / 4));
  long long t = idx / (QKV / 4);
  const int i = (int)(t % LM);
  const int b = (int)(t / LM);
  const int c = c4 * 4;
  const int wch = c >> 9;
  if (wch == 2) return;   // v_l unused
  const int hd = (c >> 6) & 7;
  const int d4 = (c & 63) >> 2;
  float4 val = reinterpret_cast<const float4*>(qkvf)[idx];
  if (wch == 0) { val.x *= 0.125f; val.y *= 0.125f; val.z *= 0.125f; val.w *= 0.125f; }
  float* dst = (wch == 0) ? ql : kl;
  reinterpret_cast<float4*>(dst)[(((size_t)(b * NH + hd)) * LM + i) * 16 + d4] = val;
}

__global__ void softmax_rows(float* __restrict__ X, int LEN)
{
  extern __shared__ float buf[];
  const size_t row = blockIdx.x;
  float* x = X + row * (size_t)LEN;
  const int tid = threadIdx.x;
  __shared__ float red[256];
  float m = -INFINITY;
  for (int i = tid; i < LEN; i += 256) { const float v = x[i]; buf[i] = v; m = fmaxf(m, v); }
  red[tid] = m;
  __syncthreads();
  for (int s = 128; s > 0; s >>= 1) { if (tid < s) red[tid] = fmaxf(red[tid], red[tid + s]); __syncthreads(); }
  m = red[0];
  __syncthreads();
  float sum = 0.f;
  for (int i = tid; i < LEN; i += 256) { const float v = expf(buf[i] - m); buf[i] = v; sum += v; }
  red[tid] = sum;
  __syncthreads();
  for (int s = 128; s > 0; s >>= 1) { if (tid < s) red[tid] += red[tid + s]; __syncthreads(); }
  const float inv = 1.f / red[0];
  for (int i = tid; i < LEN; i += 256) x[i] = buf[i] * inv;
}

__global__ void init_gmax(unsigned int* g) { if (threadIdx.x < 2) g[threadIdx.x] = 0u; }

__global__ __launch_bounds__(256)
void colrow_max(const float* __restrict__ a2, unsigned int* __restrict__ gmax)
{
  const float* a = a2 + (size_t)blockIdx.x * LM * LM;
  const int tid = threadIdx.x;
  float rowsum = 0.f, colsum = 0.f;
  for (int j = 0; j < LM; j++) rowsum += a[(size_t)tid * LM + j];
  for (int i = 0; i < LM; i++) colsum += a[(size_t)i * LM + tid];
  __shared__ float r1[256], r2[256];
  r1[tid] = rowsum; r2[tid] = colsum;
  __syncthreads();
  for (int s = 128; s > 0; s >>= 1) {
    if (tid < s) { r1[tid] = fmaxf(r1[tid], r1[tid + s]); r2[tid] = fmaxf(r2[tid], r2[tid + s]); }
    __syncthreads();
  }
  if (tid == 0) {
    atomicMax(&gmax[0], __float_as_uint(r1[0]));
    atomicMax(&gmax[1], __float_as_uint(r2[0]));
  }
}

__global__ void pinv_init_z(const float* __restrict__ a2, const unsigned int* __restrict__ gmax,
                            float* __restrict__ z)
{
  long long idx = (long long)blockIdx.x * 256 + threadIdx.x;
  const long long total = (long long)BH * LM * LM;
  if (idx >= total) return;
  const int j = (int)(idx % LM);
  long long t = idx / LM;
  const int i = (int)(t % LM);
  const int bh = (int)(t / LM);
  const float denom = __uint_as_float(gmax[0]) * __uint_as_float(gmax[1]);
  z[idx] = a2[((size_t)bh * LM + j) * LM + i] / denom;   // x^T / (maxcol*maxrow)
}

__global__ void reduce_parts(const float* __restrict__ part, float* __restrict__ out, int nitems)
{
  const int idx = blockIdx.x * 256 + threadIdx.x;
  if (idx >= nitems) return;
  const int local = idx / (LM * DH);
  const int r = idx % (LM * DH);
  float s = 0.f;
  #pragma unroll
  for (int sp = 0; sp < NSPLIT; sp++)
    s += part[((size_t)(local * NSPLIT + sp)) * LM * DH + r];
  out[idx] = s;
}

__global__ void dwconv_add(const float* __restrict__ v, const float* __restrict__ w,
                           float* __restrict__ outh)
{
  long long idx = (long long)blockIdx.x * 256 + threadIdx.x;
  const long long total = (long long)BH * NP * 16;
  if (idx >= total) return;
  const int d4 = (int)(idx & 15);
  long long t = idx >> 4;
  const int p = (int)(t % NP);
  const int bh = (int)(t / NP);
  const float4* vb = reinterpret_cast<const float4*>(v) + (size_t)bh * NP * 16;
  const float* wt = w + (bh % NH) * 33;
  float4 acc = reinterpret_cast<float4*>(outh)[idx];
  #pragma unroll
  for (int tp = 0; tp < 33; tp++) {
    const int pp = p + tp - 16;
    if (pp < 0 || pp >= NP) continue;
    const float ww = wt[tp];
    const float4 vv = vb[(size_t)pp * 16 + d4];
    acc.x = fmaf(ww, vv.x, acc.x);
    acc.y = fmaf(ww, vv.y, acc.y);
    acc.z = fmaf(ww, vv.z, acc.z);
    acc.w = fmaf(ww, vv.w, acc.w);
  }
  reinterpret_cast<float4*>(outh)[idx] = acc;
}

// LAST-attention: only cls row (p=PADS) of a1/PV/dwconv is needed
__global__ __launch_bounds__(256)
void last_row_attn(const float* __restrict__ q, const float* __restrict__ kl,
                   const float* __restrict__ W2, const float* __restrict__ v,
                   const float* __restrict__ resw, float* __restrict__ hb)
{
  const int bh = blockIdx.x;
  const int tid = threadIdx.x;
  __shared__ float qrow[DH];
  __shared__ float p[LM];
  __shared__ float red[256];
  const float* qr = q + ((size_t)bh * NP + PADS) * DH;
  if (tid < DH) qrow[tid] = qr[tid];
  __syncthreads();
  const float* krow = kl + ((size_t)bh * LM + tid) * DH;
  float s = 0.f;
  for (int d = 0; d < DH; d++) s = fmaf(qrow[d], krow[d], s);
  red[tid] = s;
  __syncthreads();
  for (int st = 128; st > 0; st >>= 1) { if (tid < st) red[tid] = fmaxf(red[tid], red[tid + st]); __syncthreads(); }
  const float m = red[0];
  __syncthreads();
  const float e = expf(s - m);
  red[tid] = e;
  __syncthreads();
  for (int st = 128; st > 0; st >>= 1) { if (tid < st) red[tid] += red[tid + st]; __syncthreads(); }
  p[tid] = e / red[0];
  __syncthreads();
  if (tid < DH) {
    const float* w2b = W2 + (size_t)bh * LM * DH;
    float acc = 0.f;
    for (int j = 0; j < LM; j++) acc = fmaf(p[j], w2b[(size_t)j * DH + tid], acc);
    const float* wt = resw + (bh % NH) * 33;
    const float* vb = v + (size_t)bh * NP * DH;
    #pragma unroll
    for (int t = 0; t < 33; t++)
      acc = fmaf(wt[t], vb[(size_t)(PADS - 16 + t) * DH + tid], acc);
    hb[bh * DH + tid] = acc;
  }
}

__global__ __launch_bounds__(256)
void last_outproj(const float* __restrict__ hb, const float* __restrict__ outw,
                  const float* __restrict__ outb, float* __restrict__ h)
{
  const int b = blockIdx.x;
  const int tid = threadIdx.x;
  __shared__ float cat[E];
  for (int c = tid; c < E; c += 256) cat[c] = hb[(b * NH + (c >> 6)) * DH + (c & 63)];
  __syncthreads();
  for (int e = tid; e < E; e += 256) {
    float acc = outb[e];
    for (int c = 0; c < E; c++) acc = fmaf(cat[c], outw[(size_t)c * E + e], acc);
    h[(size_t)b * N1 * E + e] += acc;
  }
}

__global__ __launch_bounds__(256)
void ppeg_conv(const float* __restrict__ h,
               const float* __restrict__ w7, const float* __restrict__ b7,
               const float* __restrict__ w5, const float* __restrict__ b5,
               const float* __restrict__ w3, const float* __restrict__ b3,
               float* __restrict__ tmp)
{
  long long idx = (long long)blockIdx.x * 256 + threadIdx.x;
  const long long total = (long long)Bq * HWp * E;
  if (idx >= total) return;
  const int e = (int)(idx % E);
  long long t = idx / E;
  const int pix = (int)(t % HWp);
  const int b = (int)(t / HWp);
  const int py = pix / HH, px = pix % HH;
  const float* hb = h + ((size_t)b * N1 + 1) * E;
  float acc = hb[(size_t)pix * E + e] + b7[e] + b5[e] + b3[e];
  const float* W7 = w7 + e * 49;
  const float* W5 = w5 + e * 25;
  const float* W3 = w3 + e * 9;
  #pragma unroll
  for (int ky = 0; ky < 7; ky++) {
    const int yy = py + ky - 3; if (yy < 0 || yy >= HH) continue;
    #pragma unroll
    for (int kx = 0; kx < 7; kx++) {
      const int xx = px + kx - 3; if (xx < 0 || xx >= HH) continue;
      acc = fmaf(W7[ky * 7 + kx], hb[((size_t)yy * HH + xx) * E + e], acc);
    }
  }
  #pragma unroll
  for (int ky = 0; ky < 5; ky++) {
    const int yy = py + ky - 2; if (yy < 0 || yy >= HH) continue;
    #pragma unroll
    for (int kx = 0; kx < 5; kx++) {
      const int xx = px + kx - 2; if (xx < 0 || xx >= HH) continue;
      acc = fmaf(W5[ky * 5 + kx], hb[((size_t)yy * HH + xx) * E + e], acc);
    }
  }
  #pragma unroll
  for (int ky = 0; ky < 3; ky++) {
    const int yy = py + ky - 1; if (yy < 0 || yy >= HH) continue;
    #pragma unroll
    for (int kx = 0; kx < 3; kx++) {
      const int xx = px + kx - 1; if (xx < 0 || xx >= HH) continue;
      acc = fmaf(W3[ky * 3 + kx], hb[((size_t)yy * HH + xx) * E + e], acc);
    }
  }
  tmp[idx] = acc;
}

__global__ void ppeg_copyback(const float* __restrict__ tmp, float* __restrict__ h)
{
  long long idx = (long long)blockIdx.x * 256 + threadIdx.x;
  const long long total = (long long)Bq * HWp * (E / 4);
  if (idx >= total) return;
  const int e4 = (int)(idx % (E / 4));
  long long t = idx / (E / 4);
  const int pix = (int)(t % HWp);
  const int b = (int)(t / HWp);
  reinterpret_cast<float4*>(h)[((size_t)b * N1 + 1 + pix) * (E / 4) + e4] =
      reinterpret_cast<const float4*>(tmp)[idx];
}

__global__ __launch_bounds__(256)
void final_head(const float* __restrict__ h, const float* __restrict__ g,
                const float* __restrict__ bb, const float* __restrict__ w2,
                const float* __restrict__ b2, float* __restrict__ out)
{
  const int b = blockIdx.x;
  const int tid = threadIdx.x;
  const float* x = h + (size_t)b * N1 * E;  // cls row
  float2 v = *reinterpret_cast<const float2*>(x + tid * 2);
  __shared__ float red[256];
  red[tid] = v.x + v.y;
  __syncthreads();
  for (int st = 128; st > 0; st >>= 1) { if (tid < st) red[tid] += red[tid + st]; __syncthreads(); }
  const float mu = red[0] * (1.f / E);
  __syncthreads();
  const float dx = v.x - mu, dy = v.y - mu;
  red[tid] = dx * dx + dy * dy;
  __syncthreads();
  for (int st = 128; st > 0; st >>= 1) { if (tid < st) red[tid] += red[tid + st]; __syncthreads(); }
  const float inv = 1.f / sqrtf(red[0] * (1.f / E) + 1e-5f);
  __shared__ float hn[E];
  float2 gg = *reinterpret_cast<const float2*>(g + tid * 2);
  float2 bv = *reinterpret_cast<const float2*>(bb + tid * 2);
  hn[tid * 2]     = dx * inv * gg.x + bv.x;
  hn[tid * 2 + 1] = dy * inv * gg.y + bv.y;
  __syncthreads();
  __shared__ float lg[4];
  if (tid < 4) {
    float a = b2[tid];
    for (int e = 0; e < E; e++) a = fmaf(hn[e], w2[e * 4 + tid], a);
    lg[tid] = a;
  }
  __syncthreads();
  if (tid == 0) {
    int best = 0;
    float bvv = lg[0];
    for (int j = 1; j < 4; j++) if (lg[j] > bvv) { bvv = lg[j]; best = j; }
    float S = 1.f;
    for (int j = 0; j < 4; j++) {
      const float hz = 1.f / (1.f + expf(-lg[j]));
      out[b * 4 + j] = hz;
      S *= (1.f - hz);
      out[16 + b * 4 + j] = S;
    }
    out[32 + b] = (float)best;
  }
}

__global__ void write_sentinel(float* out) { if (threadIdx.x < 36) out[threadIdx.x] = -777.f; }

// ---------------------------------------------------------------------------
struct Ws {
  float *q, *k, *v, *h, *F, *G, *ql, *kl, *z0, *stats;
  unsigned int* gmax;
};

static void run_attention(hipStream_t stream, Ws& w,
                          const float* lng, const float* lnb, const float* qkvw,
                          const float* outw, const float* outb, const float* resw,
                          bool last)
{
  const dim3 blk(256);
  // region G phases: [xl | qkvl] -> [a2] -> [a3v | a3vp | W2 | hb]
  float* xl   = w.G;
  float* qkvl = w.G + (size_t)Bq * LM * E;
  float* a2   = w.G;
  float* a3v  = w.G;
  float* a3vp = w.G + (size_t)BH * LM * DH;
  float* W2   = w.G + (size_t)2 * BH * LM * DH;
  float* hb   = w.G + (size_t)3 * BH * LM * DH;
  // region F phases: pinv temps f1..f3 -> chunk buffer U
  float* f1 = w.F;
  float* f2 = w.F + (size_t)BH * sMM;
  float* f3 = w.F + (size_t)2 * BH * sMM;
  float* U  = w.F;

  // 1. LN stats of h
  ln_stats<<<Bq * N1, blk, 0, stream>>>(w.h, w.stats);
  // 2. landmark means of LN(h) (projection is linear)
  landmark_mean<<<Bq * LM, blk, 0, stream>>>(w.h, w.stats, lng, lnb, xl);
  // 3. qkv projection with fused LN on A, scattered into padded [bh][p][d]
  gemm128<false, false, false, true, false, false, true>
      <<<dim3(QKV / 128, (Bq * N1 + 127) / 128), blk, 0, stream>>>(
      w.h, qkvw, nullptr, nullptr, w.q, w.k, w.v, nullptr, lng, lnb, w.stats,
      Bq * N1, QKV, E);
  zero_pad_rows<<<gblocks_i((long long)BH * PADS * DH), blk, 0, stream>>>(w.q, w.k, w.v);
  // 4. landmark qkv
  gemm128<false, false, false, false, false, false, false>
      <<<dim3(QKV / 128, (Bq * LM + 127) / 128), blk, 0, stream>>>(
      xl, qkvw, nullptr, qkvl, nullptr, nullptr, nullptr, nullptr, nullptr, nullptr, nullptr,
      Bq * LM, QKV, E);
  scatter_qk_l<<<gblocks_i((long long)Bq * LM * (QKV / 4)), blk, 0, stream>>>(qkvl, w.ql, w.kl);

  // 5. a2 = softmax(q_l @ k_l^T)
  bgemm64<true, false><<<dim3(LM / 64, LM / 64, BH), blk, 0, stream>>>(
      w.ql, w.kl, a2, LM, DH, sLD, sLD, sMM, 1, 1.f, 0.f);
  softmax_rows<<<BH * LM, blk, LM * 4, stream>>>(a2, LM);

  // 6. Moore-Penrose pinv, 6 Newton-Schulz iters, 4-buffer rotation
  init_gmax<<<1, 64, 0, stream>>>(w.gmax);
  colrow_max<<<BH, blk, 0, stream>>>(a2, w.gmax);
  pinv_init_z<<<gblocks_i((long long)BH * sMM), blk, 0, stream>>>(a2, w.gmax, w.z0);
  float* zc = w.z0;
  for (int it = 0; it < 6; ++it) {
    float* other = (zc == w.z0) ? f2 : w.z0;
    bgemm64<false, false><<<dim3(4, 4, BH), blk, 0, stream>>>(a2, zc, f1, LM, LM, sMM, sMM, sMM, 1, 1.f, 0.f);
    bgemm64<false, true ><<<dim3(4, 4, BH), blk, 0, stream>>>(f1, f1, other, LM, LM, sMM, sMM, sMM, 1, 1.f, 7.f);
    bgemm64<false, true ><<<dim3(4, 4, BH), blk, 0, stream>>>(f1, other, f3, LM, LM, sMM, sMM, sMM, 1, 1.f, 15.f);
    bgemm64<false, true ><<<dim3(4, 4, BH), blk, 0, stream>>>(zc, f3, other, LM, LM, sMM, sMM, sMM, 1, 0.25f, 13.f);
    zc = other;
  }
  // even iter count -> zc == w.z0 (persists while F is reused as U)

  // 7. a3v = softmax(q_l @ k^T) @ v, streamed in head-chunks through U
  for (int c = 0; c < BH / CH; ++c) {
    bgemm64<true, false><<<dim3(NP / 64, LM / 64, CH), blk, 0, stream>>>(
        w.ql + (size_t)c * CH * sLD, w.k + (size_t)c * CH * sND, U,
        NP, DH, sLD, sND, (long long)LM * NP, 1, 1.f, 0.f);
    softmax_rows<<<CH * LM, blk, NP * 4, stream>>>(U, NP);
    bgemm64<false, false><<<dim3(1, LM / 64, CH * NSPLIT), blk, 0, stream>>>(
        U, w.v + (size_t)c * CH * sND, a3vp,
        DH, NP, (long long)LM * NP, sND, sLD, NSPLIT, 1.f, 0.f);
    reduce_parts<<<gblocks_i((long long)CH * LM * DH), blk, 0, stream>>>(
        a3vp, a3v + (size_t)c * CH * LM * DH, CH * LM * DH);
  }

  // 8. W2 = a2_inv @ a3v
  bgemm64<false, false><<<dim3(1, LM / 64, BH), blk, 0, stream>>>(
      zc, a3v, W2, DH, LM, sMM, sLD, sLD, 1, 1.f, 0.f);

  if (!last) {
    // 9. heads = softmax(q @ k_l^T) @ W2, chunked; heads alias q
    for (int c = 0; c < BH / CH; ++c) {
      bgemm64<true, false><<<dim3(LM / 64, NP / 64, CH), blk, 0, stream>>>(
          w.q + (size_t)c * CH * sND, w.kl + (size_t)c * CH * sLD, U,
          LM, DH, sND, sLD, (long long)NP * LM, 1, 1.f, 0.f);
      softmax_rows<<<CH * NP, blk, LM * 4, stream>>>(U, LM);
      bgemm64<false, false><<<dim3(1, NP / 64, CH), blk, 0, stream>>>(
          U, W2 + (size_t)c * CH * sLD, w.q + (size_t)c * CH * sND,
          DH, LM, (long long)NP * LM, sLD, sND, 1, 1.f, 0.f);
    }
    // 10. depthwise seq-conv residual on v
    dwconv_add<<<gblocks_i((long long)BH * NP * 16), blk, 0, stream>>>(w.v, resw, w.q);
    // 11. merge heads (gather epilogue-free A) + out-proj + residual into h
    gemm128<true, false, true, false, false, true, false>
        <<<dim3(E / 128, (Bq * N1 + 127) / 128), blk, 0, stream>>>(
        nullptr, outw, outb, w.h, nullptr, nullptr, nullptr, w.q, nullptr, nullptr, nullptr,
        Bq * N1, E, E);
  } else {
    // only h row 0 feeds the output head: compute cls row only
    last_row_attn<<<BH, blk, 0, stream>>>(w.q, w.kl, W2, w.v, resw, hb);
    last_outproj<<<Bq, blk, 0, stream>>>(hb, outw, outb, w.h);
  }
}

}  // namespace

extern "C" void kernel_launch(void* const* d_in, const int* in_sizes, int n_in,
                              void* d_out, int out_size, void* d_ws, size_t ws_size,
                              hipStream_t stream)
{
  const float* x_path   = (const float*)d_in[0];
  const float* fc1_w    = (const float*)d_in[1];
  const float* fc1_b    = (const float*)d_in[2];
  const float* cls_tok  = (const float*)d_in[3];
  const float* ln1_g    = (const float*)d_in[4];
  const float* ln1_b    = (const float*)d_in[5];
  const float* qkv1_w   = (const float*)d_in[6];
  const float* out1_w   = (const float*)d_in[7];
  const float* out1_b   = (const float*)d_in[8];
  const float* res1_w   = (const float*)d_in[9];
  const float* ln2_g    = (const float*)d_in[10];
  const float* ln2_b    = (const float*)d_in[11];
  const float* qkv2_w   = (const float*)d_in[12];
  const float* out2_w   = (const float*)d_in[13];
  const float* out2_b   = (const float*)d_in[14];
  const float* res2_w   = (const float*)d_in[15];
  const float* conv7_w  = (const float*)d_in[16];
  const float* conv7_b  = (const float*)d_in[17];
  const float* conv5_w  = (const float*)d_in[18];
  const float* conv5_b  = (const float*)d_in[19];
  const float* conv3_w  = (const float*)d_in[20];
  const float* conv3_b  = (const float*)d_in[21];
  const float* norm_g   = (const float*)d_in[22];
  const float* norm_b   = (const float*)d_in[23];
  const float* fc2_w    = (const float*)d_in[24];
  const float* fc2_b    = (const float*)d_in[25];
  (void)in_sizes; (void)n_in; (void)out_size;

  float* W = (float*)d_ws;
  size_t off = 0;
  auto take = [&](size_t n) -> float* {
    float* p = W + off;
    off += (n + 255) & ~(size_t)255;
    return p;
  };

  Ws w;
  w.q     = take((size_t)BH * NP * DH);   // also heads (attn1) & ppeg tmp
  w.k     = take((size_t)BH * NP * DH);
  w.v     = take((size_t)BH * NP * DH);
  w.h     = take((size_t)Bq * N1 * E);
  w.F     = take((size_t)3 * BH * sMM);   // pinv temps / U chunk buffer
  w.G     = take((size_t)BH * sMM);       // xl+qkvl / a2 / a3v+a3vp+W2+hb
  w.ql    = take((size_t)BH * LM * DH);
  w.kl    = take((size_t)BH * LM * DH);
  w.z0    = take((size_t)BH * sMM);
  w.stats = take((size_t)2 * Bq * N1);
  w.gmax  = (unsigned int*)take(64);

  if (ws_size < off * sizeof(float)) {
    // workspace too small: write a distinctive sentinel so the bench signal
    // (absmax ~777) is distinguishable from a math bug
    write_sentinel<<<1, 64, 0, stream>>>((float*)d_out);
    return;
  }

  const dim3 blk(256);

  // fc1 + relu, written directly into h rows [b*N1+1 .. b*N1+N0]
  gemm128<true, true, false, false, true, false, false>
      <<<dim3(E / 128, (Bq * N0 + 127) / 128), blk, 0, stream>>>(
      x_path, fc1_w, fc1_b, w.h, nullptr, nullptr, nullptr, nullptr, nullptr, nullptr, nullptr,
      Bq * N0, E, KIN);
  fill_cls_wrap<<<gblocks_i((long long)Bq * 85 * (E / 4)), blk, 0, stream>>>(cls_tok, w.h);

  run_attention(stream, w, ln1_g, ln1_b, qkv1_w, out1_w, out1_b, res1_w, false);

  // ppeg (q/k/v dead here -> q serves as tmp)
  ppeg_conv<<<gblocks_i((long long)Bq * HWp * E), blk, 0, stream>>>(
      w.h, conv7_w, conv7_b, conv5_w, conv5_b, conv3_w, conv3_b, w.q);
  ppeg_copyback<<<gblocks_i((long long)Bq * HWp * (E / 4)), blk, 0, stream>>>(w.q, w.h);

  run_attention(stream, w, ln2_g, ln2_b, qkv2_w, out2_w, out2_b, res2_w, true);

  final_head<<<Bq, blk, 0, stream>>>(w.h, norm_g, norm_b, fc2_w, fc2_b, (float*)d_out);
}

// Round 3
// 4104.151 us; speedup vs baseline: 1.8831x; 1.8831x over previous
//
#include <hip/hip_runtime.h>
#include <math.h>

namespace {

constexpr int Bq   = 4;
constexpr int N0   = 6000;
constexpr int KIN  = 1024;
constexpr int E    = 512;
constexpr int HH   = 78;
constexpr int HWp  = 6084;        // 78*78
constexpr int N1   = 6085;        // 1 + HWp
constexpr int NH   = 8;
constexpr int DH   = 64;
constexpr int LM   = 256;         // landmarks
constexpr int NP   = 6144;        // padded seq
constexpr int LCH  = 24;          // chunk len per landmark
constexpr int PADS = 59;          // front zero-pad
constexpr int BH   = Bq * NH;     // 32
constexpr int QKV  = 3 * E;       // 1536
constexpr int CH   = 4;           // head-chunk for a3/a1 streaming
constexpr int NSPLIT = 8;         // K-split for PV gemm

constexpr long long sLD = (long long)LM * DH;   // 16384
constexpr long long sND = (long long)NP * DH;   // 393216
constexpr long long sMM = (long long)LM * LM;   // 65536

typedef __attribute__((ext_vector_type(8))) short bf16x8;
typedef __attribute__((ext_vector_type(4))) float f32x4;

__host__ __device__ inline int gblocks_i(long long n) { return (int)((n + 255) / 256); }

__device__ inline unsigned short f2bf(float x) {
  unsigned u = __float_as_uint(x);
  u += 0x7FFFu + ((u >> 16) & 1u);   // round-to-nearest-even
  return (unsigned short)(u >> 16);
}

// ---------------------------------------------------------------------------
// weight transpose + f32->bf16: in[K][N] -> out[N][K]
// ---------------------------------------------------------------------------
__global__ __launch_bounds__(256)
void wcvt_t(const float* __restrict__ in, short* __restrict__ out, int K, int N)
{
  __shared__ float T[32][33];
  const int tx = threadIdx.x & 31, ty = threadIdx.x >> 5;
  const int n0 = blockIdx.x * 32, k0 = blockIdx.y * 32;
  #pragma unroll
  for (int i = 0; i < 4; i++)
    T[ty + i * 8][tx] = in[(size_t)(k0 + ty + i * 8) * N + n0 + tx];
  __syncthreads();
  #pragma unroll
  for (int i = 0; i < 4; i++)
    out[(size_t)(n0 + ty + i * 8) * K + k0 + tx] = (short)f2bf(T[tx][ty + i * 8]);
}

// ---------------------------------------------------------------------------
// mgemm: C[M,N] = A[M,K] @ B[K,N] via bf16 MFMA (B pre-transposed bf16 [N][K]).
// 128x128 tile, BK=32, 256 thr = 4 waves (2x2 of 64x64), 16x16x32 MFMA.
// ASRC: 0 plain f32 A, 1 LN-on-A (h+stats+g+b), 2 gather from heads layout.
// STORE: 0 plain, 1 shift (fc1->h rows), 2 scatter (qkv->q/k/v), 3 accum.
// N mult of 128, K mult of 32; M guarded.
// ---------------------------------------------------------------------------
template<int ASRC, int STORE, bool BIAS, bool RELU>
__global__ __launch_bounds__(256)
void mgemm(const float* __restrict__ A, const short* __restrict__ Bt,
           const float* __restrict__ bias, float* __restrict__ C,
           float* __restrict__ qp, float* __restrict__ kp, float* __restrict__ vp,
           const float* __restrict__ Ag, const float* __restrict__ lng,
           const float* __restrict__ lnb, const float* __restrict__ stats,
           int Mrows, int N, int K)
{
  __shared__ __align__(16) short As[128 * 40];   // 80B row stride (16B aligned)
  __shared__ __align__(16) short Bs[128 * 40];
  const int t = threadIdx.x;
  const int lane = t & 63;
  const int l16 = lane & 15, g = lane >> 4;
  const int wave = t >> 6;
  const int wr = (wave >> 1) * 64, wc = (wave & 1) * 64;
  const int rowBase = blockIdx.y * 128, colBase = blockIdx.x * 128;

  f32x4 acc[4][4];
  #pragma unroll
  for (int mi = 0; mi < 4; mi++)
    #pragma unroll
    for (int ni = 0; ni < 4; ni++) acc[mi][ni] = (f32x4){0.f, 0.f, 0.f, 0.f};

  for (int k0 = 0; k0 < K; k0 += 32) {
    // stage A (f32 -> bf16)
    #pragma unroll
    for (int i = 0; i < 4; i++) {
      const int id = i * 256 + t;
      const int row = id >> 3, kq = id & 7;
      const int r = rowBase + row;
      float4 va = make_float4(0.f, 0.f, 0.f, 0.f);
      if (r < Mrows) {
        const int kk = k0 + kq * 4;
        if (ASRC == 2) {
          const int b = r / N1, rr = r % N1;
          va = *reinterpret_cast<const float4*>(
              Ag + (((size_t)(b * NH + (kk >> 6))) * NP + PADS + rr) * DH + (kk & 63));
        } else if (ASRC == 1) {
          float4 hx = *reinterpret_cast<const float4*>(A + (size_t)r * K + kk);
          const float mu = stats[2 * r], inv = stats[2 * r + 1];
          float4 gg = *reinterpret_cast<const float4*>(lng + kk);
          float4 bb = *reinterpret_cast<const float4*>(lnb + kk);
          va.x = (hx.x - mu) * inv * gg.x + bb.x;
          va.y = (hx.y - mu) * inv * gg.y + bb.y;
          va.z = (hx.z - mu) * inv * gg.z + bb.z;
          va.w = (hx.w - mu) * inv * gg.w + bb.w;
        } else {
          va = *reinterpret_cast<const float4*>(A + (size_t)r * K + kk);
        }
      }
      const unsigned lo = (unsigned)f2bf(va.x) | ((unsigned)f2bf(va.y) << 16);
      const unsigned hi = (unsigned)f2bf(va.z) | ((unsigned)f2bf(va.w) << 16);
      *reinterpret_cast<uint2*>(&As[row * 40 + kq * 4]) = make_uint2(lo, hi);
    }
    // stage B (bf16 [N][K], k-contiguous)
    #pragma unroll
    for (int i = 0; i < 2; i++) {
      const int id = i * 256 + t;
      const int row = id >> 2, g8 = id & 3;
      int4 vb = *reinterpret_cast<const int4*>(Bt + (size_t)(colBase + row) * K + k0 + g8 * 8);
      *reinterpret_cast<int4*>(&Bs[row * 40 + g8 * 8]) = vb;
    }
    __syncthreads();
    bf16x8 af[4], bf[4];
    #pragma unroll
    for (int mi = 0; mi < 4; mi++)
      af[mi] = *reinterpret_cast<const bf16x8*>(&As[(wr + mi * 16 + l16) * 40 + g * 8]);
    #pragma unroll
    for (int ni = 0; ni < 4; ni++)
      bf[ni] = *reinterpret_cast<const bf16x8*>(&Bs[(wc + ni * 16 + l16) * 40 + g * 8]);
    #pragma unroll
    for (int mi = 0; mi < 4; mi++)
      #pragma unroll
      for (int ni = 0; ni < 4; ni++)
        acc[mi][ni] = __builtin_amdgcn_mfma_f32_16x16x32_bf16(af[mi], bf[ni], acc[mi][ni], 0, 0, 0);
    __syncthreads();
  }

  // epilogue: C/D layout col = lane&15, row = (lane>>4)*4 + reg
  #pragma unroll
  for (int mi = 0; mi < 4; mi++) {
    #pragma unroll
    for (int ni = 0; ni < 4; ni++) {
      #pragma unroll
      for (int r4 = 0; r4 < 4; r4++) {
        const int row = rowBase + wr + mi * 16 + g * 4 + r4;
        if (row >= Mrows) continue;
        const int col = colBase + wc + ni * 16 + l16;
        float v = acc[mi][ni][r4];
        if (BIAS) v += bias[col];
        if (RELU) v = fmaxf(v, 0.f);
        if (STORE == 2) {
          const int b   = row / N1;
          const int p   = (row % N1) + PADS;
          const int wch = col >> 9;
          const int hd  = (col >> 6) & 7;
          const int d   = col & 63;
          float vv = (wch == 0) ? v * 0.125f : v;
          float* dst = (wch == 0) ? qp : (wch == 1) ? kp : vp;
          dst[(((size_t)(b * NH + hd)) * NP + p) * DH + d] = vv;
        } else if (STORE == 1) {
          C[((size_t)(row / N0) * N1 + 1 + (row % N0)) * N + col] = v;
        } else if (STORE == 3) {
          C[(size_t)row * N + col] += v;
        } else {
          C[(size_t)row * N + col] = v;
        }
      }
    }
  }
}

// ---------------------------------------------------------------------------
// bgemm64: batched C = alpha * A @ Beff, 64x64 tile, 4x4 micro, BK=16. (f32)
// ---------------------------------------------------------------------------
template<bool TRANSB, bool DIAG>
__global__ __launch_bounds__(256)
void bgemm64(const float* __restrict__ A, const float* __restrict__ Bw,
             float* __restrict__ C, int N, int K,
             long long sA, long long sB, long long sC,
             int NS, float alpha, float c0)
{
  const int batch = blockIdx.z / NS;
  const int split = blockIdx.z % NS;
  const int Ks = K / NS;
  const int kbeg = split * Ks;
  const float* Ab = A + (size_t)batch * sA;
  const float* Bb = Bw + (size_t)batch * sB;
  float* Cb = C + (size_t)blockIdx.z * sC;

  __shared__ float As[16][68];
  __shared__ float Bs[16][68];
  const int tid = threadIdx.x;
  const int tx = tid & 15, ty = tid >> 4;
  const int rowBase = blockIdx.y * 64;
  const int colBase = blockIdx.x * 64;
  const int lrow = tid >> 2;
  const int lcol = (tid & 3) << 2;

  float acc[4][4];
  #pragma unroll
  for (int i = 0; i < 4; i++)
    #pragma unroll
    for (int j = 0; j < 4; j++) acc[i][j] = 0.f;

  for (int kb = kbeg; kb < kbeg + Ks; kb += 16) {
    {
      float4 va = *reinterpret_cast<const float4*>(Ab + (size_t)(rowBase + lrow) * K + kb + lcol);
      As[lcol + 0][lrow] = va.x;
      As[lcol + 1][lrow] = va.y;
      As[lcol + 2][lrow] = va.z;
      As[lcol + 3][lrow] = va.w;
    }
    if (TRANSB) {
      float4 vb = *reinterpret_cast<const float4*>(Bb + (size_t)(colBase + lrow) * K + kb + lcol);
      Bs[lcol + 0][lrow] = vb.x;
      Bs[lcol + 1][lrow] = vb.y;
      Bs[lcol + 2][lrow] = vb.z;
      Bs[lcol + 3][lrow] = vb.w;
    } else {
      const int kr = tid >> 4;
      const int bc = (tid & 15) << 2;
      float4 vb = *reinterpret_cast<const float4*>(Bb + (size_t)(kb + kr) * N + colBase + bc);
      if (DIAG) {
        const int gk = kb + kr;
        const int gn = colBase + bc;
        vb.x = ((gk == gn + 0) ? c0 : 0.f) - vb.x;
        vb.y = ((gk == gn + 1) ? c0 : 0.f) - vb.y;
        vb.z = ((gk == gn + 2) ? c0 : 0.f) - vb.z;
        vb.w = ((gk == gn + 3) ? c0 : 0.f) - vb.w;
      }
      *reinterpret_cast<float4*>(&Bs[kr][bc]) = vb;
    }
    __syncthreads();
    #pragma unroll
    for (int kk = 0; kk < 16; kk++) {
      float a[4], b[4];
      *reinterpret_cast<float4*>(&a[0]) = *reinterpret_cast<const float4*>(&As[kk][ty * 4]);
      *reinterpret_cast<float4*>(&b[0]) = *reinterpret_cast<const float4*>(&Bs[kk][tx * 4]);
      #pragma unroll
      for (int i = 0; i < 4; i++)
        #pragma unroll
        for (int j = 0; j < 4; j++)
          acc[i][j] = fmaf(a[i], b[j], acc[i][j]);
    }
    __syncthreads();
  }

  #pragma unroll
  for (int i = 0; i < 4; i++)
    #pragma unroll
    for (int j = 0; j < 4; j++)
      Cb[(size_t)(rowBase + ty * 4 + i) * N + colBase + tx * 4 + j] = alpha * acc[i][j];
}

// ---------------------------------------------------------------------------
__global__ __launch_bounds__(256)
void ln_stats(const float* __restrict__ X, float* __restrict__ stats)
{
  const size_t row = blockIdx.x;
  const float* x = X + row * E;
  const int tid = threadIdx.x;
  float2 v = *reinterpret_cast<const float2*>(x + tid * 2);
  __shared__ float red[256];
  red[tid] = v.x + v.y;
  __syncthreads();
  for (int s = 128; s > 0; s >>= 1) { if (tid < s) red[tid] += red[tid + s]; __syncthreads(); }
  const float mu = red[0] * (1.f / E);
  __syncthreads();
  const float dx = v.x - mu, dy = v.y - mu;
  red[tid] = dx * dx + dy * dy;
  __syncthreads();
  for (int s = 128; s > 0; s >>= 1) { if (tid < s) red[tid] += red[tid + s]; __syncthreads(); }
  if (tid == 0) {
    stats[2 * row]     = mu;
    stats[2 * row + 1] = 1.f / sqrtf(red[0] * (1.f / E) + 1e-5f);
  }
}

__global__ void fill_cls_wrap(const float* __restrict__ cls, float* __restrict__ h)
{
  int idx = blockIdx.x * 256 + threadIdx.x;
  const int total = Bq * 85 * (E / 4);
  if (idx >= total) return;
  const int e4 = idx % (E / 4);
  int t = idx / (E / 4);
  const int rr = t % 85;
  const int b = t / 85;
  float4* H = reinterpret_cast<float4*>(h);
  if (rr == 0) {
    H[((size_t)b * N1) * (E / 4) + e4] = reinterpret_cast<const float4*>(cls)[e4];
  } else {
    const int i = rr - 1;  // wrap rows: dest 1+N0+i <- src 1+i
    H[((size_t)b * N1 + 1 + N0 + i) * (E / 4) + e4] =
        H[((size_t)b * N1 + 1 + i) * (E / 4) + e4];
  }
}

__global__ __launch_bounds__(256)
void landmark_mean(const float* __restrict__ h, const float* __restrict__ stats,
                   const float* __restrict__ g, const float* __restrict__ bta,
                   float* __restrict__ xl)
{
  const int bm = blockIdx.x;
  const int b = bm / LM, i = bm % LM;
  const int tid = threadIdx.x;
  float2 acc = make_float2(0.f, 0.f);
  float cnt = 0.f;
  for (int j = 0; j < LCH; j++) {
    const int real = i * LCH + j - PADS;
    if (real < 0) continue;
    const size_t row = (size_t)b * N1 + real;
    float2 hv = *reinterpret_cast<const float2*>(h + row * E + tid * 2);
    const float mu = stats[2 * row], inv = stats[2 * row + 1];
    acc.x += (hv.x - mu) * inv;
    acc.y += (hv.y - mu) * inv;
    cnt += 1.f;
  }
  float2 gg = *reinterpret_cast<const float2*>(g + tid * 2);
  float2 bb = *reinterpret_cast<const float2*>(bta + tid * 2);
  float2 o;
  o.x = (gg.x * acc.x + bb.x * cnt) * (1.f / LCH);
  o.y = (gg.y * acc.y + bb.y * cnt) * (1.f / LCH);
  *reinterpret_cast<float2*>(xl + (size_t)bm * E + tid * 2) = o;
}

__global__ void zero_pad_rows(float* __restrict__ q, float* __restrict__ k, float* __restrict__ v)
{
  const int idx = blockIdx.x * 256 + threadIdx.x;
  const int total = BH * PADS * DH;
  if (idx >= total) return;
  const int d = idx % DH;
  int t = idx / DH;
  const int p = t % PADS;
  const int bh = t / PADS;
  const size_t o = ((size_t)bh * NP + p) * DH + d;
  q[o] = 0.f; k[o] = 0.f; v[o] = 0.f;
}

__global__ void scatter_qk_l(const float* __restrict__ qkvf, float* __restrict__ ql,
                             float* __restrict__ kl)
{
  long long idx = (long long)blockIdx.x * 256 + threadIdx.x;
  const long long total = (long long)Bq * LM * (QKV / 4);
  if (idx >= total) return;
  const int c4 = (int)(idx % (QKV / 4));
  long long t = idx / (QKV / 4);
  const int i = (int)(t % LM);
  const int b = (int)(t / LM);
  const int c = c4 * 4;
  const int wch = c >> 9;
  if (wch == 2) return;   // v_l unused
  const int hd = (c >> 6) & 7;
  const int d4 = (c & 63) >> 2;
  float4 val = reinterpret_cast<const float4*>(qkvf)[idx];
  if (wch == 0) { val.x *= 0.125f; val.y *= 0.125f; val.z *= 0.125f; val.w *= 0.125f; }
  float* dst = (wch == 0) ? ql : kl;
  reinterpret_cast<float4*>(dst)[(((size_t)(b * NH + hd)) * LM + i) * 16 + d4] = val;
}

__global__ void softmax_rows(float* __restrict__ X, int LEN)
{
  extern __shared__ float buf[];
  const size_t row = blockIdx.x;
  float* x = X + row * (size_t)LEN;
  const int tid = threadIdx.x;
  __shared__ float red[256];
  float m = -INFINITY;
  for (int i = tid; i < LEN; i += 256) { const float v = x[i]; buf[i] = v; m = fmaxf(m, v); }
  red[tid] = m;
  __syncthreads();
  for (int s = 128; s > 0; s >>= 1) { if (tid < s) red[tid] = fmaxf(red[tid], red[tid + s]); __syncthreads(); }
  m = red[0];
  __syncthreads();
  float sum = 0.f;
  for (int i = tid; i < LEN; i += 256) { const float v = expf(buf[i] - m); buf[i] = v; sum += v; }
  red[tid] = sum;
  __syncthreads();
  for (int s = 128; s > 0; s >>= 1) { if (tid < s) red[tid] += red[tid + s]; __syncthreads(); }
  const float inv = 1.f / red[0];
  for (int i = tid; i < LEN; i += 256) x[i] = buf[i] * inv;
}

__global__ void init_gmax(unsigned int* g) { if (threadIdx.x < 2) g[threadIdx.x] = 0u; }

__global__ __launch_bounds__(256)
void colrow_max(const float* __restrict__ a2, unsigned int* __restrict__ gmax)
{
  const float* a = a2 + (size_t)blockIdx.x * LM * LM;
  const int tid = threadIdx.x;
  float rowsum = 0.f, colsum = 0.f;
  for (int j = 0; j < LM; j++) rowsum += a[(size_t)tid * LM + j];
  for (int i = 0; i < LM; i++) colsum += a[(size_t)i * LM + tid];
  __shared__ float r1[256], r2[256];
  r1[tid] = rowsum; r2[tid] = colsum;
  __syncthreads();
  for (int s = 128; s > 0; s >>= 1) {
    if (tid < s) { r1[tid] = fmaxf(r1[tid], r1[tid + s]); r2[tid] = fmaxf(r2[tid], r2[tid + s]); }
    __syncthreads();
  }
  if (tid == 0) {
    atomicMax(&gmax[0], __float_as_uint(r1[0]));
    atomicMax(&gmax[1], __float_as_uint(r2[0]));
  }
}

__global__ void pinv_init_z(const float* __restrict__ a2, const unsigned int* __restrict__ gmax,
                            float* __restrict__ z)
{
  long long idx = (long long)blockIdx.x * 256 + threadIdx.x;
  const long long total = (long long)BH * LM * LM;
  if (idx >= total) return;
  const int j = (int)(idx % LM);
  long long t = idx / LM;
  const int i = (int)(t % LM);
  const int bh = (int)(t / LM);
  const float denom = __uint_as_float(gmax[0]) * __uint_as_float(gmax[1]);
  z[idx] = a2[((size_t)bh * LM + j) * LM + i] / denom;   // x^T / (maxcol*maxrow)
}

__global__ void reduce_parts(const float* __restrict__ part, float* __restrict__ out, int nitems)
{
  const int idx = blockIdx.x * 256 + threadIdx.x;
  if (idx >= nitems) return;
  const int local = idx / (LM * DH);
  const int r = idx % (LM * DH);
  float s = 0.f;
  #pragma unroll
  for (int sp = 0; sp < NSPLIT; sp++)
    s += part[((size_t)(local * NSPLIT + sp)) * LM * DH + r];
  out[idx] = s;
}

// depthwise seq-conv residual, register-sliding: thread = (bh, d4, 8 pixels)
__global__ __launch_bounds__(256)
void dwconv_add2(const float* __restrict__ v, const float* __restrict__ w,
                 float* __restrict__ outh)
{
  const int idx = blockIdx.x * 256 + threadIdx.x;
  const int total = BH * (NP / 8) * 16;
  if (idx >= total) return;
  const int d4 = idx & 15;
  int t = idx >> 4;
  const int pb = t % (NP / 8);
  const int bh = t / (NP / 8);
  const int p0 = pb * 8;
  const float4* vb = reinterpret_cast<const float4*>(v) + (size_t)bh * NP * 16;
  float4* ob = reinterpret_cast<float4*>(outh) + (size_t)bh * NP * 16;
  const float* wt = w + (bh % NH) * 33;
  float wl[33];
  #pragma unroll
  for (int i = 0; i < 33; i++) wl[i] = wt[i];
  float4 acc[8];
  #pragma unroll
  for (int j = 0; j < 8; j++) acc[j] = ob[(size_t)(p0 + j) * 16 + d4];
  for (int s = 0; s < 40; s++) {
    const int pp = p0 - 16 + s;
    if (pp < 0 || pp >= NP) continue;
    const float4 vv = vb[(size_t)pp * 16 + d4];
    #pragma unroll
    for (int j = 0; j < 8; j++) {
      const int ti = s - j;
      if (ti >= 0 && ti < 33) {
        const float ww = wl[ti];
        acc[j].x = fmaf(ww, vv.x, acc[j].x);
        acc[j].y = fmaf(ww, vv.y, acc[j].y);
        acc[j].z = fmaf(ww, vv.z, acc[j].z);
        acc[j].w = fmaf(ww, vv.w, acc[j].w);
      }
    }
  }
  #pragma unroll
  for (int j = 0; j < 8; j++) ob[(size_t)(p0 + j) * 16 + d4] = acc[j];
}

// LAST-attention: only cls row (p=PADS) of a1/PV/dwconv is needed
__global__ __launch_bounds__(256)
void last_row_attn(const float* __restrict__ q, const float* __restrict__ kl,
                   const float* __restrict__ W2, const float* __restrict__ v,
                   const float* __restrict__ resw, float* __restrict__ hb)
{
  const int bh = blockIdx.x;
  const int tid = threadIdx.x;
  __shared__ float qrow[DH];
  __shared__ float p[LM];
  __shared__ float red[256];
  const float* qr = q + ((size_t)bh * NP + PADS) * DH;
  if (tid < DH) qrow[tid] = qr[tid];
  __syncthreads();
  const float* krow = kl + ((size_t)bh * LM + tid) * DH;
  float s = 0.f;
  for (int d = 0; d < DH; d++) s = fmaf(qrow[d], krow[d], s);
  red[tid] = s;
  __syncthreads();
  for (int st = 128; st > 0; st >>= 1) { if (tid < st) red[tid] = fmaxf(red[tid], red[tid + st]); __syncthreads(); }
  const float m = red[0];
  __syncthreads();
  const float e = expf(s - m);
  red[tid] = e;
  __syncthreads();
  for (int st = 128; st > 0; st >>= 1) { if (tid < st) red[tid] += red[tid + st]; __syncthreads(); }
  p[tid] = e / red[0];
  __syncthreads();
  if (tid < DH) {
    const float* w2b = W2 + (size_t)bh * LM * DH;
    float acc = 0.f;
    for (int j = 0; j < LM; j++) acc = fmaf(p[j], w2b[(size_t)j * DH + tid], acc);
    const float* wt = resw + (bh % NH) * 33;
    const float* vb = v + (size_t)bh * NP * DH;
    #pragma unroll
    for (int t = 0; t < 33; t++)
      acc = fmaf(wt[t], vb[(size_t)(PADS - 16 + t) * DH + tid], acc);
    hb[bh * DH + tid] = acc;
  }
}

__global__ __launch_bounds__(256)
void last_outproj(const float* __restrict__ hb, const float* __restrict__ outw,
                  const float* __restrict__ outb, float* __restrict__ h)
{
  const int b = blockIdx.x;
  const int tid = threadIdx.x;
  __shared__ float cat[E];
  for (int c = tid; c < E; c += 256) cat[c] = hb[(b * NH + (c >> 6)) * DH + (c & 63)];
  __syncthreads();
  for (int e = tid; e < E; e += 256) {
    float acc = outb[e];
    for (int c = 0; c < E; c++) acc = fmaf(cat[c], outw[(size_t)c * E + e], acc);
    h[(size_t)b * N1 * E + e] += acc;
  }
}

// ---------------------------------------------------------------------------
// PPEG: transpose h feature rows to per-(b,e) planes, conv from LDS, back.
// ---------------------------------------------------------------------------
__global__ __launch_bounds__(256)
void transpose_h2p(const float* __restrict__ h, float* __restrict__ ht)
{
  __shared__ float T[32][33];
  const int tx = threadIdx.x & 31, ty = threadIdx.x >> 5;
  const int px0 = blockIdx.x * 32, e0 = blockIdx.y * 32, b = blockIdx.z;
  #pragma unroll
  for (int i = 0; i < 4; i++) {
    const int pix = px0 + ty + i * 8;
    if (pix < HWp)
      T[ty + i * 8][tx] = h[((size_t)b * N1 + 1 + pix) * E + e0 + tx];
  }
  __syncthreads();
  #pragma unroll
  for (int i = 0; i < 4; i++) {
    const int pix = px0 + tx;
    if (pix < HWp)
      ht[((size_t)b * E + e0 + ty + i * 8) * HWp + pix] = T[tx][ty + i * 8];
  }
}

__global__ __launch_bounds__(256)
void transpose_p2h(const float* __restrict__ ht, float* __restrict__ h)
{
  __shared__ float T[32][33];
  const int tx = threadIdx.x & 31, ty = threadIdx.x >> 5;
  const int px0 = blockIdx.x * 32, e0 = blockIdx.y * 32, b = blockIdx.z;
  #pragma unroll
  for (int i = 0; i < 4; i++) {
    const int pix = px0 + tx;
    if (pix < HWp)
      T[ty + i * 8][tx] = ht[((size_t)b * E + e0 + ty + i * 8) * HWp + pix];
  }
  __syncthreads();
  #pragma unroll
  for (int i = 0; i < 4; i++) {
    const int pix = px0 + ty + i * 8;
    if (pix < HWp)
      h[((size_t)b * N1 + 1 + pix) * E + e0 + tx] = T[tx][ty + i * 8];
  }
}

// one block = one (b,e) 78x78 plane; zero-padded LDS tile; in-place update
__global__ __launch_bounds__(256)
void ppeg_plane(float* __restrict__ ht,
                const float* __restrict__ w7, const float* __restrict__ b7,
                const float* __restrict__ w5, const float* __restrict__ b5,
                const float* __restrict__ w3, const float* __restrict__ b3)
{
  __shared__ float S[84][88];     // rows y -3..80, cols x -3..84 (zero halo)
  __shared__ float Wl[84];        // 0..48 w7, 49..73 w5, 74..82 w3
  const int t = threadIdx.x;
  const int e = blockIdx.x & (E - 1);
  float* plane = ht + (size_t)blockIdx.x * HWp;

  for (int i = t; i < 84 * 88; i += 256) (&S[0][0])[i] = 0.f;
  if (t < 49) Wl[t] = w7[(size_t)e * 49 + t];
  else if (t >= 64 && t < 89) Wl[49 + t - 64] = w5[(size_t)e * 25 + t - 64];
  else if (t >= 96 && t < 105) Wl[74 + t - 96] = w3[(size_t)e * 9 + t - 96];
  __syncthreads();
  for (int i = t; i < HWp; i += 256) S[3 + i / HH][3 + i % HH] = plane[i];
  const float bsum = b7[e] + b5[e] + b3[e];
  __syncthreads();

  float res[7][4];
  int it = 0;
  for (int gidx = t; gidx < 1560; gidx += 256, ++it) {
    const int y = gidx / 20, x0 = (gidx % 20) * 4;
    float a0 = bsum + S[y + 3][x0 + 3];
    float a1 = bsum + S[y + 3][x0 + 4];
    float a2 = bsum + S[y + 3][x0 + 5];
    float a3 = bsum + S[y + 3][x0 + 6];
    #pragma unroll
    for (int dy = -3; dy <= 3; dy++) {
      const int row = y + 3 + dy;
      float win[10];
      #pragma unroll
      for (int m = 0; m < 10; m++) win[m] = S[row][x0 + m];
      const int ky7 = dy + 3;
      #pragma unroll
      for (int kx = 0; kx < 7; kx++) {
        const float c = Wl[ky7 * 7 + kx];
        a0 = fmaf(c, win[kx + 0], a0);
        a1 = fmaf(c, win[kx + 1], a1);
        a2 = fmaf(c, win[kx + 2], a2);
        a3 = fmaf(c, win[kx + 3], a3);
      }
      if (dy >= -2 && dy <= 2) {
        const int ky5 = dy + 2;
        #pragma unroll
        for (int kx = 0; kx < 5; kx++) {
          const float c = Wl[49 + ky5 * 5 + kx];
          a0 = fmaf(c, win[kx + 1], a0);
          a1 = fmaf(c, win[kx + 2], a1);
          a2 = fmaf(c, win[kx + 3], a2);
          a3 = fmaf(c, win[kx + 4], a3);
        }
      }
      if (dy >= -1 && dy <= 1) {
        const int ky3 = dy + 1;
        #pragma unroll
        for (int kx = 0; kx < 3; kx++) {
          const float c = Wl[74 + ky3 * 3 + kx];
          a0 = fmaf(c, win[kx + 2], a0);
          a1 = fmaf(c, win[kx + 3], a1);
          a2 = fmaf(c, win[kx + 4], a2);
          a3 = fmaf(c, win[kx + 5], a3);
        }
      }
    }
    res[it][0] = a0; res[it][1] = a1; res[it][2] = a2; res[it][3] = a3;
  }
  __syncthreads();
  it = 0;
  for (int gidx = t; gidx < 1560; gidx += 256, ++it) {
    const int y = gidx / 20, x0 = (gidx % 20) * 4;
    #pragma unroll
    for (int j = 0; j < 4; j++)
      if (x0 + j < HH) plane[y * HH + x0 + j] = res[it][j];
  }
}

__global__ __launch_bounds__(256)
void final_head(const float* __restrict__ h, const float* __restrict__ g,
                const float* __restrict__ bb, const float* __restrict__ w2,
                const float* __restrict__ b2, float* __restrict__ out)
{
  const int b = blockIdx.x;
  const int tid = threadIdx.x;
  const float* x = h + (size_t)b * N1 * E;  // cls row
  float2 v = *reinterpret_cast<const float2*>(x + tid * 2);
  __shared__ float red[256];
  red[tid] = v.x + v.y;
  __syncthreads();
  for (int st = 128; st > 0; st >>= 1) { if (tid < st) red[tid] += red[tid + st]; __syncthreads(); }
  const float mu = red[0] * (1.f / E);
  __syncthreads();
  const float dx = v.x - mu, dy = v.y - mu;
  red[tid] = dx * dx + dy * dy;
  __syncthreads();
  for (int st = 128; st > 0; st >>= 1) { if (tid < st) red[tid] += red[tid + st]; __syncthreads(); }
  const float inv = 1.f / sqrtf(red[0] * (1.f / E) + 1e-5f);
  __shared__ float hn[E];
  float2 gg = *reinterpret_cast<const float2*>(g + tid * 2);
  float2 bv = *reinterpret_cast<const float2*>(bb + tid * 2);
  hn[tid * 2]     = dx * inv * gg.x + bv.x;
  hn[tid * 2 + 1] = dy * inv * gg.y + bv.y;
  __syncthreads();
  __shared__ float lg[4];
  if (tid < 4) {
    float a = b2[tid];
    for (int e = 0; e < E; e++) a = fmaf(hn[e], w2[e * 4 + tid], a);
    lg[tid] = a;
  }
  __syncthreads();
  if (tid == 0) {
    int best = 0;
    float bvv = lg[0];
    for (int j = 1; j < 4; j++) if (lg[j] > bvv) { bvv = lg[j]; best = j; }
    float S = 1.f;
    for (int j = 0; j < 4; j++) {
      const float hz = 1.f / (1.f + expf(-lg[j]));
      out[b * 4 + j] = hz;
      S *= (1.f - hz);
      out[16 + b * 4 + j] = S;
    }
    out[32 + b] = (float)best;
  }
}

__global__ void write_sentinel(float* out) { if (threadIdx.x < 36) out[threadIdx.x] = -777.f; }

// ---------------------------------------------------------------------------
struct Ws {
  float *q, *k, *v, *h, *F, *G, *ql, *kl, *z0, *stats;
  short *fc1T, *qkv1T, *qkv2T, *out1T, *out2T;
  unsigned int* gmax;
};

static void run_attention(hipStream_t stream, Ws& w,
                          const float* lng, const float* lnb, const short* qkvT,
                          const short* outT, const float* outb, const float* resw,
                          bool last)
{
  const dim3 blk(256);
  // region G phases: [xl | qkvl] -> [a2] -> [a3v | a3vp | W2 | hb]
  float* xl   = w.G;
  float* qkvl = w.G + (size_t)Bq * LM * E;
  float* a2   = w.G;
  float* a3v  = w.G;
  float* a3vp = w.G + (size_t)BH * LM * DH;
  float* W2   = w.G + (size_t)2 * BH * LM * DH;
  float* hb   = w.G + (size_t)3 * BH * LM * DH;
  // region F phases: pinv temps f1..f3 -> chunk buffer U
  float* f1 = w.F;
  float* f2 = w.F + (size_t)BH * sMM;
  float* f3 = w.F + (size_t)2 * BH * sMM;
  float* U  = w.F;

  // 1. LN stats of h
  ln_stats<<<Bq * N1, blk, 0, stream>>>(w.h, w.stats);
  // 2. landmark means of LN(h) (projection is linear)
  landmark_mean<<<Bq * LM, blk, 0, stream>>>(w.h, w.stats, lng, lnb, xl);
  // 3. qkv projection (bf16 MFMA) with fused LN on A, scatter to [bh][p][d]
  mgemm<1, 2, false, false><<<dim3(QKV / 128, (Bq * N1 + 127) / 128), blk, 0, stream>>>(
      w.h, qkvT, nullptr, nullptr, w.q, w.k, w.v, nullptr, lng, lnb, w.stats,
      Bq * N1, QKV, E);
  zero_pad_rows<<<gblocks_i((long long)BH * PADS * DH), blk, 0, stream>>>(w.q, w.k, w.v);
  // 4. landmark qkv
  mgemm<0, 0, false, false><<<dim3(QKV / 128, (Bq * LM + 127) / 128), blk, 0, stream>>>(
      xl, qkvT, nullptr, qkvl, nullptr, nullptr, nullptr, nullptr, nullptr, nullptr, nullptr,
      Bq * LM, QKV, E);
  scatter_qk_l<<<gblocks_i((long long)Bq * LM * (QKV / 4)), blk, 0, stream>>>(qkvl, w.ql, w.kl);

  // 5. a2 = softmax(q_l @ k_l^T)
  bgemm64<true, false><<<dim3(LM / 64, LM / 64, BH), blk, 0, stream>>>(
      w.ql, w.kl, a2, LM, DH, sLD, sLD, sMM, 1, 1.f, 0.f);
  softmax_rows<<<BH * LM, blk, LM * 4, stream>>>(a2, LM);

  // 6. Moore-Penrose pinv, 6 Newton-Schulz iters, 4-buffer rotation
  init_gmax<<<1, 64, 0, stream>>>(w.gmax);
  colrow_max<<<BH, blk, 0, stream>>>(a2, w.gmax);
  pinv_init_z<<<gblocks_i((long long)BH * sMM), blk, 0, stream>>>(a2, w.gmax, w.z0);
  float* zc = w.z0;
  for (int it = 0; it < 6; ++it) {
    float* other = (zc == w.z0) ? f2 : w.z0;
    bgemm64<false, false><<<dim3(4, 4, BH), blk, 0, stream>>>(a2, zc, f1, LM, LM, sMM, sMM, sMM, 1, 1.f, 0.f);
    bgemm64<false, true ><<<dim3(4, 4, BH), blk, 0, stream>>>(f1, f1, other, LM, LM, sMM, sMM, sMM, 1, 1.f, 7.f);
    bgemm64<false, true ><<<dim3(4, 4, BH), blk, 0, stream>>>(f1, other, f3, LM, LM, sMM, sMM, sMM, 1, 1.f, 15.f);
    bgemm64<false, true ><<<dim3(4, 4, BH), blk, 0, stream>>>(zc, f3, other, LM, LM, sMM, sMM, sMM, 1, 0.25f, 13.f);
    zc = other;
  }
  // even iter count -> zc == w.z0 (persists while F is reused as U)

  // 7. a3v = softmax(q_l @ k^T) @ v, streamed in head-chunks through U
  for (int c = 0; c < BH / CH; ++c) {
    bgemm64<true, false><<<dim3(NP / 64, LM / 64, CH), blk, 0, stream>>>(
        w.ql + (size_t)c * CH * sLD, w.k + (size_t)c * CH * sND, U,
        NP, DH, sLD, sND, (long long)LM * NP, 1, 1.f, 0.f);
    softmax_rows<<<CH * LM, blk, NP * 4, stream>>>(U, NP);
    bgemm64<false, false><<<dim3(1, LM / 64, CH * NSPLIT), blk, 0, stream>>>(
        U, w.v + (size_t)c * CH * sND, a3vp,
        DH, NP, (long long)LM * NP, sND, sLD, NSPLIT, 1.f, 0.f);
    reduce_parts<<<gblocks_i((long long)CH * LM * DH), blk, 0, stream>>>(
        a3vp, a3v + (size_t)c * CH * LM * DH, CH * LM * DH);
  }

  // 8. W2 = a2_inv @ a3v
  bgemm64<false, false><<<dim3(1, LM / 64, BH), blk, 0, stream>>>(
      zc, a3v, W2, DH, LM, sMM, sLD, sLD, 1, 1.f, 0.f);

  if (!last) {
    // 9. heads = softmax(q @ k_l^T) @ W2, chunked; heads alias q
    for (int c = 0; c < BH / CH; ++c) {
      bgemm64<true, false><<<dim3(LM / 64, NP / 64, CH), blk, 0, stream>>>(
          w.q + (size_t)c * CH * sND, w.kl + (size_t)c * CH * sLD, U,
          LM, DH, sND, sLD, (long long)NP * LM, 1, 1.f, 0.f);
      softmax_rows<<<CH * NP, blk, LM * 4, stream>>>(U, LM);
      bgemm64<false, false><<<dim3(1, NP / 64, CH), blk, 0, stream>>>(
          U, W2 + (size_t)c * CH * sLD, w.q + (size_t)c * CH * sND,
          DH, LM, (long long)NP * LM, sLD, sND, 1, 1.f, 0.f);
    }
    // 10. depthwise seq-conv residual on v
    dwconv_add2<<<gblocks_i((long long)BH * (NP / 8) * 16), blk, 0, stream>>>(w.v, resw, w.q);
    // 11. merge heads (gather A) + out-proj + residual into h (bf16 MFMA)
    mgemm<2, 3, true, false><<<dim3(E / 128, (Bq * N1 + 127) / 128), blk, 0, stream>>>(
        nullptr, outT, outb, w.h, nullptr, nullptr, nullptr, w.q, nullptr, nullptr, nullptr,
        Bq * N1, E, E);
  } else {
    // only h row 0 feeds the output head: compute cls row only (f32 exact)
    last_row_attn<<<BH, blk, 0, stream>>>(w.q, w.kl, W2, w.v, resw, hb);
    // note: last_outproj uses the ORIGINAL f32 weights, passed via resw trick? No:
    // it is launched from kernel_launch with out2_w directly.
  }
}

}  // namespace

extern "C" void kernel_launch(void* const* d_in, const int* in_sizes, int n_in,
                              void* d_out, int out_size, void* d_ws, size_t ws_size,
                              hipStream_t stream)
{
  const float* x_path   = (const float*)d_in[0];
  const float* fc1_w    = (const float*)d_in[1];
  const float* fc1_b    = (const float*)d_in[2];
  const float* cls_tok  = (const float*)d_in[3];
  const float* ln1_g    = (const float*)d_in[4];
  const float* ln1_b    = (const float*)d_in[5];
  const float* qkv1_w   = (const float*)d_in[6];
  const float* out1_w   = (const float*)d_in[7];
  const float* out1_b   = (const float*)d_in[8];
  const float* res1_w   = (const float*)d_in[9];
  const float* ln2_g    = (const float*)d_in[10];
  const float* ln2_b    = (const float*)d_in[11];
  const float* qkv2_w   = (const float*)d_in[12];
  const float* out2_w   = (const float*)d_in[13];
  const float* out2_b   = (const float*)d_in[14];
  const float* res2_w   = (const float*)d_in[15];
  const float* conv7_w  = (const float*)d_in[16];
  const float* conv7_b  = (const float*)d_in[17];
  const float* conv5_w  = (const float*)d_in[18];
  const float* conv5_b  = (const float*)d_in[19];
  const float* conv3_w  = (const float*)d_in[20];
  const float* conv3_b  = (const float*)d_in[21];
  const float* norm_g   = (const float*)d_in[22];
  const float* norm_b   = (const float*)d_in[23];
  const float* fc2_w    = (const float*)d_in[24];
  const float* fc2_b    = (const float*)d_in[25];
  (void)in_sizes; (void)n_in; (void)out_size;

  float* W = (float*)d_ws;
  size_t off = 0;
  auto take = [&](size_t n) -> float* {
    float* p = W + off;
    off += (n + 255) & ~(size_t)255;
    return p;
  };

  Ws w;
  w.q     = take((size_t)BH * NP * DH);   // also heads (attn1) & ppeg planes
  w.k     = take((size_t)BH * NP * DH);
  w.v     = take((size_t)BH * NP * DH);
  w.h     = take((size_t)Bq * N1 * E);
  w.F     = take((size_t)3 * BH * sMM);   // pinv temps / U chunk buffer
  w.G     = take((size_t)BH * sMM);       // xl+qkvl / a2 / a3v+a3vp+W2+hb
  w.ql    = take((size_t)BH * LM * DH);
  w.kl    = take((size_t)BH * LM * DH);
  w.z0    = take((size_t)BH * sMM);
  w.stats = take((size_t)2 * Bq * N1);
  w.fc1T  = (short*)take((size_t)512 * 1024 / 2);
  w.qkv1T = (short*)take((size_t)1536 * 512 / 2);
  w.qkv2T = (short*)take((size_t)1536 * 512 / 2);
  w.out1T = (short*)take((size_t)512 * 512 / 2);
  w.out2T = (short*)take((size_t)512 * 512 / 2);
  w.gmax  = (unsigned int*)take(64);

  if (ws_size < off * sizeof(float)) {
    write_sentinel<<<1, 64, 0, stream>>>((float*)d_out);
    return;
  }

  const dim3 blk(256);

  // weight transposes + bf16 casts (tiny)
  wcvt_t<<<dim3(E / 32, KIN / 32), blk, 0, stream>>>(fc1_w, w.fc1T, KIN, E);
  wcvt_t<<<dim3(QKV / 32, E / 32), blk, 0, stream>>>(qkv1_w, w.qkv1T, E, QKV);
  wcvt_t<<<dim3(QKV / 32, E / 32), blk, 0, stream>>>(qkv2_w, w.qkv2T, E, QKV);
  wcvt_t<<<dim3(E / 32, E / 32), blk, 0, stream>>>(out1_w, w.out1T, E, E);
  wcvt_t<<<dim3(E / 32, E / 32), blk, 0, stream>>>(out2_w, w.out2T, E, E);

  // fc1 + relu (bf16 MFMA), written directly into h rows [b*N1+1 ..]
  mgemm<0, 1, true, true><<<dim3(E / 128, (Bq * N0 + 127) / 128), blk, 0, stream>>>(
      x_path, w.fc1T, fc1_b, w.h, nullptr, nullptr, nullptr, nullptr, nullptr, nullptr, nullptr,
      Bq * N0, E, KIN);
  fill_cls_wrap<<<gblocks_i((long long)Bq * 85 * (E / 4)), blk, 0, stream>>>(cls_tok, w.h);

  run_attention(stream, w, ln1_g, ln1_b, w.qkv1T, w.out1T, out1_b, res1_w, false);

  // PPEG: h -> planes (alias q), conv in LDS in-place, planes -> h
  {
    float* ht = w.q;
    transpose_h2p<<<dim3((HWp + 31) / 32, E / 32, Bq), blk, 0, stream>>>(w.h, ht);
    ppeg_plane<<<Bq * E, blk, 0, stream>>>(ht, conv7_w, conv7_b, conv5_w, conv5_b,
                                           conv3_w, conv3_b);
    transpose_p2h<<<dim3((HWp + 31) / 32, E / 32, Bq), blk, 0, stream>>>(ht, w.h);
  }

  run_attention(stream, w, ln2_g, ln2_b, w.qkv2T, w.out2T, out2_b, res2_w, true);
  // cls-row out-projection for attn2 (f32 exact, tiny)
  last_outproj<<<Bq, blk, 0, stream>>>(w.G + (size_t)3 * BH * LM * DH, out2_w, out2_b, w.h);

  final_head<<<Bq, blk, 0, stream>>>(w.h, norm_g, norm_b, fc2_w, fc2_b, (float*)d_out);
}

// Round 4
// 2275.836 us; speedup vs baseline: 3.3958x; 1.8034x over previous
//
#include <hip/hip_runtime.h>
#include <math.h>

namespace {

constexpr int Bq   = 4;
constexpr int N0   = 6000;
constexpr int KIN  = 1024;
constexpr int E    = 512;
constexpr int HH   = 78;
constexpr int HWp  = 6084;
constexpr int N1   = 6085;        // 1 + HWp
constexpr int NH   = 8;
constexpr int DH   = 64;
constexpr int LM   = 256;
constexpr int NP   = 6144;
constexpr int LCH  = 24;
constexpr int PADS = 59;
constexpr int BH   = Bq * NH;     // 32
constexpr int QKV  = 3 * E;

typedef __attribute__((ext_vector_type(8))) short bf16x8;
typedef __attribute__((ext_vector_type(4))) float f32x4;

__host__ __device__ inline int gblocks_i(long long n) { return (int)((n + 255) / 256); }

__device__ inline unsigned short f2bf(float x) {
  unsigned u = __float_as_uint(x);
  u += 0x7FFFu + ((u >> 16) & 1u);
  return (unsigned short)(u >> 16);
}
__device__ inline float bf2f(unsigned short s) {
  return __uint_as_float(((unsigned)s) << 16);
}
// LDS chunk swizzle: 8-bf16 (16B) chunks XORed by row bits -> bank-balanced
__device__ inline int swz8(int row, int chunk) {
  return chunk ^ (row & 7) ^ ((row >> 3) & 7);
}

// ---------------------------------------------------------------------------
// weight transpose + f32->bf16: in[K][N] -> out[N][K]
// ---------------------------------------------------------------------------
__global__ __launch_bounds__(256)
void wcvt_t(const float* __restrict__ in, unsigned short* __restrict__ out, int K, int N)
{
  __shared__ float T[32][33];
  const int tx = threadIdx.x & 31, ty = threadIdx.x >> 5;
  const int n0 = blockIdx.x * 32, k0 = blockIdx.y * 32;
  #pragma unroll
  for (int i = 0; i < 4; i++)
    T[ty + i * 8][tx] = in[(size_t)(k0 + ty + i * 8) * N + n0 + tx];
  __syncthreads();
  #pragma unroll
  for (int i = 0; i < 4; i++)
    out[(size_t)(n0 + ty + i * 8) * K + k0 + tx] = f2bf(T[tx][ty + i * 8]);
}

// ---------------------------------------------------------------------------
// mgemm: C[M,N] = A[M,K] @ B[K,N], bf16 MFMA, B pre-transposed bf16 [N][K].
// 128x128 tile, BK=32, 256 thr (2x2 waves of 64x64), 16x16x32 MFMA.
// ASRC: 0 f32 A; 3 bf16 A; 4 bf16 gather from heads layout.
// STORE: 0 f32 C; 1 shift (fc1->h rows); 2 bf16 scatter qkv; 3 f32 accum.
// SWIZ: XCD-bijective block remap.
// ---------------------------------------------------------------------------
template<int ASRC, int STORE, bool BIAS, bool RELU, bool SWIZ>
__global__ __launch_bounds__(256)
void mgemm(const void* __restrict__ Av, const unsigned short* __restrict__ Bt,
           const float* __restrict__ bias, float* __restrict__ C,
           unsigned short* __restrict__ qp, unsigned short* __restrict__ kp,
           unsigned short* __restrict__ vp, const unsigned short* __restrict__ Ag,
           int Mrows, int N, int K)
{
  __shared__ __align__(16) short As[128 * 40];
  __shared__ __align__(16) short Bs[128 * 40];
  const int t = threadIdx.x;
  const int lane = t & 63;
  const int l16 = lane & 15, g = lane >> 4;
  const int wave = t >> 6;
  const int wr = (wave >> 1) * 64, wc = (wave & 1) * 64;

  int bx = blockIdx.x, by = blockIdx.y;
  if (SWIZ) {
    const int gx = gridDim.x, nwg = gx * gridDim.y;
    const int flat = by * gx + bx;
    const int qq = nwg >> 3, rr = nwg & 7;
    const int xcd = flat & 7, pos = flat >> 3;
    const int nid = (xcd < rr ? xcd * (qq + 1) : rr * (qq + 1) + (xcd - rr) * qq) + pos;
    bx = nid % gx; by = nid / gx;
  }
  const int rowBase = by * 128, colBase = bx * 128;

  f32x4 acc[4][4];
  #pragma unroll
  for (int mi = 0; mi < 4; mi++)
    #pragma unroll
    for (int ni = 0; ni < 4; ni++) acc[mi][ni] = (f32x4){0.f, 0.f, 0.f, 0.f};

  for (int k0 = 0; k0 < K; k0 += 32) {
    if (ASRC == 0) {
      const float* A = (const float*)Av;
      #pragma unroll
      for (int i = 0; i < 4; i++) {
        const int id = i * 256 + t;
        const int row = id >> 3, kq = id & 7;
        const int r = rowBase + row;
        float4 va = make_float4(0.f, 0.f, 0.f, 0.f);
        if (r < Mrows)
          va = *reinterpret_cast<const float4*>(A + (size_t)r * K + k0 + kq * 4);
        const unsigned lo = (unsigned)f2bf(va.x) | ((unsigned)f2bf(va.y) << 16);
        const unsigned hi = (unsigned)f2bf(va.z) | ((unsigned)f2bf(va.w) << 16);
        *reinterpret_cast<uint2*>(&As[row * 40 + kq * 4]) = make_uint2(lo, hi);
      }
    } else {
      #pragma unroll
      for (int i = 0; i < 2; i++) {
        const int id = i * 256 + t;
        const int row = id >> 2, c8 = id & 3;
        const int r = rowBase + row;
        int4 va = make_int4(0, 0, 0, 0);
        if (r < Mrows) {
          const int kk = k0 + c8 * 8;
          if (ASRC == 4) {
            const int b = r / N1, rr2 = r % N1;
            va = *reinterpret_cast<const int4*>(
                Ag + (((size_t)(b * NH + (kk >> 6))) * NP + PADS + rr2) * DH + (kk & 63));
          } else {
            va = *reinterpret_cast<const int4*>(((const unsigned short*)Av) + (size_t)r * K + kk);
          }
        }
        *reinterpret_cast<int4*>(&As[row * 40 + c8 * 8]) = va;
      }
    }
    #pragma unroll
    for (int i = 0; i < 2; i++) {
      const int id = i * 256 + t;
      const int row = id >> 2, g8 = id & 3;
      int4 vb = *reinterpret_cast<const int4*>(Bt + (size_t)(colBase + row) * K + k0 + g8 * 8);
      *reinterpret_cast<int4*>(&Bs[row * 40 + g8 * 8]) = vb;
    }
    __syncthreads();
    bf16x8 af[4], bf[4];
    #pragma unroll
    for (int mi = 0; mi < 4; mi++)
      af[mi] = *reinterpret_cast<const bf16x8*>(&As[(wr + mi * 16 + l16) * 40 + g * 8]);
    #pragma unroll
    for (int ni = 0; ni < 4; ni++)
      bf[ni] = *reinterpret_cast<const bf16x8*>(&Bs[(wc + ni * 16 + l16) * 40 + g * 8]);
    #pragma unroll
    for (int mi = 0; mi < 4; mi++)
      #pragma unroll
      for (int ni = 0; ni < 4; ni++)
        acc[mi][ni] = __builtin_amdgcn_mfma_f32_16x16x32_bf16(af[mi], bf[ni], acc[mi][ni], 0, 0, 0);
    __syncthreads();
  }

  #pragma unroll
  for (int mi = 0; mi < 4; mi++) {
    #pragma unroll
    for (int ni = 0; ni < 4; ni++) {
      #pragma unroll
      for (int r4 = 0; r4 < 4; r4++) {
        const int row = rowBase + wr + mi * 16 + g * 4 + r4;
        if (row >= Mrows) continue;
        const int col = colBase + wc + ni * 16 + l16;
        float v = acc[mi][ni][r4];
        if (BIAS) v += bias[col];
        if (RELU) v = fmaxf(v, 0.f);
        if (STORE == 2) {
          const int b   = row / N1;
          const int p   = (row % N1) + PADS;
          const int wch = col >> 9;
          const int hd  = (col >> 6) & 7;
          const int d   = col & 63;
          float vv = (wch == 0) ? v * 0.125f : v;
          unsigned short* dst = (wch == 0) ? qp : (wch == 1) ? kp : vp;
          dst[(((size_t)(b * NH + hd)) * NP + p) * DH + d] = f2bf(vv);
        } else if (STORE == 1) {
          C[((size_t)(row / N0) * N1 + 1 + (row % N0)) * N + col] = v;
        } else if (STORE == 3) {
          C[(size_t)row * N + col] += v;
        } else {
          C[(size_t)row * N + col] = v;
        }
      }
    }
  }
}

// ---------------------------------------------------------------------------
// mm_ns: batched M = A[256xK] @ B[KxN] via BT bf16-split MFMA (3-term hi/lo).
// Writes (optionally) Cn = cN*I + aN*M  and  Ct = cT*I + aT*M^T (f32 or bf16).
// grid (Ncols/64, 4, batch). K mult of 64.
// ---------------------------------------------------------------------------
template<bool WN, bool WT, bool TBF>
__global__ __launch_bounds__(256)
void mm_ns(const float* __restrict__ A, const float* __restrict__ BT,
           float* __restrict__ Cn, unsigned short* __restrict__ CtB,
           float* __restrict__ CtF, int Ncols, int Mtot, int K,
           long long sA, long long sBT, long long sCn, long long sCt,
           float cN, float aN, float cT, float aT)
{
  const int z = blockIdx.z;
  A  += (size_t)z * sA;
  BT += (size_t)z * sBT;
  __shared__ __align__(16) char smem[32768];
  unsigned short* Ah = (unsigned short*)smem;
  unsigned short* Al = Ah + 4096;
  unsigned short* Bh = Ah + 8192;
  unsigned short* Bl = Ah + 12288;
  const int t = threadIdx.x, lane = t & 63, w = t >> 6;
  const int l15 = lane & 15, g = lane >> 4;
  const int rb = blockIdx.y * 64, cb = blockIdx.x * 64;
  const int wr = w * 16;

  f32x4 acc[4];
  #pragma unroll
  for (int ni = 0; ni < 4; ni++) acc[ni] = (f32x4){0.f, 0.f, 0.f, 0.f};

  for (int k0 = 0; k0 < K; k0 += 64) {
    if (k0) __syncthreads();
    #pragma unroll
    for (int it = 0; it < 4; it++) {
      const int id = it * 256 + t;
      const int row = id >> 4, kq = (id & 15) * 4;
      float4 va = *reinterpret_cast<const float4*>(A + (size_t)(rb + row) * K + k0 + kq);
      const int eo = row * 64 + swz8(row, kq >> 3) * 8 + (kq & 7);
      unsigned short h0 = f2bf(va.x), h1 = f2bf(va.y), h2 = f2bf(va.z), h3 = f2bf(va.w);
      unsigned short lo0 = f2bf(va.x - bf2f(h0)), lo1 = f2bf(va.y - bf2f(h1));
      unsigned short lo2 = f2bf(va.z - bf2f(h2)), lo3 = f2bf(va.w - bf2f(h3));
      *reinterpret_cast<ushort4*>(&Ah[eo]) = make_ushort4(h0, h1, h2, h3);
      *reinterpret_cast<ushort4*>(&Al[eo]) = make_ushort4(lo0, lo1, lo2, lo3);
      float4 vb = *reinterpret_cast<const float4*>(BT + (size_t)(cb + row) * K + k0 + kq);
      unsigned short b0 = f2bf(vb.x), b1 = f2bf(vb.y), b2 = f2bf(vb.z), b3 = f2bf(vb.w);
      unsigned short c0_ = f2bf(vb.x - bf2f(b0)), c1 = f2bf(vb.y - bf2f(b1));
      unsigned short c2 = f2bf(vb.z - bf2f(b2)), c3 = f2bf(vb.w - bf2f(b3));
      *reinterpret_cast<ushort4*>(&Bh[eo]) = make_ushort4(b0, b1, b2, b3);
      *reinterpret_cast<ushort4*>(&Bl[eo]) = make_ushort4(c0_, c1, c2, c3);
    }
    __syncthreads();
    #pragma unroll
    for (int ds = 0; ds < 2; ds++) {
      const int ar = wr + l15;
      bf16x8 ah = *reinterpret_cast<const bf16x8*>(&Ah[ar * 64 + swz8(ar, ds * 4 + g) * 8]);
      bf16x8 al = *reinterpret_cast<const bf16x8*>(&Al[ar * 64 + swz8(ar, ds * 4 + g) * 8]);
      #pragma unroll
      for (int ni = 0; ni < 4; ni++) {
        const int nr = ni * 16 + l15;
        bf16x8 bhf = *reinterpret_cast<const bf16x8*>(&Bh[nr * 64 + swz8(nr, ds * 4 + g) * 8]);
        bf16x8 blf = *reinterpret_cast<const bf16x8*>(&Bl[nr * 64 + swz8(nr, ds * 4 + g) * 8]);
        acc[ni] = __builtin_amdgcn_mfma_f32_16x16x32_bf16(ah, bhf, acc[ni], 0, 0, 0);
        acc[ni] = __builtin_amdgcn_mfma_f32_16x16x32_bf16(ah, blf, acc[ni], 0, 0, 0);
        acc[ni] = __builtin_amdgcn_mfma_f32_16x16x32_bf16(al, bhf, acc[ni], 0, 0, 0);
      }
    }
  }
  __syncthreads();
  float* tb = (float*)smem;   // [64][65]
  #pragma unroll
  for (int ni = 0; ni < 4; ni++)
    #pragma unroll
    for (int r = 0; r < 4; r++)
      tb[(wr + g * 4 + r) * 65 + l15 + ni * 16] = acc[ni][r];
  __syncthreads();
  #pragma unroll
  for (int it = 0; it < 4; it++) {
    const int id = it * 256 + t;
    const int row = id >> 4, q4 = (id & 15) * 4;
    if (WN) {
      float4 o;
      #pragma unroll
      for (int j = 0; j < 4; j++) {
        float v = tb[row * 65 + q4 + j];
        ((float*)&o)[j] = ((rb + row) == (cb + q4 + j) ? cN : 0.f) + aN * v;
      }
      *reinterpret_cast<float4*>(Cn + (size_t)z * sCn + (size_t)(rb + row) * Ncols + cb + q4) = o;
    }
    if (WT) {
      float v[4];
      #pragma unroll
      for (int j = 0; j < 4; j++) {
        float m = tb[(q4 + j) * 65 + row];
        v[j] = ((cb + row) == (rb + q4 + j) ? cT : 0.f) + aT * m;
      }
      if (TBF) {
        ushort4 o = make_ushort4(f2bf(v[0]), f2bf(v[1]), f2bf(v[2]), f2bf(v[3]));
        *reinterpret_cast<ushort4*>(CtB + (size_t)z * sCt + (size_t)(cb + row) * Mtot + rb + q4) = o;
      } else {
        float4 o = make_float4(v[0], v[1], v[2], v[3]);
        *reinterpret_cast<float4*>(CtF + (size_t)z * sCt + (size_t)(cb + row) * Mtot + rb + q4) = o;
      }
    }
  }
}

// ---------------------------------------------------------------------------
// a2_fused: a2 = softmax_rows(ql @ kl^T); writes a2 and a2T (f32).
// grid (4, BH); 256 thr.
// ---------------------------------------------------------------------------
__global__ __launch_bounds__(256)
void a2_fused(const unsigned short* __restrict__ ql, const unsigned short* __restrict__ kl,
              float* __restrict__ a2, float* __restrict__ a2T)
{
  const int bh = blockIdx.y;
  const int t = threadIdx.x, lane = t & 63, w = t >> 6;
  const int l15 = lane & 15, g = lane >> 4;
  const int row0 = blockIdx.x * 64 + w * 16;
  __shared__ float tb[4][16][68];

  bf16x8 af[2];
  #pragma unroll
  for (int ds = 0; ds < 2; ds++)
    af[ds] = *reinterpret_cast<const bf16x8*>(ql + ((size_t)bh * LM + row0 + l15) * 64 + ds * 32 + g * 8);

  f32x4 s[16];
  #pragma unroll
  for (int ni = 0; ni < 16; ni++) s[ni] = (f32x4){0.f, 0.f, 0.f, 0.f};
  #pragma unroll
  for (int ni = 0; ni < 16; ni++)
    #pragma unroll
    for (int ds = 0; ds < 2; ds++) {
      bf16x8 bf = *reinterpret_cast<const bf16x8*>(kl + ((size_t)bh * LM + ni * 16 + l15) * 64 + ds * 32 + g * 8);
      s[ni] = __builtin_amdgcn_mfma_f32_16x16x32_bf16(af[ds], bf, s[ni], 0, 0, 0);
    }
  #pragma unroll
  for (int r = 0; r < 4; r++) {
    float m = -INFINITY;
    #pragma unroll
    for (int ni = 0; ni < 16; ni++) m = fmaxf(m, s[ni][r]);
    #pragma unroll
    for (int msk = 1; msk < 16; msk <<= 1) m = fmaxf(m, __shfl_xor(m, msk));
    float sm = 0.f;
    #pragma unroll
    for (int ni = 0; ni < 16; ni++) { float e = expf(s[ni][r] - m); s[ni][r] = e; sm += e; }
    #pragma unroll
    for (int msk = 1; msk < 16; msk <<= 1) sm += __shfl_xor(sm, msk);
    const float inv = 1.f / sm;
    #pragma unroll
    for (int ni = 0; ni < 16; ni++) s[ni][r] *= inv;
  }
  #pragma unroll
  for (int ni = 0; ni < 16; ni++)
    #pragma unroll
    for (int r = 0; r < 4; r++)
      a2[((size_t)bh << 16) + (size_t)(row0 + g * 4 + r) * 256 + ni * 16 + l15] = s[ni][r];
  // transposed copy, per-wave LDS, 4 column chunks of 64
  for (int c4 = 0; c4 < 4; c4++) {
    #pragma unroll
    for (int ni2 = 0; ni2 < 4; ni2++)
      #pragma unroll
      for (int r = 0; r < 4; r++)
        tb[w][g * 4 + r][ni2 * 16 + l15] = s[c4 * 4 + ni2][r];
    #pragma unroll
    for (int q = 0; q < 4; q++) {
      float4 o;
      #pragma unroll
      for (int j = 0; j < 4; j++) ((float*)&o)[j] = tb[w][q * 4 + j][lane];
      *reinterpret_cast<float4*>(a2T + ((size_t)bh << 16) + (size_t)(c4 * 64 + lane) * 256 + row0 + q * 4) = o;
    }
  }
}

// ---------------------------------------------------------------------------
// flash_a3: a3vT[bh][d][lm] = (softmax_rows(ql @ k^T) @ v)^T, online softmax.
// grid (4, BH).
// ---------------------------------------------------------------------------
__global__ __launch_bounds__(256)
void flash_a3(const unsigned short* __restrict__ ql, const unsigned short* __restrict__ k,
              const unsigned short* __restrict__ v, float* __restrict__ a3vT)
{
  const int bh = blockIdx.y;
  const int lm0 = blockIdx.x * 64;
  const int t = threadIdx.x, lane = t & 63, w = t >> 6;
  const int l15 = lane & 15, g = lane >> 4;
  __shared__ __align__(16) char smem[24576];
  unsigned short* Kl = (unsigned short*)smem;              // [64][64] swizzled
  unsigned short* VT = (unsigned short*)(smem + 8192);     // [64 d][64 p] swizzled
  unsigned short* Pl = (unsigned short*)(smem + 16384);    // per-wave [16][64]

  bf16x8 af[2];
  #pragma unroll
  for (int ds = 0; ds < 2; ds++)
    af[ds] = *reinterpret_cast<const bf16x8*>(ql + ((size_t)bh * LM + lm0 + w * 16 + l15) * 64 + ds * 32 + g * 8);

  f32x4 O[4];
  #pragma unroll
  for (int ni = 0; ni < 4; ni++) O[ni] = (f32x4){0.f, 0.f, 0.f, 0.f};
  float m[4] = {-INFINITY, -INFINITY, -INFINITY, -INFINITY};
  float sd[4] = {0.f, 0.f, 0.f, 0.f};

  for (int kt = 0; kt < NP / 64; kt++) {
    if (kt) __syncthreads();
    #pragma unroll
    for (int it = 0; it < 2; it++) {
      const int id = it * 256 + t;
      const int kp = id >> 3, ch = id & 7;
      int4 kv = *reinterpret_cast<const int4*>(k + ((size_t)bh * NP + kt * 64 + kp) * 64 + ch * 8);
      *reinterpret_cast<int4*>(&Kl[kp * 64 + swz8(kp, ch) * 8]) = kv;
      int4 vv = *reinterpret_cast<const int4*>(v + ((size_t)bh * NP + kt * 64 + kp) * 64 + ch * 8);
      const unsigned short* ps = (const unsigned short*)&vv;
      #pragma unroll
      for (int j = 0; j < 8; j++) {
        const int d = ch * 8 + j;
        VT[d * 64 + swz8(d, kp >> 3) * 8 + (kp & 7)] = ps[j];
      }
    }
    __syncthreads();
    f32x4 s[4];
    #pragma unroll
    for (int ni = 0; ni < 4; ni++) s[ni] = (f32x4){0.f, 0.f, 0.f, 0.f};
    #pragma unroll
    for (int ni = 0; ni < 4; ni++)
      #pragma unroll
      for (int ds = 0; ds < 2; ds++) {
        const int kr = ni * 16 + l15;
        bf16x8 bf = *reinterpret_cast<const bf16x8*>(&Kl[kr * 64 + swz8(kr, ds * 4 + g) * 8]);
        s[ni] = __builtin_amdgcn_mfma_f32_16x16x32_bf16(af[ds], bf, s[ni], 0, 0, 0);
      }
    #pragma unroll
    for (int r = 0; r < 4; r++) {
      float mc = fmaxf(fmaxf(s[0][r], s[1][r]), fmaxf(s[2][r], s[3][r]));
      #pragma unroll
      for (int msk = 1; msk < 16; msk <<= 1) mc = fmaxf(mc, __shfl_xor(mc, msk));
      const float mn = fmaxf(m[r], mc);
      const float sc = expf(m[r] - mn);
      float rs = 0.f;
      #pragma unroll
      for (int ni = 0; ni < 4; ni++) { float e = expf(s[ni][r] - mn); s[ni][r] = e; rs += e; }
      #pragma unroll
      for (int msk = 1; msk < 16; msk <<= 1) rs += __shfl_xor(rs, msk);
      sd[r] = sd[r] * sc + rs;
      m[r] = mn;
      #pragma unroll
      for (int ni = 0; ni < 4; ni++) O[ni][r] *= sc;
    }
    unsigned short* Pw = Pl + w * 1024;
    #pragma unroll
    for (int ni = 0; ni < 4; ni++)
      #pragma unroll
      for (int r = 0; r < 4; r++) {
        const int rowl = g * 4 + r, col = ni * 16 + l15;
        Pw[rowl * 64 + swz8(rowl, col >> 3) * 8 + (col & 7)] = f2bf(s[ni][r]);
      }
    #pragma unroll
    for (int ks = 0; ks < 2; ks++) {
      bf16x8 pa = *reinterpret_cast<const bf16x8*>(&Pw[l15 * 64 + swz8(l15, ks * 4 + g) * 8]);
      #pragma unroll
      for (int ni = 0; ni < 4; ni++) {
        const int d = ni * 16 + l15;
        bf16x8 bv = *reinterpret_cast<const bf16x8*>(&VT[d * 64 + swz8(d, ks * 4 + g) * 8]);
        O[ni] = __builtin_amdgcn_mfma_f32_16x16x32_bf16(pa, bv, O[ni], 0, 0, 0);
      }
    }
  }
  __syncthreads();
  float* tb = (float*)smem;   // per wave [16][68]
  float* tw = tb + w * 16 * 68;
  #pragma unroll
  for (int r = 0; r < 4; r++) {
    const float inv = 1.f / sd[r];
    #pragma unroll
    for (int ni = 0; ni < 4; ni++)
      tw[(g * 4 + r) * 68 + ni * 16 + l15] = O[ni][r] * inv;
  }
  #pragma unroll
  for (int q = 0; q < 4; q++) {
    float4 o;
    #pragma unroll
    for (int j = 0; j < 4; j++) ((float*)&o)[j] = tw[(q * 4 + j) * 68 + lane];
    *reinterpret_cast<float4*>(a3vT + ((size_t)bh * 64 + lane) * 256 + lm0 + w * 16 + q * 4) = o;
  }
}

// ---------------------------------------------------------------------------
// a1_fused: heads = softmax_rows(q @ kl^T) @ W2 + dwconv33(v), bf16 out.
// grid (NP/64, BH).
// ---------------------------------------------------------------------------
__global__ __launch_bounds__(256)
void a1_fused(const unsigned short* __restrict__ q, const unsigned short* __restrict__ kl,
              const unsigned short* __restrict__ W2T, const unsigned short* __restrict__ v,
              const float* __restrict__ resw, unsigned short* __restrict__ heads)
{
  const int bh = blockIdx.y;
  const int p0 = blockIdx.x * 64;
  const int t = threadIdx.x, lane = t & 63, w = t >> 6;
  const int l15 = lane & 15, g = lane >> 4;
  __shared__ __align__(16) unsigned short Pl[4][4096];   // [16][256] swizzled per wave
  __shared__ __align__(16) unsigned short VTc[8192];     // [64 d][96->128 p] swizzled
  __shared__ __align__(16) unsigned short P2[8192];      // [64 r][96->128 k] banded w

  const float* w33 = resw + (bh & 7) * 33;
  for (int i = t; i < 64 * 96; i += 256) {
    const int r = i / 96, kk = i % 96;
    const int d = kk - r;
    const float val = (d >= 0 && d <= 32) ? w33[d] : 0.f;
    P2[r * 128 + swz8(r, kk >> 3) * 8 + (kk & 7)] = f2bf(val);
  }
  #pragma unroll
  for (int it = 0; it < 3; it++) {
    const int id = it * 256 + t;
    const int kp = id >> 3, ch = id & 7;
    const int gp = p0 - 16 + kp;
    int4 vv = make_int4(0, 0, 0, 0);
    if (gp >= 0 && gp < NP)
      vv = *reinterpret_cast<const int4*>(v + ((size_t)bh * NP + gp) * 64 + ch * 8);
    const unsigned short* ps = (const unsigned short*)&vv;
    #pragma unroll
    for (int j = 0; j < 8; j++) {
      const int d = ch * 8 + j;
      VTc[d * 128 + swz8(d, kp >> 3) * 8 + (kp & 7)] = ps[j];
    }
  }
  __syncthreads();

  bf16x8 af[2];
  #pragma unroll
  for (int ds = 0; ds < 2; ds++)
    af[ds] = *reinterpret_cast<const bf16x8*>(q + ((size_t)bh * NP + p0 + w * 16 + l15) * 64 + ds * 32 + g * 8);
  f32x4 s[16];
  #pragma unroll
  for (int ni = 0; ni < 16; ni++) s[ni] = (f32x4){0.f, 0.f, 0.f, 0.f};
  #pragma unroll
  for (int ni = 0; ni < 16; ni++)
    #pragma unroll
    for (int ds = 0; ds < 2; ds++) {
      bf16x8 bf = *reinterpret_cast<const bf16x8*>(kl + ((size_t)bh * LM + ni * 16 + l15) * 64 + ds * 32 + g * 8);
      s[ni] = __builtin_amdgcn_mfma_f32_16x16x32_bf16(af[ds], bf, s[ni], 0, 0, 0);
    }
  #pragma unroll
  for (int r = 0; r < 4; r++) {
    float m = -INFINITY;
    #pragma unroll
    for (int ni = 0; ni < 16; ni++) m = fmaxf(m, s[ni][r]);
    #pragma unroll
    for (int msk = 1; msk < 16; msk <<= 1) m = fmaxf(m, __shfl_xor(m, msk));
    float sm = 0.f;
    #pragma unroll
    for (int ni = 0; ni < 16; ni++) { float e = expf(s[ni][r] - m); s[ni][r] = e; sm += e; }
    #pragma unroll
    for (int msk = 1; msk < 16; msk <<= 1) sm += __shfl_xor(sm, msk);
    const float inv = 1.f / sm;
    #pragma unroll
    for (int ni = 0; ni < 16; ni++) s[ni][r] *= inv;
  }
  unsigned short* Pw = Pl[w];
  #pragma unroll
  for (int ni = 0; ni < 16; ni++)
    #pragma unroll
    for (int r = 0; r < 4; r++) {
      const int rowl = g * 4 + r, col = ni * 16 + l15;
      Pw[rowl * 256 + swz8(rowl, col >> 3) * 8 + (col & 7)] = f2bf(s[ni][r]);
    }
  f32x4 O[4];
  #pragma unroll
  for (int ni = 0; ni < 4; ni++) O[ni] = (f32x4){0.f, 0.f, 0.f, 0.f};
  #pragma unroll
  for (int ks = 0; ks < 8; ks++) {
    bf16x8 pa = *reinterpret_cast<const bf16x8*>(&Pw[l15 * 256 + swz8(l15, ks * 4 + g) * 8]);
    #pragma unroll
    for (int ni = 0; ni < 4; ni++) {
      bf16x8 bf = *reinterpret_cast<const bf16x8*>(
          W2T + ((size_t)bh * 64 + ni * 16 + l15) * 256 + ks * 32 + g * 8);
      O[ni] = __builtin_amdgcn_mfma_f32_16x16x32_bf16(pa, bf, O[ni], 0, 0, 0);
    }
  }
  // depthwise conv as banded-matrix MFMA
  #pragma unroll
  for (int ks = 0; ks < 3; ks++) {
    const int ar = w * 16 + l15;
    bf16x8 pa = *reinterpret_cast<const bf16x8*>(&P2[ar * 128 + swz8(ar, ks * 4 + g) * 8]);
    #pragma unroll
    for (int ni = 0; ni < 4; ni++) {
      const int d = ni * 16 + l15;
      bf16x8 bv = *reinterpret_cast<const bf16x8*>(&VTc[d * 128 + swz8(d, ks * 4 + g) * 8]);
      O[ni] = __builtin_amdgcn_mfma_f32_16x16x32_bf16(pa, bv, O[ni], 0, 0, 0);
    }
  }
  #pragma unroll
  for (int ni = 0; ni < 4; ni++)
    #pragma unroll
    for (int r = 0; r < 4; r++)
      heads[((size_t)bh * NP + p0 + w * 16 + g * 4 + r) * 64 + ni * 16 + l15] = f2bf(O[ni][r]);
}

// ---------------------------------------------------------------------------
__global__ __launch_bounds__(256)
void ln_stats(const float* __restrict__ X, float* __restrict__ stats)
{
  const size_t row = blockIdx.x;
  const float* x = X + row * E;
  const int tid = threadIdx.x;
  float2 v = *reinterpret_cast<const float2*>(x + tid * 2);
  __shared__ float red[256];
  red[tid] = v.x + v.y;
  __syncthreads();
  for (int s = 128; s > 0; s >>= 1) { if (tid < s) red[tid] += red[tid + s]; __syncthreads(); }
  const float mu = red[0] * (1.f / E);
  __syncthreads();
  const float dx = v.x - mu, dy = v.y - mu;
  red[tid] = dx * dx + dy * dy;
  __syncthreads();
  for (int s = 128; s > 0; s >>= 1) { if (tid < s) red[tid] += red[tid + s]; __syncthreads(); }
  if (tid == 0) {
    stats[2 * row]     = mu;
    stats[2 * row + 1] = 1.f / sqrtf(red[0] * (1.f / E) + 1e-5f);
  }
}

__global__ __launch_bounds__(256)
void ln_to_bf16(const float* __restrict__ h, const float* __restrict__ stats,
                const float* __restrict__ g, const float* __restrict__ b,
                unsigned short* __restrict__ xb)
{
  long long idx = (long long)blockIdx.x * 256 + threadIdx.x;
  const long long total = (long long)Bq * N1 * (E / 4);
  if (idx >= total) return;
  const int e4 = (int)(idx % (E / 4));
  const long long row = idx / (E / 4);
  float4 hx = reinterpret_cast<const float4*>(h)[idx];
  const float mu = stats[2 * row], inv = stats[2 * row + 1];
  float4 gg = reinterpret_cast<const float4*>(g)[e4];
  float4 bb = reinterpret_cast<const float4*>(b)[e4];
  ushort4 o;
  o.x = f2bf((hx.x - mu) * inv * gg.x + bb.x);
  o.y = f2bf((hx.y - mu) * inv * gg.y + bb.y);
  o.z = f2bf((hx.z - mu) * inv * gg.z + bb.z);
  o.w = f2bf((hx.w - mu) * inv * gg.w + bb.w);
  reinterpret_cast<ushort4*>(xb)[idx] = o;
}

__global__ void fill_cls_wrap(const float* __restrict__ cls, float* __restrict__ h)
{
  int idx = blockIdx.x * 256 + threadIdx.x;
  const int total = Bq * 85 * (E / 4);
  if (idx >= total) return;
  const int e4 = idx % (E / 4);
  int t = idx / (E / 4);
  const int rr = t % 85;
  const int b = t / 85;
  float4* H = reinterpret_cast<float4*>(h);
  if (rr == 0) {
    H[((size_t)b * N1) * (E / 4) + e4] = reinterpret_cast<const float4*>(cls)[e4];
  } else {
    const int i = rr - 1;
    H[((size_t)b * N1 + 1 + N0 + i) * (E / 4) + e4] =
        H[((size_t)b * N1 + 1 + i) * (E / 4) + e4];
  }
}

__global__ __launch_bounds__(256)
void landmark_mean(const float* __restrict__ h, const float* __restrict__ stats,
                   const float* __restrict__ g, const float* __restrict__ bta,
                   unsigned short* __restrict__ xl)
{
  const int bm = blockIdx.x;
  const int b = bm / LM, i = bm % LM;
  const int tid = threadIdx.x;
  float2 acc = make_float2(0.f, 0.f);
  float cnt = 0.f;
  for (int j = 0; j < LCH; j++) {
    const int real = i * LCH + j - PADS;
    if (real < 0) continue;
    const size_t row = (size_t)b * N1 + real;
    float2 hv = *reinterpret_cast<const float2*>(h + row * E + tid * 2);
    const float mu = stats[2 * row], inv = stats[2 * row + 1];
    acc.x += (hv.x - mu) * inv;
    acc.y += (hv.y - mu) * inv;
    cnt += 1.f;
  }
  float2 gg = *reinterpret_cast<const float2*>(g + tid * 2);
  float2 bb = *reinterpret_cast<const float2*>(bta + tid * 2);
  ushort2 o;
  o.x = f2bf((gg.x * acc.x + bb.x * cnt) * (1.f / LCH));
  o.y = f2bf((gg.y * acc.y + bb.y * cnt) * (1.f / LCH));
  *reinterpret_cast<ushort2*>(xl + (size_t)bm * E + tid * 2) = o;
}

__global__ void zero_pad_rows(unsigned short* __restrict__ q, unsigned short* __restrict__ k,
                              unsigned short* __restrict__ v)
{
  const int idx = blockIdx.x * 256 + threadIdx.x;
  const int total = BH * PADS * DH;
  if (idx >= total) return;
  const int d = idx % DH;
  int t = idx / DH;
  const int p = t % PADS;
  const int bh = t / PADS;
  const size_t o = ((size_t)bh * NP + p) * DH + d;
  q[o] = 0; k[o] = 0; v[o] = 0;
}

__global__ void scatter_qk_l(const float* __restrict__ qkvf, unsigned short* __restrict__ ql,
                             unsigned short* __restrict__ kl)
{
  int idx = blockIdx.x * 256 + threadIdx.x;
  const int total = Bq * LM * (1024 / 4);
  if (idx >= total) return;
  const int c4 = idx % 256;
  int t = idx / 256;
  const int i = t % LM;
  const int b = t / LM;
  const int c = c4 * 4;
  const int wch = c >> 9;
  const int hd = (c >> 6) & 7;
  float4 val = reinterpret_cast<const float4*>(qkvf)[idx];
  if (wch == 0) { val.x *= 0.125f; val.y *= 0.125f; val.z *= 0.125f; val.w *= 0.125f; }
  unsigned short* dst = (wch == 0) ? ql : kl;
  ushort4 o = make_ushort4(f2bf(val.x), f2bf(val.y), f2bf(val.z), f2bf(val.w));
  *reinterpret_cast<ushort4*>(dst + (((size_t)(b * NH + hd)) * LM + i) * 64 + (c & 63)) = o;
}

__global__ void init_gmax(unsigned int* g) { if (threadIdx.x < 2) g[threadIdx.x] = 0u; }

__global__ __launch_bounds__(256)
void colrow_max(const float* __restrict__ a2, unsigned int* __restrict__ gmax)
{
  const float* a = a2 + (size_t)blockIdx.x * LM * LM;
  const int tid = threadIdx.x;
  float rowsum = 0.f, colsum = 0.f;
  for (int j = 0; j < LM; j++) rowsum += a[(size_t)tid * LM + j];
  for (int i = 0; i < LM; i++) colsum += a[(size_t)i * LM + tid];
  __shared__ float r1[256], r2[256];
  r1[tid] = rowsum; r2[tid] = colsum;
  __syncthreads();
  for (int s = 128; s > 0; s >>= 1) {
    if (tid < s) { r1[tid] = fmaxf(r1[tid], r1[tid + s]); r2[tid] = fmaxf(r2[tid], r2[tid + s]); }
    __syncthreads();
  }
  if (tid == 0) {
    atomicMax(&gmax[0], __float_as_uint(r1[0]));
    atomicMax(&gmax[1], __float_as_uint(r2[0]));
  }
}

__global__ void pinv_init2(const float* __restrict__ a2, const float* __restrict__ a2T,
                           const unsigned int* __restrict__ gmax,
                           float* __restrict__ zA, float* __restrict__ zAT)
{
  long long idx = (long long)blockIdx.x * 256 + threadIdx.x;
  const long long total = (long long)BH * LM * LM;
  if (idx >= total) return;
  const float inv = 1.f / (__uint_as_float(gmax[0]) * __uint_as_float(gmax[1]));
  zA[idx]  = a2T[idx] * inv;
  zAT[idx] = a2[idx] * inv;
}

// LAST-attention: only cls row (p=PADS) needed
__global__ __launch_bounds__(256)
void last_row_attn(const unsigned short* __restrict__ q, const unsigned short* __restrict__ kl,
                   const unsigned short* __restrict__ W2T, const unsigned short* __restrict__ v,
                   const float* __restrict__ resw, float* __restrict__ hb)
{
  const int bh = blockIdx.x;
  const int tid = threadIdx.x;
  __shared__ float qrow[DH];
  __shared__ float p[LM];
  __shared__ float red[256];
  if (tid < DH) qrow[tid] = bf2f(q[((size_t)bh * NP + PADS) * DH + tid]);
  __syncthreads();
  const unsigned short* krow = kl + ((size_t)bh * LM + tid) * DH;
  float s = 0.f;
  for (int d = 0; d < DH; d++) s = fmaf(qrow[d], bf2f(krow[d]), s);
  red[tid] = s;
  __syncthreads();
  for (int st = 128; st > 0; st >>= 1) { if (tid < st) red[tid] = fmaxf(red[tid], red[tid + st]); __syncthreads(); }
  const float m = red[0];
  __syncthreads();
  const float e = expf(s - m);
  red[tid] = e;
  __syncthreads();
  for (int st = 128; st > 0; st >>= 1) { if (tid < st) red[tid] += red[tid + st]; __syncthreads(); }
  p[tid] = e / red[0];
  __syncthreads();
  if (tid < DH) {
    const unsigned short* w2r = W2T + ((size_t)bh * 64 + tid) * 256;
    float acc = 0.f;
    for (int j = 0; j < LM; j++) acc = fmaf(p[j], bf2f(w2r[j]), acc);
    const float* wt = resw + (bh % NH) * 33;
    const unsigned short* vb = v + (size_t)bh * NP * DH;
    #pragma unroll
    for (int t2 = 0; t2 < 33; t2++)
      acc = fmaf(wt[t2], bf2f(vb[(size_t)(PADS - 16 + t2) * DH + tid]), acc);
    hb[bh * DH + tid] = acc;
  }
}

__global__ __launch_bounds__(256)
void last_outproj(const float* __restrict__ hb, const float* __restrict__ outw,
                  const float* __restrict__ outb, float* __restrict__ h)
{
  const int b = blockIdx.x;
  const int tid = threadIdx.x;
  __shared__ float cat[E];
  for (int c = tid; c < E; c += 256) cat[c] = hb[(b * NH + (c >> 6)) * DH + (c & 63)];
  __syncthreads();
  for (int e = tid; e < E; e += 256) {
    float acc = outb[e];
    for (int c = 0; c < E; c++) acc = fmaf(cat[c], outw[(size_t)c * E + e], acc);
    h[(size_t)b * N1 * E + e] += acc;
  }
}

// ---------------------------------------------------------------------------
// PPEG (unchanged from round 3)
// ---------------------------------------------------------------------------
__global__ __launch_bounds__(256)
void transpose_h2p(const float* __restrict__ h, float* __restrict__ ht)
{
  __shared__ float T[32][33];
  const int tx = threadIdx.x & 31, ty = threadIdx.x >> 5;
  const int px0 = blockIdx.x * 32, e0 = blockIdx.y * 32, b = blockIdx.z;
  #pragma unroll
  for (int i = 0; i < 4; i++) {
    const int pix = px0 + ty + i * 8;
    if (pix < HWp)
      T[ty + i * 8][tx] = h[((size_t)b * N1 + 1 + pix) * E + e0 + tx];
  }
  __syncthreads();
  #pragma unroll
  for (int i = 0; i < 4; i++) {
    const int pix = px0 + tx;
    if (pix < HWp)
      ht[((size_t)b * E + e0 + ty + i * 8) * HWp + pix] = T[tx][ty + i * 8];
  }
}

__global__ __launch_bounds__(256)
void transpose_p2h(const float* __restrict__ ht, float* __restrict__ h)
{
  __shared__ float T[32][33];
  const int tx = threadIdx.x & 31, ty = threadIdx.x >> 5;
  const int px0 = blockIdx.x * 32, e0 = blockIdx.y * 32, b = blockIdx.z;
  #pragma unroll
  for (int i = 0; i < 4; i++) {
    const int pix = px0 + tx;
    if (pix < HWp)
      T[ty + i * 8][tx] = ht[((size_t)b * E + e0 + ty + i * 8) * HWp + pix];
  }
  __syncthreads();
  #pragma unroll
  for (int i = 0; i < 4; i++) {
    const int pix = px0 + ty + i * 8;
    if (pix < HWp)
      h[((size_t)b * N1 + 1 + pix) * E + e0 + tx] = T[tx][ty + i * 8];
  }
}

__global__ __launch_bounds__(256)
void ppeg_plane(float* __restrict__ ht,
                const float* __restrict__ w7, const float* __restrict__ b7,
                const float* __restrict__ w5, const float* __restrict__ b5,
                const float* __restrict__ w3, const float* __restrict__ b3)
{
  __shared__ float S[84][88];
  __shared__ float Wl[84];
  const int t = threadIdx.x;
  const int e = blockIdx.x & (E - 1);
  float* plane = ht + (size_t)blockIdx.x * HWp;

  for (int i = t; i < 84 * 88; i += 256) (&S[0][0])[i] = 0.f;
  if (t < 49) Wl[t] = w7[(size_t)e * 49 + t];
  else if (t >= 64 && t < 89) Wl[49 + t - 64] = w5[(size_t)e * 25 + t - 64];
  else if (t >= 96 && t < 105) Wl[74 + t - 96] = w3[(size_t)e * 9 + t - 96];
  __syncthreads();
  for (int i = t; i < HWp; i += 256) S[3 + i / HH][3 + i % HH] = plane[i];
  const float bsum = b7[e] + b5[e] + b3[e];
  __syncthreads();

  float res[7][4];
  int it = 0;
  for (int gidx = t; gidx < 1560; gidx += 256, ++it) {
    const int y = gidx / 20, x0 = (gidx % 20) * 4;
    float a0 = bsum + S[y + 3][x0 + 3];
    float a1 = bsum + S[y + 3][x0 + 4];
    float a2v = bsum + S[y + 3][x0 + 5];
    float a3 = bsum + S[y + 3][x0 + 6];
    #pragma unroll
    for (int dy = -3; dy <= 3; dy++) {
      const int row = y + 3 + dy;
      float win[10];
      #pragma unroll
      for (int m = 0; m < 10; m++) win[m] = S[row][x0 + m];
      const int ky7 = dy + 3;
      #pragma unroll
      for (int kx = 0; kx < 7; kx++) {
        const float c = Wl[ky7 * 7 + kx];
        a0 = fmaf(c, win[kx + 0], a0);
        a1 = fmaf(c, win[kx + 1], a1);
        a2v = fmaf(c, win[kx + 2], a2v);
        a3 = fmaf(c, win[kx + 3], a3);
      }
      if (dy >= -2 && dy <= 2) {
        const int ky5 = dy + 2;
        #pragma unroll
        for (int kx = 0; kx < 5; kx++) {
          const float c = Wl[49 + ky5 * 5 + kx];
          a0 = fmaf(c, win[kx + 1], a0);
          a1 = fmaf(c, win[kx + 2], a1);
          a2v = fmaf(c, win[kx + 3], a2v);
          a3 = fmaf(c, win[kx + 4], a3);
        }
      }
      if (dy >= -1 && dy <= 1) {
        const int ky3 = dy + 1;
        #pragma unroll
        for (int kx = 0; kx < 3; kx++) {
          const float c = Wl[74 + ky3 * 3 + kx];
          a0 = fmaf(c, win[kx + 2], a0);
          a1 = fmaf(c, win[kx + 3], a1);
          a2v = fmaf(c, win[kx + 4], a2v);
          a3 = fmaf(c, win[kx + 5], a3);
        }
      }
    }
    res[it][0] = a0; res[it][1] = a1; res[it][2] = a2v; res[it][3] = a3;
  }
  __syncthreads();
  it = 0;
  for (int gidx = t; gidx < 1560; gidx += 256, ++it) {
    const int y = gidx / 20, x0 = (gidx % 20) * 4;
    #pragma unroll
    for (int j = 0; j < 4; j++)
      if (x0 + j < HH) plane[y * HH + x0 + j] = res[it][j];
  }
}

__global__ __launch_bounds__(256)
void final_head(const float* __restrict__ h, const float* __restrict__ g,
                const float* __restrict__ bb, const float* __restrict__ w2,
                const float* __restrict__ b2, float* __restrict__ out)
{
  const int b = blockIdx.x;
  const int tid = threadIdx.x;
  const float* x = h + (size_t)b * N1 * E;
  float2 v = *reinterpret_cast<const float2*>(x + tid * 2);
  __shared__ float red[256];
  red[tid] = v.x + v.y;
  __syncthreads();
  for (int st = 128; st > 0; st >>= 1) { if (tid < st) red[tid] += red[tid + st]; __syncthreads(); }
  const float mu = red[0] * (1.f / E);
  __syncthreads();
  const float dx = v.x - mu, dy = v.y - mu;
  red[tid] = dx * dx + dy * dy;
  __syncthreads();
  for (int st = 128; st > 0; st >>= 1) { if (tid < st) red[tid] += red[tid + st]; __syncthreads(); }
  const float inv = 1.f / sqrtf(red[0] * (1.f / E) + 1e-5f);
  __shared__ float hn[E];
  float2 gg = *reinterpret_cast<const float2*>(g + tid * 2);
  float2 bv = *reinterpret_cast<const float2*>(bb + tid * 2);
  hn[tid * 2]     = dx * inv * gg.x + bv.x;
  hn[tid * 2 + 1] = dy * inv * gg.y + bv.y;
  __syncthreads();
  __shared__ float lg[4];
  if (tid < 4) {
    float a = b2[tid];
    for (int e = 0; e < E; e++) a = fmaf(hn[e], w2[e * 4 + tid], a);
    lg[tid] = a;
  }
  __syncthreads();
  if (tid == 0) {
    int best = 0;
    float bvv = lg[0];
    for (int j = 1; j < 4; j++) if (lg[j] > bvv) { bvv = lg[j]; best = j; }
    float S = 1.f;
    for (int j = 0; j < 4; j++) {
      const float hz = 1.f / (1.f + expf(-lg[j]));
      out[b * 4 + j] = hz;
      S *= (1.f - hz);
      out[16 + b * 4 + j] = S;
    }
    out[32 + b] = (float)best;
  }
}

__global__ void write_sentinel(float* out) { if (threadIdx.x < 36) out[threadIdx.x] = -777.f; }

// ---------------------------------------------------------------------------
struct Ws {
  unsigned short *q, *k, *v, *ql, *kl, *xl, *W2T;
  unsigned short *fc1T, *qkv1T, *qkv2T, *out1T;
  float *h, *pool, *a3vT, *qkvl, *stats;
  unsigned int* gmax;
};

constexpr long long MM = (long long)BH * LM * LM;   // 2,097,152

static void run_attention(hipStream_t stream, Ws& w,
                          const float* lng, const float* lnb, const unsigned short* qkvT,
                          const unsigned short* outT, const float* outb, const float* resw,
                          bool last)
{
  const dim3 blk(256);
  float* a2   = w.pool;
  float* a2T  = w.pool + MM;
  float* zA   = w.pool + 2 * MM;
  float* zAT  = w.pool + 3 * MM;
  float* zB   = w.pool + 4 * MM;
  float* zBT  = w.pool + 5 * MM;
  float* Y    = w.pool + 6 * MM;
  float* P1T  = w.pool + 7 * MM;
  float* P2T  = w.pool + 8 * MM;
  float* P3T  = w.pool + 9 * MM;
  unsigned short* xb    = (unsigned short*)w.pool;          // aliases a2..zA (dead before a2 write)
  unsigned short* heads = (unsigned short*)(w.pool + 6 * MM); // aliases Y..P2T (dead after NS)
  float* hb = w.qkvl;                                        // qkvl dead after scatter

  ln_stats<<<Bq * N1, blk, 0, stream>>>(w.h, w.stats);
  ln_to_bf16<<<gblocks_i((long long)Bq * N1 * (E / 4)), blk, 0, stream>>>(w.h, w.stats, lng, lnb, xb);
  landmark_mean<<<Bq * LM, blk, 0, stream>>>(w.h, w.stats, lng, lnb, w.xl);
  mgemm<3, 2, false, false, true><<<dim3(QKV / 128, (Bq * N1 + 127) / 128), blk, 0, stream>>>(
      xb, qkvT, nullptr, nullptr, w.q, w.k, w.v, nullptr, Bq * N1, QKV, E);
  zero_pad_rows<<<gblocks_i((long long)BH * PADS * DH), blk, 0, stream>>>(w.q, w.k, w.v);
  mgemm<3, 0, false, false, false><<<dim3(8, 8), blk, 0, stream>>>(
      w.xl, qkvT, nullptr, w.qkvl, nullptr, nullptr, nullptr, nullptr, Bq * LM, 1024, E);
  scatter_qk_l<<<gblocks_i((long long)Bq * LM * 256), blk, 0, stream>>>(w.qkvl, w.ql, w.kl);

  a2_fused<<<dim3(4, BH), blk, 0, stream>>>(w.ql, w.kl, a2, a2T);
  init_gmax<<<1, 64, 0, stream>>>(w.gmax);
  colrow_max<<<BH, blk, 0, stream>>>(a2, w.gmax);
  pinv_init2<<<gblocks_i(MM), blk, 0, stream>>>(a2, a2T, w.gmax, zA, zAT);

  float *zc = zA, *zcT = zAT, *zo = zB, *zoT = zBT;
  const long long sM = (long long)LM * LM;
  for (int it = 0; it < 6; ++it) {
    mm_ns<true, true, false><<<dim3(4, 4, BH), blk, 0, stream>>>(
        a2, zcT, Y, nullptr, P1T, 256, 256, 256, sM, sM, sM, sM, 0.f, 1.f, 7.f, -1.f);
    mm_ns<false, true, false><<<dim3(4, 4, BH), blk, 0, stream>>>(
        Y, P1T, nullptr, nullptr, P2T, 256, 256, 256, sM, sM, sM, sM, 0.f, 0.f, 15.f, -1.f);
    mm_ns<false, true, false><<<dim3(4, 4, BH), blk, 0, stream>>>(
        Y, P2T, nullptr, nullptr, P3T, 256, 256, 256, sM, sM, sM, sM, 0.f, 0.f, 13.f, -1.f);
    mm_ns<true, true, false><<<dim3(4, 4, BH), blk, 0, stream>>>(
        zc, P3T, zo, nullptr, zoT, 256, 256, 256, sM, sM, sM, sM, 0.f, 0.25f, 0.f, 0.25f);
    float* t1 = zc; zc = zo; zo = t1;
    float* t2 = zcT; zcT = zoT; zoT = t2;
  }
  // after 6 iters zc == zA

  flash_a3<<<dim3(4, BH), blk, 0, stream>>>(w.ql, w.k, w.v, w.a3vT);
  mm_ns<false, true, true><<<dim3(1, 4, BH), blk, 0, stream>>>(
      zc, w.a3vT, nullptr, w.W2T, nullptr, 64, 256, 256, sM, 64 * 256, 0, 64 * 256,
      0.f, 0.f, 0.f, 1.f);

  if (!last) {
    a1_fused<<<dim3(NP / 64, BH), blk, 0, stream>>>(w.q, w.kl, w.W2T, w.v, resw, heads);
    mgemm<4, 3, true, false, true><<<dim3(E / 128, (Bq * N1 + 127) / 128), blk, 0, stream>>>(
        nullptr, outT, outb, w.h, nullptr, nullptr, nullptr, heads, Bq * N1, E, E);
  } else {
    last_row_attn<<<BH, blk, 0, stream>>>(w.q, w.kl, w.W2T, w.v, resw, hb);
  }
}

}  // namespace

extern "C" void kernel_launch(void* const* d_in, const int* in_sizes, int n_in,
                              void* d_out, int out_size, void* d_ws, size_t ws_size,
                              hipStream_t stream)
{
  const float* x_path   = (const float*)d_in[0];
  const float* fc1_w    = (const float*)d_in[1];
  const float* fc1_b    = (const float*)d_in[2];
  const float* cls_tok  = (const float*)d_in[3];
  const float* ln1_g    = (const float*)d_in[4];
  const float* ln1_b    = (const float*)d_in[5];
  const float* qkv1_w   = (const float*)d_in[6];
  const float* out1_w   = (const float*)d_in[7];
  const float* out1_b   = (const float*)d_in[8];
  const float* res1_w   = (const float*)d_in[9];
  const float* ln2_g    = (const float*)d_in[10];
  const float* ln2_b    = (const float*)d_in[11];
  const float* qkv2_w   = (const float*)d_in[12];
  const float* out2_w   = (const float*)d_in[13];
  const float* out2_b   = (const float*)d_in[14];
  const float* res2_w   = (const float*)d_in[15];
  const float* conv7_w  = (const float*)d_in[16];
  const float* conv7_b  = (const float*)d_in[17];
  const float* conv5_w  = (const float*)d_in[18];
  const float* conv5_b  = (const float*)d_in[19];
  const float* conv3_w  = (const float*)d_in[20];
  const float* conv3_b  = (const float*)d_in[21];
  const float* norm_g   = (const float*)d_in[22];
  const float* norm_b   = (const float*)d_in[23];
  const float* fc2_w    = (const float*)d_in[24];
  const float* fc2_b    = (const float*)d_in[25];
  (void)in_sizes; (void)n_in; (void)out_size;

  float* W = (float*)d_ws;
  size_t off = 0;
  auto take = [&](size_t n) -> float* {
    float* p = W + off;
    off += (n + 255) & ~(size_t)255;
    return p;
  };

  Ws w;
  w.q     = (unsigned short*)take((size_t)BH * NP * DH / 2);
  w.k     = (unsigned short*)take((size_t)BH * NP * DH / 2);
  w.v     = (unsigned short*)take((size_t)BH * NP * DH / 2);
  w.h     = take((size_t)Bq * N1 * E);
  w.pool  = take((size_t)10 * MM);
  w.a3vT  = take((size_t)BH * DH * LM);
  w.W2T   = (unsigned short*)take((size_t)BH * DH * LM / 2);
  w.ql    = (unsigned short*)take((size_t)BH * LM * DH / 2);
  w.kl    = (unsigned short*)take((size_t)BH * LM * DH / 2);
  w.xl    = (unsigned short*)take((size_t)Bq * LM * E / 2);
  w.qkvl  = take((size_t)Bq * LM * 1024);
  w.stats = take((size_t)2 * Bq * N1);
  w.fc1T  = (unsigned short*)take((size_t)E * KIN / 2);
  w.qkv1T = (unsigned short*)take((size_t)QKV * E / 2);
  w.qkv2T = (unsigned short*)take((size_t)QKV * E / 2);
  w.out1T = (unsigned short*)take((size_t)E * E / 2);
  w.gmax  = (unsigned int*)take(64);

  if (ws_size < off * sizeof(float)) {
    write_sentinel<<<1, 64, 0, stream>>>((float*)d_out);
    return;
  }

  const dim3 blk(256);

  wcvt_t<<<dim3(E / 32, KIN / 32), blk, 0, stream>>>(fc1_w, w.fc1T, KIN, E);
  wcvt_t<<<dim3(QKV / 32, E / 32), blk, 0, stream>>>(qkv1_w, w.qkv1T, E, QKV);
  wcvt_t<<<dim3(QKV / 32, E / 32), blk, 0, stream>>>(qkv2_w, w.qkv2T, E, QKV);
  wcvt_t<<<dim3(E / 32, E / 32), blk, 0, stream>>>(out1_w, w.out1T, E, E);

  mgemm<0, 1, true, true, true><<<dim3(E / 128, (Bq * N0 + 127) / 128), blk, 0, stream>>>(
      x_path, w.fc1T, fc1_b, w.h, nullptr, nullptr, nullptr, nullptr, Bq * N0, E, KIN);
  fill_cls_wrap<<<gblocks_i((long long)Bq * 85 * (E / 4)), blk, 0, stream>>>(cls_tok, w.h);

  run_attention(stream, w, ln1_g, ln1_b, w.qkv1T, w.out1T, out1_b, res1_w, false);

  {
    float* planes = w.pool;   // NS buffers dead between attentions
    transpose_h2p<<<dim3((HWp + 31) / 32, E / 32, Bq), blk, 0, stream>>>(w.h, planes);
    ppeg_plane<<<Bq * E, blk, 0, stream>>>(planes, conv7_w, conv7_b, conv5_w, conv5_b,
                                           conv3_w, conv3_b);
    transpose_p2h<<<dim3((HWp + 31) / 32, E / 32, Bq), blk, 0, stream>>>(planes, w.h);
  }

  run_attention(stream, w, ln2_g, ln2_b, w.qkv2T, nullptr, out2_b, res2_w, true);
  last_outproj<<<Bq, blk, 0, stream>>>(w.qkvl, out2_w, out2_b, w.h);

  final_head<<<Bq, blk, 0, stream>>>(w.h, norm_g, norm_b, fc2_w, fc2_b, (float*)d_out);
}

// Round 5
// 1930.528 us; speedup vs baseline: 4.0032x; 1.1789x over previous
//
#include <hip/hip_runtime.h>
#include <math.h>

namespace {

constexpr int Bq   = 4;
constexpr int N0   = 6000;
constexpr int KIN  = 1024;
constexpr int E    = 512;
constexpr int HH   = 78;
constexpr int HWp  = 6084;
constexpr int N1   = 6085;        // 1 + HWp
constexpr int NH   = 8;
constexpr int DH   = 64;
constexpr int LM   = 256;
constexpr int NP   = 6144;
constexpr int LCH  = 24;
constexpr int PADS = 59;
constexpr int BH   = Bq * NH;     // 32
constexpr int QKV  = 3 * E;
constexpr int NSPL = 8;           // flash split-K factor

typedef __attribute__((ext_vector_type(8))) short bf16x8;
typedef __attribute__((ext_vector_type(4))) float f32x4;

__host__ __device__ inline int gblocks_i(long long n) { return (int)((n + 255) / 256); }

__device__ inline unsigned short f2bf(float x) {
  unsigned u = __float_as_uint(x);
  u += 0x7FFFu + ((u >> 16) & 1u);
  return (unsigned short)(u >> 16);
}
__device__ inline float bf2f(unsigned short s) {
  return __uint_as_float(((unsigned)s) << 16);
}
// LDS chunk swizzle: 8-bf16 (16B) chunks XORed by row bits -> bank-balanced
__device__ inline int swz8(int row, int chunk) {
  return chunk ^ (row & 7) ^ ((row >> 3) & 7);
}
// XCD-bijective flat-grid swizzle (m204): contiguous nid chunks per XCD
__device__ inline int xcd_swz(int flat, int nwg) {
  const int q8 = nwg >> 3, r8 = nwg & 7;
  const int xcd = flat & 7, pos = flat >> 3;
  return (xcd < r8 ? xcd * (q8 + 1) : r8 * (q8 + 1) + (xcd - r8) * q8) + pos;
}

// ---------------------------------------------------------------------------
// weight transpose + f32->bf16: in[K][N] -> out[N][K]
// ---------------------------------------------------------------------------
__global__ __launch_bounds__(256)
void wcvt_t(const float* __restrict__ in, unsigned short* __restrict__ out, int K, int N)
{
  __shared__ float T[32][33];
  const int tx = threadIdx.x & 31, ty = threadIdx.x >> 5;
  const int n0 = blockIdx.x * 32, k0 = blockIdx.y * 32;
  #pragma unroll
  for (int i = 0; i < 4; i++)
    T[ty + i * 8][tx] = in[(size_t)(k0 + ty + i * 8) * N + n0 + tx];
  __syncthreads();
  #pragma unroll
  for (int i = 0; i < 4; i++)
    out[(size_t)(n0 + ty + i * 8) * K + k0 + tx] = f2bf(T[tx][ty + i * 8]);
}

// ---------------------------------------------------------------------------
// mgemm: C[M,N] = A[M,K] @ B[K,N], bf16 MFMA, B pre-transposed bf16 [N][K].
// 128x128 tile, BK=32, 256 thr (2x2 waves of 64x64), 16x16x32 MFMA.
// ASRC: 0 f32 A; 3 bf16 A; 4 bf16 gather from heads layout.
// STORE: 0 f32 C; 1 shift (fc1->h rows); 2 bf16 scatter qkv; 3 f32 accum.
// ---------------------------------------------------------------------------
template<int ASRC, int STORE, bool BIAS, bool RELU, bool SWIZ>
__global__ __launch_bounds__(256)
void mgemm(const void* __restrict__ Av, const unsigned short* __restrict__ Bt,
           const float* __restrict__ bias, float* __restrict__ C,
           unsigned short* __restrict__ qp, unsigned short* __restrict__ kp,
           unsigned short* __restrict__ vp, const unsigned short* __restrict__ Ag,
           int Mrows, int N, int K)
{
  __shared__ __align__(16) short As[128 * 40];
  __shared__ __align__(16) short Bs[128 * 40];
  const int t = threadIdx.x;
  const int lane = t & 63;
  const int l16 = lane & 15, g = lane >> 4;
  const int wave = t >> 6;
  const int wr = (wave >> 1) * 64, wc = (wave & 1) * 64;

  int bx = blockIdx.x, by = blockIdx.y;
  if (SWIZ) {
    const int gx = gridDim.x;
    const int nid = xcd_swz(by * gx + bx, gx * gridDim.y);
    bx = nid % gx; by = nid / gx;
  }
  const int rowBase = by * 128, colBase = bx * 128;

  f32x4 acc[4][4];
  #pragma unroll
  for (int mi = 0; mi < 4; mi++)
    #pragma unroll
    for (int ni = 0; ni < 4; ni++) acc[mi][ni] = (f32x4){0.f, 0.f, 0.f, 0.f};

  for (int k0 = 0; k0 < K; k0 += 32) {
    if (ASRC == 0) {
      const float* A = (const float*)Av;
      #pragma unroll
      for (int i = 0; i < 4; i++) {
        const int id = i * 256 + t;
        const int row = id >> 3, kq = id & 7;
        const int r = rowBase + row;
        float4 va = make_float4(0.f, 0.f, 0.f, 0.f);
        if (r < Mrows)
          va = *reinterpret_cast<const float4*>(A + (size_t)r * K + k0 + kq * 4);
        const unsigned lo = (unsigned)f2bf(va.x) | ((unsigned)f2bf(va.y) << 16);
        const unsigned hi = (unsigned)f2bf(va.z) | ((unsigned)f2bf(va.w) << 16);
        *reinterpret_cast<uint2*>(&As[row * 40 + kq * 4]) = make_uint2(lo, hi);
      }
    } else {
      #pragma unroll
      for (int i = 0; i < 2; i++) {
        const int id = i * 256 + t;
        const int row = id >> 2, c8 = id & 3;
        const int r = rowBase + row;
        int4 va = make_int4(0, 0, 0, 0);
        if (r < Mrows) {
          const int kk = k0 + c8 * 8;
          if (ASRC == 4) {
            const int b = r / N1, rr2 = r % N1;
            va = *reinterpret_cast<const int4*>(
                Ag + (((size_t)(b * NH + (kk >> 6))) * NP + PADS + rr2) * DH + (kk & 63));
          } else {
            va = *reinterpret_cast<const int4*>(((const unsigned short*)Av) + (size_t)r * K + kk);
          }
        }
        *reinterpret_cast<int4*>(&As[row * 40 + c8 * 8]) = va;
      }
    }
    #pragma unroll
    for (int i = 0; i < 2; i++) {
      const int id = i * 256 + t;
      const int row = id >> 2, g8 = id & 3;
      int4 vb = *reinterpret_cast<const int4*>(Bt + (size_t)(colBase + row) * K + k0 + g8 * 8);
      *reinterpret_cast<int4*>(&Bs[row * 40 + g8 * 8]) = vb;
    }
    __syncthreads();
    bf16x8 af[4], bf[4];
    #pragma unroll
    for (int mi = 0; mi < 4; mi++)
      af[mi] = *reinterpret_cast<const bf16x8*>(&As[(wr + mi * 16 + l16) * 40 + g * 8]);
    #pragma unroll
    for (int ni = 0; ni < 4; ni++)
      bf[ni] = *reinterpret_cast<const bf16x8*>(&Bs[(wc + ni * 16 + l16) * 40 + g * 8]);
    #pragma unroll
    for (int mi = 0; mi < 4; mi++)
      #pragma unroll
      for (int ni = 0; ni < 4; ni++)
        acc[mi][ni] = __builtin_amdgcn_mfma_f32_16x16x32_bf16(af[mi], bf[ni], acc[mi][ni], 0, 0, 0);
    __syncthreads();
  }

  #pragma unroll
  for (int mi = 0; mi < 4; mi++) {
    #pragma unroll
    for (int ni = 0; ni < 4; ni++) {
      #pragma unroll
      for (int r4 = 0; r4 < 4; r4++) {
        const int row = rowBase + wr + mi * 16 + g * 4 + r4;
        if (row >= Mrows) continue;
        const int col = colBase + wc + ni * 16 + l16;
        float v = acc[mi][ni][r4];
        if (BIAS) v += bias[col];
        if (RELU) v = fmaxf(v, 0.f);
        if (STORE == 2) {
          const int b   = row / N1;
          const int p   = (row % N1) + PADS;
          const int wch = col >> 9;
          const int hd  = (col >> 6) & 7;
          const int d   = col & 63;
          float vv = (wch == 0) ? v * 0.125f : v;
          unsigned short* dst = (wch == 0) ? qp : (wch == 1) ? kp : vp;
          dst[(((size_t)(b * NH + hd)) * NP + p) * DH + d] = f2bf(vv);
        } else if (STORE == 1) {
          C[((size_t)(row / N0) * N1 + 1 + (row % N0)) * N + col] = v;
        } else if (STORE == 3) {
          C[(size_t)row * N + col] += v;
        } else {
          C[(size_t)row * N + col] = v;
        }
      }
    }
  }
}

// ---------------------------------------------------------------------------
// mm_ns: batched M = A[256xK] @ B[KxN] via BT bf16-split MFMA (3-term hi/lo).
// Writes (optionally) Cn = cN*I + aN*M  and  Ct = cT*I + aT*M^T (f32 or bf16).
// grid (Ncols/64, 4, batch), XCD-swizzled. K mult of 64.
// ---------------------------------------------------------------------------
template<bool WN, bool WT, bool TBF>
__global__ __launch_bounds__(256)
void mm_ns(const float* __restrict__ A, const float* __restrict__ BT,
           float* __restrict__ Cn, unsigned short* __restrict__ CtB,
           float* __restrict__ CtF, int Ncols, int Mtot, int K,
           long long sA, long long sBT, long long sCn, long long sCt,
           float cN, float aN, float cT, float aT)
{
  int bx = blockIdx.x, by = blockIdx.y, bz = blockIdx.z;
  {
    const int gx = gridDim.x, gy = gridDim.y;
    int nid = xcd_swz((bz * gy + by) * gx + bx, gx * gy * gridDim.z);
    bx = nid % gx; nid /= gx; by = nid % gy; bz = nid / gy;
  }
  A  += (size_t)bz * sA;
  BT += (size_t)bz * sBT;
  __shared__ __align__(16) char smem[32768];
  unsigned short* Ah = (unsigned short*)smem;
  unsigned short* Al = Ah + 4096;
  unsigned short* Bh = Ah + 8192;
  unsigned short* Bl = Ah + 12288;
  const int t = threadIdx.x, lane = t & 63, w = t >> 6;
  const int l15 = lane & 15, g = lane >> 4;
  const int rb = by * 64, cb = bx * 64;
  const int wr = w * 16;

  f32x4 acc[4];
  #pragma unroll
  for (int ni = 0; ni < 4; ni++) acc[ni] = (f32x4){0.f, 0.f, 0.f, 0.f};

  for (int k0 = 0; k0 < K; k0 += 64) {
    if (k0) __syncthreads();
    #pragma unroll
    for (int it = 0; it < 4; it++) {
      const int id = it * 256 + t;
      const int row = id >> 4, kq = (id & 15) * 4;
      float4 va = *reinterpret_cast<const float4*>(A + (size_t)(rb + row) * K + k0 + kq);
      const int eo = row * 64 + swz8(row, kq >> 3) * 8 + (kq & 7);
      unsigned short h0 = f2bf(va.x), h1 = f2bf(va.y), h2 = f2bf(va.z), h3 = f2bf(va.w);
      unsigned short lo0 = f2bf(va.x - bf2f(h0)), lo1 = f2bf(va.y - bf2f(h1));
      unsigned short lo2 = f2bf(va.z - bf2f(h2)), lo3 = f2bf(va.w - bf2f(h3));
      *reinterpret_cast<ushort4*>(&Ah[eo]) = make_ushort4(h0, h1, h2, h3);
      *reinterpret_cast<ushort4*>(&Al[eo]) = make_ushort4(lo0, lo1, lo2, lo3);
      float4 vb = *reinterpret_cast<const float4*>(BT + (size_t)(cb + row) * K + k0 + kq);
      unsigned short b0 = f2bf(vb.x), b1 = f2bf(vb.y), b2 = f2bf(vb.z), b3 = f2bf(vb.w);
      unsigned short c0_ = f2bf(vb.x - bf2f(b0)), c1 = f2bf(vb.y - bf2f(b1));
      unsigned short c2 = f2bf(vb.z - bf2f(b2)), c3 = f2bf(vb.w - bf2f(b3));
      *reinterpret_cast<ushort4*>(&Bh[eo]) = make_ushort4(b0, b1, b2, b3);
      *reinterpret_cast<ushort4*>(&Bl[eo]) = make_ushort4(c0_, c1, c2, c3);
    }
    __syncthreads();
    #pragma unroll
    for (int ds = 0; ds < 2; ds++) {
      const int ar = wr + l15;
      bf16x8 ah = *reinterpret_cast<const bf16x8*>(&Ah[ar * 64 + swz8(ar, ds * 4 + g) * 8]);
      bf16x8 al = *reinterpret_cast<const bf16x8*>(&Al[ar * 64 + swz8(ar, ds * 4 + g) * 8]);
      #pragma unroll
      for (int ni = 0; ni < 4; ni++) {
        const int nr = ni * 16 + l15;
        bf16x8 bhf = *reinterpret_cast<const bf16x8*>(&Bh[nr * 64 + swz8(nr, ds * 4 + g) * 8]);
        bf16x8 blf = *reinterpret_cast<const bf16x8*>(&Bl[nr * 64 + swz8(nr, ds * 4 + g) * 8]);
        acc[ni] = __builtin_amdgcn_mfma_f32_16x16x32_bf16(ah, bhf, acc[ni], 0, 0, 0);
        acc[ni] = __builtin_amdgcn_mfma_f32_16x16x32_bf16(ah, blf, acc[ni], 0, 0, 0);
        acc[ni] = __builtin_amdgcn_mfma_f32_16x16x32_bf16(al, bhf, acc[ni], 0, 0, 0);
      }
    }
  }
  __syncthreads();
  float* tb = (float*)smem;   // [64][65]
  #pragma unroll
  for (int ni = 0; ni < 4; ni++)
    #pragma unroll
    for (int r = 0; r < 4; r++)
      tb[(wr + g * 4 + r) * 65 + l15 + ni * 16] = acc[ni][r];
  __syncthreads();
  #pragma unroll
  for (int it = 0; it < 4; it++) {
    const int id = it * 256 + t;
    const int row = id >> 4, q4 = (id & 15) * 4;
    if (WN) {
      float4 o;
      #pragma unroll
      for (int j = 0; j < 4; j++) {
        float v = tb[row * 65 + q4 + j];
        ((float*)&o)[j] = ((rb + row) == (cb + q4 + j) ? cN : 0.f) + aN * v;
      }
      *reinterpret_cast<float4*>(Cn + (size_t)bz * sCn + (size_t)(rb + row) * Ncols + cb + q4) = o;
    }
    if (WT) {
      float v[4];
      #pragma unroll
      for (int j = 0; j < 4; j++) {
        float m = tb[(q4 + j) * 65 + row];
        v[j] = ((cb + row) == (rb + q4 + j) ? cT : 0.f) + aT * m;
      }
      if (TBF) {
        ushort4 o = make_ushort4(f2bf(v[0]), f2bf(v[1]), f2bf(v[2]), f2bf(v[3]));
        *reinterpret_cast<ushort4*>(CtB + (size_t)bz * sCt + (size_t)(cb + row) * Mtot + rb + q4) = o;
      } else {
        float4 o = make_float4(v[0], v[1], v[2], v[3]);
        *reinterpret_cast<float4*>(CtF + (size_t)bz * sCt + (size_t)(cb + row) * Mtot + rb + q4) = o;
      }
    }
  }
}

// ---------------------------------------------------------------------------
// a2_fused: a2 = softmax_rows(ql @ kl^T); writes a2 and a2T (f32).
// ---------------------------------------------------------------------------
__global__ __launch_bounds__(256)
void a2_fused(const unsigned short* __restrict__ ql, const unsigned short* __restrict__ kl,
              float* __restrict__ a2, float* __restrict__ a2T)
{
  const int bh = blockIdx.y;
  const int t = threadIdx.x, lane = t & 63, w = t >> 6;
  const int l15 = lane & 15, g = lane >> 4;
  const int row0 = blockIdx.x * 64 + w * 16;
  __shared__ float tb[4][16][68];

  bf16x8 af[2];
  #pragma unroll
  for (int ds = 0; ds < 2; ds++)
    af[ds] = *reinterpret_cast<const bf16x8*>(ql + ((size_t)bh * LM + row0 + l15) * 64 + ds * 32 + g * 8);

  f32x4 s[16];
  #pragma unroll
  for (int ni = 0; ni < 16; ni++) s[ni] = (f32x4){0.f, 0.f, 0.f, 0.f};
  #pragma unroll
  for (int ni = 0; ni < 16; ni++)
    #pragma unroll
    for (int ds = 0; ds < 2; ds++) {
      bf16x8 bf = *reinterpret_cast<const bf16x8*>(kl + ((size_t)bh * LM + ni * 16 + l15) * 64 + ds * 32 + g * 8);
      s[ni] = __builtin_amdgcn_mfma_f32_16x16x32_bf16(af[ds], bf, s[ni], 0, 0, 0);
    }
  #pragma unroll
  for (int r = 0; r < 4; r++) {
    float m = -INFINITY;
    #pragma unroll
    for (int ni = 0; ni < 16; ni++) m = fmaxf(m, s[ni][r]);
    #pragma unroll
    for (int msk = 1; msk < 16; msk <<= 1) m = fmaxf(m, __shfl_xor(m, msk));
    float sm = 0.f;
    #pragma unroll
    for (int ni = 0; ni < 16; ni++) { float e = expf(s[ni][r] - m); s[ni][r] = e; sm += e; }
    #pragma unroll
    for (int msk = 1; msk < 16; msk <<= 1) sm += __shfl_xor(sm, msk);
    const float inv = 1.f / sm;
    #pragma unroll
    for (int ni = 0; ni < 16; ni++) s[ni][r] *= inv;
  }
  #pragma unroll
  for (int ni = 0; ni < 16; ni++)
    #pragma unroll
    for (int r = 0; r < 4; r++)
      a2[((size_t)bh << 16) + (size_t)(row0 + g * 4 + r) * 256 + ni * 16 + l15] = s[ni][r];
  for (int c4 = 0; c4 < 4; c4++) {
    #pragma unroll
    for (int ni2 = 0; ni2 < 4; ni2++)
      #pragma unroll
      for (int r = 0; r < 4; r++)
        tb[w][g * 4 + r][ni2 * 16 + l15] = s[c4 * 4 + ni2][r];
    #pragma unroll
    for (int q = 0; q < 4; q++) {
      float4 o;
      #pragma unroll
      for (int j = 0; j < 4; j++) ((float*)&o)[j] = tb[w][q * 4 + j][lane];
      *reinterpret_cast<float4*>(a2T + ((size_t)bh << 16) + (size_t)(c4 * 64 + lane) * 256 + row0 + q * 4) = o;
    }
  }
}

// ---------------------------------------------------------------------------
// flash_a3_split: partial (O, m, l) for K-split s; grid (4, NSPL, BH) swizzled.
// Opart[bh][s][256][64] f32 (unnormalized); msd[bh][s][256][2] = {m, sumexp}.
// ---------------------------------------------------------------------------
__global__ __launch_bounds__(256)
void flash_a3_split(const unsigned short* __restrict__ ql, const unsigned short* __restrict__ k,
                    const unsigned short* __restrict__ v, float* __restrict__ Opart,
                    float* __restrict__ msd)
{
  int bx = blockIdx.x, by = blockIdx.y, bz = blockIdx.z;
  {
    const int gx = gridDim.x, gy = gridDim.y;
    int nid = xcd_swz((bz * gy + by) * gx + bx, gx * gy * gridDim.z);
    bx = nid % gx; nid /= gx; by = nid % gy; bz = nid / gy;
  }
  const int bh = bz, sp = by, lm0 = bx * 64;
  const int t = threadIdx.x, lane = t & 63, w = t >> 6;
  const int l15 = lane & 15, g = lane >> 4;
  __shared__ __align__(16) char smem[24576];
  unsigned short* Kl = (unsigned short*)smem;
  unsigned short* VT = (unsigned short*)(smem + 8192);
  unsigned short* Pl = (unsigned short*)(smem + 16384);

  bf16x8 af[2];
  #pragma unroll
  for (int ds = 0; ds < 2; ds++)
    af[ds] = *reinterpret_cast<const bf16x8*>(ql + ((size_t)bh * LM + lm0 + w * 16 + l15) * 64 + ds * 32 + g * 8);

  f32x4 O[4];
  #pragma unroll
  for (int ni = 0; ni < 4; ni++) O[ni] = (f32x4){0.f, 0.f, 0.f, 0.f};
  float m[4] = {-INFINITY, -INFINITY, -INFINITY, -INFINITY};
  float sd[4] = {0.f, 0.f, 0.f, 0.f};

  const int kt0 = sp * (NP / 64 / NSPL), kt1 = kt0 + NP / 64 / NSPL;
  for (int kt = kt0; kt < kt1; kt++) {
    if (kt != kt0) __syncthreads();
    #pragma unroll
    for (int it = 0; it < 2; it++) {
      const int id = it * 256 + t;
      const int kp = id >> 3, ch = id & 7;
      int4 kv = *reinterpret_cast<const int4*>(k + ((size_t)bh * NP + kt * 64 + kp) * 64 + ch * 8);
      *reinterpret_cast<int4*>(&Kl[kp * 64 + swz8(kp, ch) * 8]) = kv;
      int4 vv = *reinterpret_cast<const int4*>(v + ((size_t)bh * NP + kt * 64 + kp) * 64 + ch * 8);
      const unsigned short* ps = (const unsigned short*)&vv;
      #pragma unroll
      for (int j = 0; j < 8; j++) {
        const int d = ch * 8 + j;
        VT[d * 64 + swz8(d, kp >> 3) * 8 + (kp & 7)] = ps[j];
      }
    }
    __syncthreads();
    f32x4 s[4];
    #pragma unroll
    for (int ni = 0; ni < 4; ni++) s[ni] = (f32x4){0.f, 0.f, 0.f, 0.f};
    #pragma unroll
    for (int ni = 0; ni < 4; ni++)
      #pragma unroll
      for (int ds = 0; ds < 2; ds++) {
        const int kr = ni * 16 + l15;
        bf16x8 bf = *reinterpret_cast<const bf16x8*>(&Kl[kr * 64 + swz8(kr, ds * 4 + g) * 8]);
        s[ni] = __builtin_amdgcn_mfma_f32_16x16x32_bf16(af[ds], bf, s[ni], 0, 0, 0);
      }
    #pragma unroll
    for (int r = 0; r < 4; r++) {
      float mc = fmaxf(fmaxf(s[0][r], s[1][r]), fmaxf(s[2][r], s[3][r]));
      #pragma unroll
      for (int msk = 1; msk < 16; msk <<= 1) mc = fmaxf(mc, __shfl_xor(mc, msk));
      const float mn = fmaxf(m[r], mc);
      const float sc = expf(m[r] - mn);
      float rs = 0.f;
      #pragma unroll
      for (int ni = 0; ni < 4; ni++) { float e = expf(s[ni][r] - mn); s[ni][r] = e; rs += e; }
      #pragma unroll
      for (int msk = 1; msk < 16; msk <<= 1) rs += __shfl_xor(rs, msk);
      sd[r] = sd[r] * sc + rs;
      m[r] = mn;
      #pragma unroll
      for (int ni = 0; ni < 4; ni++) O[ni][r] *= sc;
    }
    unsigned short* Pw = Pl + w * 1024;
    #pragma unroll
    for (int ni = 0; ni < 4; ni++)
      #pragma unroll
      for (int r = 0; r < 4; r++) {
        const int rowl = g * 4 + r, col = ni * 16 + l15;
        Pw[rowl * 64 + swz8(rowl, col >> 3) * 8 + (col & 7)] = f2bf(s[ni][r]);
      }
    #pragma unroll
    for (int ks = 0; ks < 2; ks++) {
      bf16x8 pa = *reinterpret_cast<const bf16x8*>(&Pw[l15 * 64 + swz8(l15, ks * 4 + g) * 8]);
      #pragma unroll
      for (int ni = 0; ni < 4; ni++) {
        const int d = ni * 16 + l15;
        bf16x8 bv = *reinterpret_cast<const bf16x8*>(&VT[d * 64 + swz8(d, ks * 4 + g) * 8]);
        O[ni] = __builtin_amdgcn_mfma_f32_16x16x32_bf16(pa, bv, O[ni], 0, 0, 0);
      }
    }
  }
  // write partials (unnormalized)
  #pragma unroll
  for (int r = 0; r < 4; r++) {
    const int row = lm0 + w * 16 + g * 4 + r;
    const size_t base = ((size_t)(bh * NSPL + sp) * LM + row);
    #pragma unroll
    for (int ni = 0; ni < 4; ni++)
      Opart[base * 64 + ni * 16 + l15] = O[ni][r];
    if (l15 == 0) {
      msd[base * 2]     = m[r];
      msd[base * 2 + 1] = sd[r];
    }
  }
}

// merge: a3vT[bh][d][lm] = (sum_s e^{m_s-M} O_s) / (sum_s e^{m_s-M} l_s), transposed
__global__ __launch_bounds__(256)
void flash_a3_merge(const float* __restrict__ Opart, const float* __restrict__ msd,
                    float* __restrict__ a3vT)
{
  const int bh = blockIdx.y, lm0 = blockIdx.x * 64;
  const int t = threadIdx.x;
  const int r = t >> 2, dg = t & 3;
  const int row = lm0 + r;
  float m8[NSPL], w8[NSPL];
  float M = -INFINITY;
  #pragma unroll
  for (int s = 0; s < NSPL; s++) {
    m8[s] = msd[((size_t)(bh * NSPL + s) * LM + row) * 2];
    M = fmaxf(M, m8[s]);
  }
  float S = 0.f;
  #pragma unroll
  for (int s = 0; s < NSPL; s++) {
    const float e = expf(m8[s] - M);
    w8[s] = e;
    S += msd[((size_t)(bh * NSPL + s) * LM + row) * 2 + 1] * e;
  }
  const float invS = 1.f / S;
  float acc[16];
  #pragma unroll
  for (int j = 0; j < 16; j++) acc[j] = 0.f;
  #pragma unroll
  for (int s = 0; s < NSPL; s++) {
    const float* op = Opart + ((size_t)(bh * NSPL + s) * LM + row) * 64 + dg * 16;
    #pragma unroll
    for (int j = 0; j < 16; j++) acc[j] = fmaf(w8[s], op[j], acc[j]);
  }
  __shared__ float Tl[64][65];
  #pragma unroll
  for (int j = 0; j < 16; j++) Tl[dg * 16 + j][r] = acc[j] * invS;
  __syncthreads();
  const int d = t >> 2, q4 = t & 3;
  #pragma unroll
  for (int j = 0; j < 4; j++) {
    const int c0 = q4 * 16 + j * 4;
    float4 o = make_float4(Tl[d][c0], Tl[d][c0 + 1], Tl[d][c0 + 2], Tl[d][c0 + 3]);
    *reinterpret_cast<float4*>(a3vT + ((size_t)bh * 64 + d) * 256 + lm0 + c0) = o;
  }
}

// ---------------------------------------------------------------------------
// a1_fused: heads = softmax_rows(q @ kl^T) @ W2 + dwconv33(v), bf16 out.
// ---------------------------------------------------------------------------
__global__ __launch_bounds__(256)
void a1_fused(const unsigned short* __restrict__ q, const unsigned short* __restrict__ kl,
              const unsigned short* __restrict__ W2T, const unsigned short* __restrict__ v,
              const float* __restrict__ resw, unsigned short* __restrict__ heads)
{
  const int bh = blockIdx.y;
  const int p0 = blockIdx.x * 64;
  const int t = threadIdx.x, lane = t & 63, w = t >> 6;
  const int l15 = lane & 15, g = lane >> 4;
  __shared__ __align__(16) unsigned short Pl[4][4096];
  __shared__ __align__(16) unsigned short VTc[8192];
  __shared__ __align__(16) unsigned short P2[8192];

  const float* w33 = resw + (bh & 7) * 33;
  for (int i = t; i < 64 * 96; i += 256) {
    const int r = i / 96, kk = i % 96;
    const int d = kk - r;
    const float val = (d >= 0 && d <= 32) ? w33[d] : 0.f;
    P2[r * 128 + swz8(r, kk >> 3) * 8 + (kk & 7)] = f2bf(val);
  }
  #pragma unroll
  for (int it = 0; it < 3; it++) {
    const int id = it * 256 + t;
    const int kp = id >> 3, ch = id & 7;
    const int gp = p0 - 16 + kp;
    int4 vv = make_int4(0, 0, 0, 0);
    if (gp >= 0 && gp < NP)
      vv = *reinterpret_cast<const int4*>(v + ((size_t)bh * NP + gp) * 64 + ch * 8);
    const unsigned short* ps = (const unsigned short*)&vv;
    #pragma unroll
    for (int j = 0; j < 8; j++) {
      const int d = ch * 8 + j;
      VTc[d * 128 + swz8(d, kp >> 3) * 8 + (kp & 7)] = ps[j];
    }
  }
  __syncthreads();

  bf16x8 af[2];
  #pragma unroll
  for (int ds = 0; ds < 2; ds++)
    af[ds] = *reinterpret_cast<const bf16x8*>(q + ((size_t)bh * NP + p0 + w * 16 + l15) * 64 + ds * 32 + g * 8);
  f32x4 s[16];
  #pragma unroll
  for (int ni = 0; ni < 16; ni++) s[ni] = (f32x4){0.f, 0.f, 0.f, 0.f};
  #pragma unroll
  for (int ni = 0; ni < 16; ni++)
    #pragma unroll
    for (int ds = 0; ds < 2; ds++) {
      bf16x8 bf = *reinterpret_cast<const bf16x8*>(kl + ((size_t)bh * LM + ni * 16 + l15) * 64 + ds * 32 + g * 8);
      s[ni] = __builtin_amdgcn_mfma_f32_16x16x32_bf16(af[ds], bf, s[ni], 0, 0, 0);
    }
  #pragma unroll
  for (int r = 0; r < 4; r++) {
    float m = -INFINITY;
    #pragma unroll
    for (int ni = 0; ni < 16; ni++) m = fmaxf(m, s[ni][r]);
    #pragma unroll
    for (int msk = 1; msk < 16; msk <<= 1) m = fmaxf(m, __shfl_xor(m, msk));
    float sm = 0.f;
    #pragma unroll
    for (int ni = 0; ni < 16; ni++) { float e = expf(s[ni][r] - m); s[ni][r] = e; sm += e; }
    #pragma unroll
    for (int msk = 1; msk < 16; msk <<= 1) sm += __shfl_xor(sm, msk);
    const float inv = 1.f / sm;
    #pragma unroll
    for (int ni = 0; ni < 16; ni++) s[ni][r] *= inv;
  }
  unsigned short* Pw = Pl[w];
  #pragma unroll
  for (int ni = 0; ni < 16; ni++)
    #pragma unroll
    for (int r = 0; r < 4; r++) {
      const int rowl = g * 4 + r, col = ni * 16 + l15;
      Pw[rowl * 256 + swz8(rowl, col >> 3) * 8 + (col & 7)] = f2bf(s[ni][r]);
    }
  f32x4 O[4];
  #pragma unroll
  for (int ni = 0; ni < 4; ni++) O[ni] = (f32x4){0.f, 0.f, 0.f, 0.f};
  #pragma unroll
  for (int ks = 0; ks < 8; ks++) {
    bf16x8 pa = *reinterpret_cast<const bf16x8*>(&Pw[l15 * 256 + swz8(l15, ks * 4 + g) * 8]);
    #pragma unroll
    for (int ni = 0; ni < 4; ni++) {
      bf16x8 bf = *reinterpret_cast<const bf16x8*>(
          W2T + ((size_t)bh * 64 + ni * 16 + l15) * 256 + ks * 32 + g * 8);
      O[ni] = __builtin_amdgcn_mfma_f32_16x16x32_bf16(pa, bf, O[ni], 0, 0, 0);
    }
  }
  #pragma unroll
  for (int ks = 0; ks < 3; ks++) {
    const int ar = w * 16 + l15;
    bf16x8 pa = *reinterpret_cast<const bf16x8*>(&P2[ar * 128 + swz8(ar, ks * 4 + g) * 8]);
    #pragma unroll
    for (int ni = 0; ni < 4; ni++) {
      const int d = ni * 16 + l15;
      bf16x8 bv = *reinterpret_cast<const bf16x8*>(&VTc[d * 128 + swz8(d, ks * 4 + g) * 8]);
      O[ni] = __builtin_amdgcn_mfma_f32_16x16x32_bf16(pa, bv, O[ni], 0, 0, 0);
    }
  }
  #pragma unroll
  for (int ni = 0; ni < 4; ni++)
    #pragma unroll
    for (int r = 0; r < 4; r++)
      heads[((size_t)bh * NP + p0 + w * 16 + g * 4 + r) * 64 + ni * 16 + l15] = f2bf(O[ni][r]);
}

// ---------------------------------------------------------------------------
__global__ __launch_bounds__(256)
void ln_stats(const float* __restrict__ X, float* __restrict__ stats)
{
  const size_t row = blockIdx.x;
  const float* x = X + row * E;
  const int tid = threadIdx.x;
  float2 v = *reinterpret_cast<const float2*>(x + tid * 2);
  __shared__ float red[256];
  red[tid] = v.x + v.y;
  __syncthreads();
  for (int s = 128; s > 0; s >>= 1) { if (tid < s) red[tid] += red[tid + s]; __syncthreads(); }
  const float mu = red[0] * (1.f / E);
  __syncthreads();
  const float dx = v.x - mu, dy = v.y - mu;
  red[tid] = dx * dx + dy * dy;
  __syncthreads();
  for (int s = 128; s > 0; s >>= 1) { if (tid < s) red[tid] += red[tid + s]; __syncthreads(); }
  if (tid == 0) {
    stats[2 * row]     = mu;
    stats[2 * row + 1] = 1.f / sqrtf(red[0] * (1.f / E) + 1e-5f);
  }
}

__global__ __launch_bounds__(256)
void ln_to_bf16(const float* __restrict__ h, const float* __restrict__ stats,
                const float* __restrict__ g, const float* __restrict__ b,
                unsigned short* __restrict__ xb)
{
  long long idx = (long long)blockIdx.x * 256 + threadIdx.x;
  const long long total = (long long)Bq * N1 * (E / 4);
  if (idx >= total) return;
  const int e4 = (int)(idx % (E / 4));
  const long long row = idx / (E / 4);
  float4 hx = reinterpret_cast<const float4*>(h)[idx];
  const float mu = stats[2 * row], inv = stats[2 * row + 1];
  float4 gg = reinterpret_cast<const float4*>(g)[e4];
  float4 bb = reinterpret_cast<const float4*>(b)[e4];
  ushort4 o;
  o.x = f2bf((hx.x - mu) * inv * gg.x + bb.x);
  o.y = f2bf((hx.y - mu) * inv * gg.y + bb.y);
  o.z = f2bf((hx.z - mu) * inv * gg.z + bb.z);
  o.w = f2bf((hx.w - mu) * inv * gg.w + bb.w);
  reinterpret_cast<ushort4*>(xb)[idx] = o;
}

__global__ void fill_cls_wrap(const float* __restrict__ cls, float* __restrict__ h)
{
  int idx = blockIdx.x * 256 + threadIdx.x;
  const int total = Bq * 85 * (E / 4);
  if (idx >= total) return;
  const int e4 = idx % (E / 4);
  int t = idx / (E / 4);
  const int rr = t % 85;
  const int b = t / 85;
  float4* H = reinterpret_cast<float4*>(h);
  if (rr == 0) {
    H[((size_t)b * N1) * (E / 4) + e4] = reinterpret_cast<const float4*>(cls)[e4];
  } else {
    const int i = rr - 1;
    H[((size_t)b * N1 + 1 + N0 + i) * (E / 4) + e4] =
        H[((size_t)b * N1 + 1 + i) * (E / 4) + e4];
  }
}

__global__ __launch_bounds__(256)
void landmark_mean(const float* __restrict__ h, const float* __restrict__ stats,
                   const float* __restrict__ g, const float* __restrict__ bta,
                   unsigned short* __restrict__ xl)
{
  const int bm = blockIdx.x;
  const int b = bm / LM, i = bm % LM;
  const int tid = threadIdx.x;
  float2 acc = make_float2(0.f, 0.f);
  float cnt = 0.f;
  for (int j = 0; j < LCH; j++) {
    const int real = i * LCH + j - PADS;
    if (real < 0) continue;
    const size_t row = (size_t)b * N1 + real;
    float2 hv = *reinterpret_cast<const float2*>(h + row * E + tid * 2);
    const float mu = stats[2 * row], inv = stats[2 * row + 1];
    acc.x += (hv.x - mu) * inv;
    acc.y += (hv.y - mu) * inv;
    cnt += 1.f;
  }
  float2 gg = *reinterpret_cast<const float2*>(g + tid * 2);
  float2 bb = *reinterpret_cast<const float2*>(bta + tid * 2);
  ushort2 o;
  o.x = f2bf((gg.x * acc.x + bb.x * cnt) * (1.f / LCH));
  o.y = f2bf((gg.y * acc.y + bb.y * cnt) * (1.f / LCH));
  *reinterpret_cast<ushort2*>(xl + (size_t)bm * E + tid * 2) = o;
}

__global__ void zero_pad_rows(unsigned short* __restrict__ q, unsigned short* __restrict__ k,
                              unsigned short* __restrict__ v)
{
  const int idx = blockIdx.x * 256 + threadIdx.x;
  const int total = BH * PADS * DH;
  if (idx >= total) return;
  const int d = idx % DH;
  int t = idx / DH;
  const int p = t % PADS;
  const int bh = t / PADS;
  const size_t o = ((size_t)bh * NP + p) * DH + d;
  q[o] = 0; k[o] = 0; v[o] = 0;
}

__global__ void scatter_qk_l(const float* __restrict__ qkvf, unsigned short* __restrict__ ql,
                             unsigned short* __restrict__ kl)
{
  int idx = blockIdx.x * 256 + threadIdx.x;
  const int total = Bq * LM * (1024 / 4);
  if (idx >= total) return;
  const int c4 = idx % 256;
  int t = idx / 256;
  const int i = t % LM;
  const int b = t / LM;
  const int c = c4 * 4;
  const int wch = c >> 9;
  const int hd = (c >> 6) & 7;
  float4 val = reinterpret_cast<const float4*>(qkvf)[idx];
  if (wch == 0) { val.x *= 0.125f; val.y *= 0.125f; val.z *= 0.125f; val.w *= 0.125f; }
  unsigned short* dst = (wch == 0) ? ql : kl;
  ushort4 o = make_ushort4(f2bf(val.x), f2bf(val.y), f2bf(val.z), f2bf(val.w));
  *reinterpret_cast<ushort4*>(dst + (((size_t)(b * NH + hd)) * LM + i) * 64 + (c & 63)) = o;
}

__global__ void init_gmax(unsigned int* g) { if (threadIdx.x < 2) g[threadIdx.x] = 0u; }

__global__ __launch_bounds__(256)
void colrow_max(const float* __restrict__ a2, unsigned int* __restrict__ gmax)
{
  const float* a = a2 + (size_t)blockIdx.x * LM * LM;
  const int tid = threadIdx.x;
  float rowsum = 0.f, colsum = 0.f;
  for (int j = 0; j < LM; j++) rowsum += a[(size_t)tid * LM + j];
  for (int i = 0; i < LM; i++) colsum += a[(size_t)i * LM + tid];
  __shared__ float r1[256], r2[256];
  r1[tid] = rowsum; r2[tid] = colsum;
  __syncthreads();
  for (int s = 128; s > 0; s >>= 1) {
    if (tid < s) { r1[tid] = fmaxf(r1[tid], r1[tid + s]); r2[tid] = fmaxf(r2[tid], r2[tid + s]); }
    __syncthreads();
  }
  if (tid == 0) {
    atomicMax(&gmax[0], __float_as_uint(r1[0]));
    atomicMax(&gmax[1], __float_as_uint(r2[0]));
  }
}

__global__ void pinv_init2(const float* __restrict__ a2, const float* __restrict__ a2T,
                           const unsigned int* __restrict__ gmax,
                           float* __restrict__ zA, float* __restrict__ zAT)
{
  long long idx = (long long)blockIdx.x * 256 + threadIdx.x;
  const long long total = (long long)BH * LM * LM;
  if (idx >= total) return;
  const float inv = 1.f / (__uint_as_float(gmax[0]) * __uint_as_float(gmax[1]));
  zA[idx]  = a2T[idx] * inv;
  zAT[idx] = a2[idx] * inv;
}

// LAST-attention: only cls row (p=PADS) needed
__global__ __launch_bounds__(256)
void last_row_attn(const unsigned short* __restrict__ q, const unsigned short* __restrict__ kl,
                   const unsigned short* __restrict__ W2T, const unsigned short* __restrict__ v,
                   const float* __restrict__ resw, float* __restrict__ hb)
{
  const int bh = blockIdx.x;
  const int tid = threadIdx.x;
  __shared__ float qrow[DH];
  __shared__ float p[LM];
  __shared__ float red[256];
  if (tid < DH) qrow[tid] = bf2f(q[((size_t)bh * NP + PADS) * DH + tid]);
  __syncthreads();
  const unsigned short* krow = kl + ((size_t)bh * LM + tid) * DH;
  float s = 0.f;
  for (int d = 0; d < DH; d++) s = fmaf(qrow[d], bf2f(krow[d]), s);
  red[tid] = s;
  __syncthreads();
  for (int st = 128; st > 0; st >>= 1) { if (tid < st) red[tid] = fmaxf(red[tid], red[tid + st]); __syncthreads(); }
  const float m = red[0];
  __syncthreads();
  const float e = expf(s - m);
  red[tid] = e;
  __syncthreads();
  for (int st = 128; st > 0; st >>= 1) { if (tid < st) red[tid] += red[tid + st]; __syncthreads(); }
  p[tid] = e / red[0];
  __syncthreads();
  if (tid < DH) {
    const unsigned short* w2r = W2T + ((size_t)bh * 64 + tid) * 256;
    float acc = 0.f;
    for (int j = 0; j < LM; j++) acc = fmaf(p[j], bf2f(w2r[j]), acc);
    const float* wt = resw + (bh % NH) * 33;
    const unsigned short* vb = v + (size_t)bh * NP * DH;
    #pragma unroll
    for (int t2 = 0; t2 < 33; t2++)
      acc = fmaf(wt[t2], bf2f(vb[(size_t)(PADS - 16 + t2) * DH + tid]), acc);
    hb[bh * DH + tid] = acc;
  }
}

__global__ __launch_bounds__(256)
void last_outproj(const float* __restrict__ hb, const float* __restrict__ outw,
                  const float* __restrict__ outb, float* __restrict__ h)
{
  const int b = blockIdx.x;
  const int tid = threadIdx.x;
  __shared__ float cat[E];
  for (int c = tid; c < E; c += 256) cat[c] = hb[(b * NH + (c >> 6)) * DH + (c & 63)];
  __syncthreads();
  for (int e = tid; e < E; e += 256) {
    float acc = outb[e];
    for (int c = 0; c < E; c++) acc = fmaf(cat[c], outw[(size_t)c * E + e], acc);
    h[(size_t)b * N1 * E + e] += acc;
  }
}

// ---------------------------------------------------------------------------
// PPEG
// ---------------------------------------------------------------------------
__global__ __launch_bounds__(256)
void transpose_h2p(const float* __restrict__ h, float* __restrict__ ht)
{
  __shared__ float T[32][33];
  const int tx = threadIdx.x & 31, ty = threadIdx.x >> 5;
  const int px0 = blockIdx.x * 32, e0 = blockIdx.y * 32, b = blockIdx.z;
  #pragma unroll
  for (int i = 0; i < 4; i++) {
    const int pix = px0 + ty + i * 8;
    if (pix < HWp)
      T[ty + i * 8][tx] = h[((size_t)b * N1 + 1 + pix) * E + e0 + tx];
  }
  __syncthreads();
  #pragma unroll
  for (int i = 0; i < 4; i++) {
    const int pix = px0 + tx;
    if (pix < HWp)
      ht[((size_t)b * E + e0 + ty + i * 8) * HWp + pix] = T[tx][ty + i * 8];
  }
}

__global__ __launch_bounds__(256)
void transpose_p2h(const float* __restrict__ ht, float* __restrict__ h)
{
  __shared__ float T[32][33];
  const int tx = threadIdx.x & 31, ty = threadIdx.x >> 5;
  const int px0 = blockIdx.x * 32, e0 = blockIdx.y * 32, b = blockIdx.z;
  #pragma unroll
  for (int i = 0; i < 4; i++) {
    const int pix = px0 + tx;
    if (pix < HWp)
      T[ty + i * 8][tx] = ht[((size_t)b * E + e0 + ty + i * 8) * HWp + pix];
  }
  __syncthreads();
  #pragma unroll
  for (int i = 0; i < 4; i++) {
    const int pix = px0 + ty + i * 8;
    if (pix < HWp)
      h[((size_t)b * N1 + 1 + pix) * E + e0 + tx] = T[tx][ty + i * 8];
  }
}

__global__ __launch_bounds__(256)
void ppeg_plane(float* __restrict__ ht,
                const float* __restrict__ w7, const float* __restrict__ b7,
                const float* __restrict__ w5, const float* __restrict__ b5,
                const float* __restrict__ w3, const float* __restrict__ b3)
{
  __shared__ float S[84][88];
  __shared__ float Wl[84];
  const int t = threadIdx.x;
  const int e = blockIdx.x & (E - 1);
  float* plane = ht + (size_t)blockIdx.x * HWp;

  for (int i = t; i < 84 * 88; i += 256) (&S[0][0])[i] = 0.f;
  if (t < 49) Wl[t] = w7[(size_t)e * 49 + t];
  else if (t >= 64 && t < 89) Wl[49 + t - 64] = w5[(size_t)e * 25 + t - 64];
  else if (t >= 96 && t < 105) Wl[74 + t - 96] = w3[(size_t)e * 9 + t - 96];
  __syncthreads();
  for (int i = t; i < HWp; i += 256) S[3 + i / HH][3 + i % HH] = plane[i];
  const float bsum = b7[e] + b5[e] + b3[e];
  __syncthreads();

  float res[7][4];
  int it = 0;
  for (int gidx = t; gidx < 1560; gidx += 256, ++it) {
    const int y = gidx / 20, x0 = (gidx % 20) * 4;
    float a0 = bsum + S[y + 3][x0 + 3];
    float a1 = bsum + S[y + 3][x0 + 4];
    float a2v = bsum + S[y + 3][x0 + 5];
    float a3 = bsum + S[y + 3][x0 + 6];
    #pragma unroll
    for (int dy = -3; dy <= 3; dy++) {
      const int row = y + 3 + dy;
      float win[10];
      #pragma unroll
      for (int m = 0; m < 10; m++) win[m] = S[row][x0 + m];
      const int ky7 = dy + 3;
      #pragma unroll
      for (int kx = 0; kx < 7; kx++) {
        const float c = Wl[ky7 * 7 + kx];
        a0 = fmaf(c, win[kx + 0], a0);
        a1 = fmaf(c, win[kx + 1], a1);
        a2v = fmaf(c, win[kx + 2], a2v);
        a3 = fmaf(c, win[kx + 3], a3);
      }
      if (dy >= -2 && dy <= 2) {
        const int ky5 = dy + 2;
        #pragma unroll
        for (int kx = 0; kx < 5; kx++) {
          const float c = Wl[49 + ky5 * 5 + kx];
          a0 = fmaf(c, win[kx + 1], a0);
          a1 = fmaf(c, win[kx + 2], a1);
          a2v = fmaf(c, win[kx + 3], a2v);
          a3 = fmaf(c, win[kx + 4], a3);
        }
      }
      if (dy >= -1 && dy <= 1) {
        const int ky3 = dy + 1;
        #pragma unroll
        for (int kx = 0; kx < 3; kx++) {
          const float c = Wl[74 + ky3 * 3 + kx];
          a0 = fmaf(c, win[kx + 2], a0);
          a1 = fmaf(c, win[kx + 3], a1);
          a2v = fmaf(c, win[kx + 4], a2v);
          a3 = fmaf(c, win[kx + 5], a3);
        }
      }
    }
    res[it][0] = a0; res[it][1] = a1; res[it][2] = a2v; res[it][3] = a3;
  }
  __syncthreads();
  it = 0;
  for (int gidx = t; gidx < 1560; gidx += 256, ++it) {
    const int y = gidx / 20, x0 = (gidx % 20) * 4;
    #pragma unroll
    for (int j = 0; j < 4; j++)
      if (x0 + j < HH) plane[y * HH + x0 + j] = res[it][j];
  }
}

__global__ __launch_bounds__(256)
void final_head(const float* __restrict__ h, const float* __restrict__ g,
                const float* __restrict__ bb, const float* __restrict__ w2,
                const float* __restrict__ b2, float* __restrict__ out)
{
  const int b = blockIdx.x;
  const int tid = threadIdx.x;
  const float* x = h + (size_t)b * N1 * E;
  float2 v = *reinterpret_cast<const float2*>(x + tid * 2);
  __shared__ float red[256];
  red[tid] = v.x + v.y;
  __syncthreads();
  for (int st = 128; st > 0; st >>= 1) { if (tid < st) red[tid] += red[tid + st]; __syncthreads(); }
  const float mu = red[0] * (1.f / E);
  __syncthreads();
  const float dx = v.x - mu, dy = v.y - mu;
  red[tid] = dx * dx + dy * dy;
  __syncthreads();
  for (int st = 128; st > 0; st >>= 1) { if (tid < st) red[tid] += red[tid + st]; __syncthreads(); }
  const float inv = 1.f / sqrtf(red[0] * (1.f / E) + 1e-5f);
  __shared__ float hn[E];
  float2 gg = *reinterpret_cast<const float2*>(g + tid * 2);
  float2 bv = *reinterpret_cast<const float2*>(bb + tid * 2);
  hn[tid * 2]     = dx * inv * gg.x + bv.x;
  hn[tid * 2 + 1] = dy * inv * gg.y + bv.y;
  __syncthreads();
  __shared__ float lg[4];
  if (tid < 4) {
    float a = b2[tid];
    for (int e = 0; e < E; e++) a = fmaf(hn[e], w2[e * 4 + tid], a);
    lg[tid] = a;
  }
  __syncthreads();
  if (tid == 0) {
    int best = 0;
    float bvv = lg[0];
    for (int j = 1; j < 4; j++) if (lg[j] > bvv) { bvv = lg[j]; best = j; }
    float S = 1.f;
    for (int j = 0; j < 4; j++) {
      const float hz = 1.f / (1.f + expf(-lg[j]));
      out[b * 4 + j] = hz;
      S *= (1.f - hz);
      out[16 + b * 4 + j] = S;
    }
    out[32 + b] = (float)best;
  }
}

__global__ void write_sentinel(float* out) { if (threadIdx.x < 36) out[threadIdx.x] = -777.f; }

// ---------------------------------------------------------------------------
struct Ws {
  unsigned short *q, *k, *v, *ql, *kl, *xl, *W2T;
  unsigned short *fc1T, *qkv1T, *qkv2T, *out1T;
  float *h, *pool, *a3vT, *qkvl, *stats;
  unsigned int* gmax;
};

constexpr long long MM = (long long)BH * LM * LM;   // 2,097,152

static void run_attention(hipStream_t stream, Ws& w,
                          const float* lng, const float* lnb, const unsigned short* qkvT,
                          const unsigned short* outT, const float* outb, const float* resw,
                          bool last)
{
  const dim3 blk(256);
  float* a2   = w.pool;
  float* a2T  = w.pool + MM;
  float* zA   = w.pool + 2 * MM;
  float* zAT  = w.pool + 3 * MM;
  float* zB   = w.pool + 4 * MM;
  float* zBT  = w.pool + 5 * MM;
  float* Y    = w.pool + 6 * MM;
  float* P1T  = w.pool + 7 * MM;
  float* P2T  = w.pool + 8 * MM;
  float* P3T  = w.pool + 9 * MM;
  unsigned short* xb    = (unsigned short*)w.pool;            // dead before a2 write
  unsigned short* heads = (unsigned short*)(w.pool + 6 * MM); // after flash partials die
  float* Opart = w.pool + 6 * MM;                             // 4.2M floats
  float* msd   = w.pool + 6 * MM + (long long)BH * NSPL * LM * DH;
  float* hb = w.qkvl;

  ln_stats<<<Bq * N1, blk, 0, stream>>>(w.h, w.stats);
  ln_to_bf16<<<gblocks_i((long long)Bq * N1 * (E / 4)), blk, 0, stream>>>(w.h, w.stats, lng, lnb, xb);
  landmark_mean<<<Bq * LM, blk, 0, stream>>>(w.h, w.stats, lng, lnb, w.xl);
  mgemm<3, 2, false, false, true><<<dim3(QKV / 128, (Bq * N1 + 127) / 128), blk, 0, stream>>>(
      xb, qkvT, nullptr, nullptr, w.q, w.k, w.v, nullptr, Bq * N1, QKV, E);
  zero_pad_rows<<<gblocks_i((long long)BH * PADS * DH), blk, 0, stream>>>(w.q, w.k, w.v);
  mgemm<3, 0, false, false, false><<<dim3(8, 8), blk, 0, stream>>>(
      w.xl, qkvT, nullptr, w.qkvl, nullptr, nullptr, nullptr, nullptr, Bq * LM, 1024, E);
  scatter_qk_l<<<gblocks_i((long long)Bq * LM * 256), blk, 0, stream>>>(w.qkvl, w.ql, w.kl);

  a2_fused<<<dim3(4, BH), blk, 0, stream>>>(w.ql, w.kl, a2, a2T);
  init_gmax<<<1, 64, 0, stream>>>(w.gmax);
  colrow_max<<<BH, blk, 0, stream>>>(a2, w.gmax);
  pinv_init2<<<gblocks_i(MM), blk, 0, stream>>>(a2, a2T, w.gmax, zA, zAT);

  float *zc = zA, *zcT = zAT, *zo = zB, *zoT = zBT;
  const long long sM = (long long)LM * LM;
  for (int it = 0; it < 6; ++it) {
    mm_ns<true, true, false><<<dim3(4, 4, BH), blk, 0, stream>>>(
        a2, zcT, Y, nullptr, P1T, 256, 256, 256, sM, sM, sM, sM, 0.f, 1.f, 7.f, -1.f);
    mm_ns<false, true, false><<<dim3(4, 4, BH), blk, 0, stream>>>(
        Y, P1T, nullptr, nullptr, P2T, 256, 256, 256, sM, sM, sM, sM, 0.f, 0.f, 15.f, -1.f);
    mm_ns<false, true, false><<<dim3(4, 4, BH), blk, 0, stream>>>(
        Y, P2T, nullptr, nullptr, P3T, 256, 256, 256, sM, sM, sM, sM, 0.f, 0.f, 13.f, -1.f);
    mm_ns<true, true, false><<<dim3(4, 4, BH), blk, 0, stream>>>(
        zc, P3T, zo, nullptr, zoT, 256, 256, 256, sM, sM, sM, sM, 0.f, 0.25f, 0.f, 0.25f);
    float* t1 = zc; zc = zo; zo = t1;
    float* t2 = zcT; zcT = zoT; zoT = t2;
  }
  // after 6 iters zc == zA (Y/P*T regions now dead -> flash partials)

  flash_a3_split<<<dim3(4, NSPL, BH), blk, 0, stream>>>(w.ql, w.k, w.v, Opart, msd);
  flash_a3_merge<<<dim3(4, BH), blk, 0, stream>>>(Opart, msd, w.a3vT);
  mm_ns<false, true, true><<<dim3(1, 4, BH), blk, 0, stream>>>(
      zc, w.a3vT, nullptr, w.W2T, nullptr, 64, 256, 256, sM, 64 * 256, 0, 64 * 256,
      0.f, 0.f, 0.f, 1.f);

  if (!last) {
    a1_fused<<<dim3(NP / 64, BH), blk, 0, stream>>>(w.q, w.kl, w.W2T, w.v, resw, heads);
    mgemm<4, 3, true, false, true><<<dim3(E / 128, (Bq * N1 + 127) / 128), blk, 0, stream>>>(
        nullptr, outT, outb, w.h, nullptr, nullptr, nullptr, heads, Bq * N1, E, E);
  } else {
    last_row_attn<<<BH, blk, 0, stream>>>(w.q, w.kl, w.W2T, w.v, resw, hb);
  }
}

}  // namespace

extern "C" void kernel_launch(void* const* d_in, const int* in_sizes, int n_in,
                              void* d_out, int out_size, void* d_ws, size_t ws_size,
                              hipStream_t stream)
{
  const float* x_path   = (const float*)d_in[0];
  const float* fc1_w    = (const float*)d_in[1];
  const float* fc1_b    = (const float*)d_in[2];
  const float* cls_tok  = (const float*)d_in[3];
  const float* ln1_g    = (const float*)d_in[4];
  const float* ln1_b    = (const float*)d_in[5];
  const float* qkv1_w   = (const float*)d_in[6];
  const float* out1_w   = (const float*)d_in[7];
  const float* out1_b   = (const float*)d_in[8];
  const float* res1_w   = (const float*)d_in[9];
  const float* ln2_g    = (const float*)d_in[10];
  const float* ln2_b    = (const float*)d_in[11];
  const float* qkv2_w   = (const float*)d_in[12];
  const float* out2_w   = (const float*)d_in[13];
  const float* out2_b   = (const float*)d_in[14];
  const float* res2_w   = (const float*)d_in[15];
  const float* conv7_w  = (const float*)d_in[16];
  const float* conv7_b  = (const float*)d_in[17];
  const float* conv5_w  = (const float*)d_in[18];
  const float* conv5_b  = (const float*)d_in[19];
  const float* conv3_w  = (const float*)d_in[20];
  const float* conv3_b  = (const float*)d_in[21];
  const float* norm_g   = (const float*)d_in[22];
  const float* norm_b   = (const float*)d_in[23];
  const float* fc2_w    = (const float*)d_in[24];
  const float* fc2_b    = (const float*)d_in[25];
  (void)in_sizes; (void)n_in; (void)out_size;

  float* W = (float*)d_ws;
  size_t off = 0;
  auto take = [&](size_t n) -> float* {
    float* p = W + off;
    off += (n + 255) & ~(size_t)255;
    return p;
  };

  Ws w;
  w.q     = (unsigned short*)take((size_t)BH * NP * DH / 2);
  w.k     = (unsigned short*)take((size_t)BH * NP * DH / 2);
  w.v     = (unsigned short*)take((size_t)BH * NP * DH / 2);
  w.h     = take((size_t)Bq * N1 * E);
  w.pool  = take((size_t)10 * MM);
  w.a3vT  = take((size_t)BH * DH * LM);
  w.W2T   = (unsigned short*)take((size_t)BH * DH * LM / 2);
  w.ql    = (unsigned short*)take((size_t)BH * LM * DH / 2);
  w.kl    = (unsigned short*)take((size_t)BH * LM * DH / 2);
  w.xl    = (unsigned short*)take((size_t)Bq * LM * E / 2);
  w.qkvl  = take((size_t)Bq * LM * 1024);
  w.stats = take((size_t)2 * Bq * N1);
  w.fc1T  = (unsigned short*)take((size_t)E * KIN / 2);
  w.qkv1T = (unsigned short*)take((size_t)QKV * E / 2);
  w.qkv2T = (unsigned short*)take((size_t)QKV * E / 2);
  w.out1T = (unsigned short*)take((size_t)E * E / 2);
  w.gmax  = (unsigned int*)take(64);

  if (ws_size < off * sizeof(float)) {
    write_sentinel<<<1, 64, 0, stream>>>((float*)d_out);
    return;
  }

  const dim3 blk(256);

  wcvt_t<<<dim3(E / 32, KIN / 32), blk, 0, stream>>>(fc1_w, w.fc1T, KIN, E);
  wcvt_t<<<dim3(QKV / 32, E / 32), blk, 0, stream>>>(qkv1_w, w.qkv1T, E, QKV);
  wcvt_t<<<dim3(QKV / 32, E / 32), blk, 0, stream>>>(qkv2_w, w.qkv2T, E, QKV);
  wcvt_t<<<dim3(E / 32, E / 32), blk, 0, stream>>>(out1_w, w.out1T, E, E);

  mgemm<0, 1, true, true, true><<<dim3(E / 128, (Bq * N0 + 127) / 128), blk, 0, stream>>>(
      x_path, w.fc1T, fc1_b, w.h, nullptr, nullptr, nullptr, nullptr, Bq * N0, E, KIN);
  fill_cls_wrap<<<gblocks_i((long long)Bq * 85 * (E / 4)), blk, 0, stream>>>(cls_tok, w.h);

  run_attention(stream, w, ln1_g, ln1_b, w.qkv1T, w.out1T, out1_b, res1_w, false);

  {
    float* planes = w.pool;
    transpose_h2p<<<dim3((HWp + 31) / 32, E / 32, Bq), blk, 0, stream>>>(w.h, planes);
    ppeg_plane<<<Bq * E, blk, 0, stream>>>(planes, conv7_w, conv7_b, conv5_w, conv5_b,
                                           conv3_w, conv3_b);
    transpose_p2h<<<dim3((HWp + 31) / 32, E / 32, Bq), blk, 0, stream>>>(planes, w.h);
  }

  run_attention(stream, w, ln2_g, ln2_b, w.qkv2T, nullptr, out2_b, res2_w, true);
  last_outproj<<<Bq, blk, 0, stream>>>(w.qkvl, out2_w, out2_b, w.h);

  final_head<<<Bq, blk, 0, stream>>>(w.h, norm_g, norm_b, fc2_w, fc2_b, (float*)d_out);
}

// Round 7
// 1829.675 us; speedup vs baseline: 4.2239x; 1.0551x over previous
//
#include <hip/hip_runtime.h>
#include <math.h>

namespace {

constexpr int Bq   = 4;
constexpr int N0   = 6000;
constexpr int KIN  = 1024;
constexpr int E    = 512;
constexpr int HH   = 78;
constexpr int HWp  = 6084;
constexpr int N1   = 6085;        // 1 + HWp
constexpr int NH   = 8;
constexpr int DH   = 64;
constexpr int LM   = 256;
constexpr int NP   = 6144;
constexpr int LCH  = 24;
constexpr int PADS = 59;
constexpr int BH   = Bq * NH;     // 32
constexpr int QKV  = 3 * E;
constexpr int NSPL = 8;           // flash split-K factor

typedef __attribute__((ext_vector_type(8))) short bf16x8;
typedef __attribute__((ext_vector_type(4))) float f32x4;

__host__ __device__ inline int gblocks_i(long long n) { return (int)((n + 255) / 256); }

__device__ inline unsigned short f2bf(float x) {
  unsigned u = __float_as_uint(x);
  u += 0x7FFFu + ((u >> 16) & 1u);
  return (unsigned short)(u >> 16);
}
__device__ inline float bf2f(unsigned short s) {
  return __uint_as_float(((unsigned)s) << 16);
}
// LDS chunk swizzle: 8-bf16 (16B) chunks XORed by row bits -> bank-balanced
__device__ inline int swz8(int row, int chunk) {
  return chunk ^ (row & 7) ^ ((row >> 3) & 7);
}
// XCD-bijective flat-grid swizzle (m204)
__device__ inline int xcd_swz(int flat, int nwg) {
  const int q8 = nwg >> 3, r8 = nwg & 7;
  const int xcd = flat & 7, pos = flat >> 3;
  return (xcd < r8 ? xcd * (q8 + 1) : r8 * (q8 + 1) + (xcd - r8) * q8) + pos;
}

// ---------------------------------------------------------------------------
// weight transpose + f32->bf16: in[K][N] -> out[N][K]
// ---------------------------------------------------------------------------
__global__ __launch_bounds__(256)
void wcvt_t(const float* __restrict__ in, unsigned short* __restrict__ out, int K, int N)
{
  __shared__ float T[32][33];
  const int tx = threadIdx.x & 31, ty = threadIdx.x >> 5;
  const int n0 = blockIdx.x * 32, k0 = blockIdx.y * 32;
  #pragma unroll
  for (int i = 0; i < 4; i++)
    T[ty + i * 8][tx] = in[(size_t)(k0 + ty + i * 8) * N + n0 + tx];
  __syncthreads();
  #pragma unroll
  for (int i = 0; i < 4; i++)
    out[(size_t)(n0 + ty + i * 8) * K + k0 + tx] = f2bf(T[tx][ty + i * 8]);
}

// ---------------------------------------------------------------------------
// mgemm: C[M,N] = A[M,K] @ B[K,N], bf16 MFMA, B pre-transposed bf16 [N][K].
// ASRC: 0 f32 A; 3 bf16 A; 4 bf16 gather from heads layout.
// STORE: 0 f32 C; 1 shift (fc1->h rows); 2 bf16 scatter qkv; 3 f32 accum.
// ---------------------------------------------------------------------------
template<int ASRC, int STORE, bool BIAS, bool RELU, bool SWIZ>
__global__ __launch_bounds__(256)
void mgemm(const void* __restrict__ Av, const unsigned short* __restrict__ Bt,
           const float* __restrict__ bias, float* __restrict__ C,
           unsigned short* __restrict__ qp, unsigned short* __restrict__ kp,
           unsigned short* __restrict__ vp, const unsigned short* __restrict__ Ag,
           int Mrows, int N, int K)
{
  __shared__ __align__(16) short As[128 * 40];
  __shared__ __align__(16) short Bs[128 * 40];
  const int t = threadIdx.x;
  const int lane = t & 63;
  const int l16 = lane & 15, g = lane >> 4;
  const int wave = t >> 6;
  const int wr = (wave >> 1) * 64, wc = (wave & 1) * 64;

  int bx = blockIdx.x, by = blockIdx.y;
  if (SWIZ) {
    const int gx = gridDim.x;
    const int nid = xcd_swz(by * gx + bx, gx * gridDim.y);
    bx = nid % gx; by = nid / gx;
  }
  const int rowBase = by * 128, colBase = bx * 128;

  f32x4 acc[4][4];
  #pragma unroll
  for (int mi = 0; mi < 4; mi++)
    #pragma unroll
    for (int ni = 0; ni < 4; ni++) acc[mi][ni] = (f32x4){0.f, 0.f, 0.f, 0.f};

  for (int k0 = 0; k0 < K; k0 += 32) {
    if (ASRC == 0) {
      const float* A = (const float*)Av;
      #pragma unroll
      for (int i = 0; i < 4; i++) {
        const int id = i * 256 + t;
        const int row = id >> 3, kq = id & 7;
        const int r = rowBase + row;
        float4 va = make_float4(0.f, 0.f, 0.f, 0.f);
        if (r < Mrows)
          va = *reinterpret_cast<const float4*>(A + (size_t)r * K + k0 + kq * 4);
        const unsigned lo = (unsigned)f2bf(va.x) | ((unsigned)f2bf(va.y) << 16);
        const unsigned hi = (unsigned)f2bf(va.z) | ((unsigned)f2bf(va.w) << 16);
        *reinterpret_cast<uint2*>(&As[row * 40 + kq * 4]) = make_uint2(lo, hi);
      }
    } else {
      #pragma unroll
      for (int i = 0; i < 2; i++) {
        const int id = i * 256 + t;
        const int row = id >> 2, c8 = id & 3;
        const int r = rowBase + row;
        int4 va = make_int4(0, 0, 0, 0);
        if (r < Mrows) {
          const int kk = k0 + c8 * 8;
          if (ASRC == 4) {
            const int b = r / N1, rr2 = r % N1;
            va = *reinterpret_cast<const int4*>(
                Ag + (((size_t)(b * NH + (kk >> 6))) * NP + PADS + rr2) * DH + (kk & 63));
          } else {
            va = *reinterpret_cast<const int4*>(((const unsigned short*)Av) + (size_t)r * K + kk);
          }
        }
        *reinterpret_cast<int4*>(&As[row * 40 + c8 * 8]) = va;
      }
    }
    #pragma unroll
    for (int i = 0; i < 2; i++) {
      const int id = i * 256 + t;
      const int row = id >> 2, g8 = id & 3;
      int4 vb = *reinterpret_cast<const int4*>(Bt + (size_t)(colBase + row) * K + k0 + g8 * 8);
      *reinterpret_cast<int4*>(&Bs[row * 40 + g8 * 8]) = vb;
    }
    __syncthreads();
    bf16x8 af[4], bf[4];
    #pragma unroll
    for (int mi = 0; mi < 4; mi++)
      af[mi] = *reinterpret_cast<const bf16x8*>(&As[(wr + mi * 16 + l16) * 40 + g * 8]);
    #pragma unroll
    for (int ni = 0; ni < 4; ni++)
      bf[ni] = *reinterpret_cast<const bf16x8*>(&Bs[(wc + ni * 16 + l16) * 40 + g * 8]);
    #pragma unroll
    for (int mi = 0; mi < 4; mi++)
      #pragma unroll
      for (int ni = 0; ni < 4; ni++)
        acc[mi][ni] = __builtin_amdgcn_mfma_f32_16x16x32_bf16(af[mi], bf[ni], acc[mi][ni], 0, 0, 0);
    __syncthreads();
  }

  #pragma unroll
  for (int mi = 0; mi < 4; mi++) {
    #pragma unroll
    for (int ni = 0; ni < 4; ni++) {
      #pragma unroll
      for (int r4 = 0; r4 < 4; r4++) {
        const int row = rowBase + wr + mi * 16 + g * 4 + r4;
        if (row >= Mrows) continue;
        const int col = colBase + wc + ni * 16 + l16;
        float v = acc[mi][ni][r4];
        if (BIAS) v += bias[col];
        if (RELU) v = fmaxf(v, 0.f);
        if (STORE == 2) {
          const int b   = row / N1;
          const int p   = (row % N1) + PADS;
          const int wch = col >> 9;
          const int hd  = (col >> 6) & 7;
          const int d   = col & 63;
          float vv = (wch == 0) ? v * 0.125f : v;
          unsigned short* dst = (wch == 0) ? qp : (wch == 1) ? kp : vp;
          dst[(((size_t)(b * NH + hd)) * NP + p) * DH + d] = f2bf(vv);
        } else if (STORE == 1) {
          C[((size_t)(row / N0) * N1 + 1 + (row % N0)) * N + col] = v;
        } else if (STORE == 3) {
          C[(size_t)row * N + col] += v;
        } else {
          C[(size_t)row * N + col] = v;
        }
      }
    }
  }
}

// ---------------------------------------------------------------------------
// mm_ns2: batched M = (Ah+Al)[256xK] @ (Bh+Bl)[KxN] via 3-term bf16 MFMA.
// All inputs pre-split bf16 pairs; A normal [r][k], B given transposed [n][k].
// Outputs (optional): normal pair Cn = cN*I + aN*M; transposed pair
// Ct = cT*I + aT*M^T. grid (Ncols/64, M/64, batch), XCD-swizzled.
// ---------------------------------------------------------------------------
template<bool WN, bool WT>
__global__ __launch_bounds__(256)
void mm_ns2(const unsigned short* __restrict__ Ah, const unsigned short* __restrict__ Al,
            const unsigned short* __restrict__ Bth, const unsigned short* __restrict__ Btl,
            unsigned short* __restrict__ Cnh, unsigned short* __restrict__ Cnl,
            unsigned short* __restrict__ Cth, unsigned short* __restrict__ Ctl,
            int Ncols, int Mtot, int K,
            long long sA, long long sB, long long sCn, long long sCt,
            float cN, float aN, float cT, float aT)
{
  int bx = blockIdx.x, by = blockIdx.y, bz = blockIdx.z;
  {
    const int gx = gridDim.x, gy = gridDim.y;
    int nid = xcd_swz((bz * gy + by) * gx + bx, gx * gy * gridDim.z);
    bx = nid % gx; nid /= gx; by = nid % gy; bz = nid / gy;
  }
  const unsigned short* Ahb = Ah + (size_t)bz * sA;
  const unsigned short* Alb = Al + (size_t)bz * sA;
  const unsigned short* Bhb = Bth + (size_t)bz * sB;
  const unsigned short* Blb = Btl + (size_t)bz * sB;
  __shared__ __align__(16) char smem[32768];
  unsigned short* AhS = (unsigned short*)smem;
  unsigned short* AlS = AhS + 4096;
  unsigned short* BhS = AhS + 8192;
  unsigned short* BlS = AhS + 12288;
  const int t = threadIdx.x, lane = t & 63, w = t >> 6;
  const int l15 = lane & 15, g = lane >> 4;
  const int rb = by * 64, cb = bx * 64;
  const int wr = w * 16;

  f32x4 acc[4];
  #pragma unroll
  for (int ni = 0; ni < 4; ni++) acc[ni] = (f32x4){0.f, 0.f, 0.f, 0.f};

  for (int k0 = 0; k0 < K; k0 += 64) {
    if (k0) __syncthreads();
    #pragma unroll
    for (int it = 0; it < 2; it++) {
      const int id = it * 256 + t;
      const int row = id >> 3, ch = id & 7;
      const int eo = row * 64 + swz8(row, ch) * 8;
      const size_t ga = (size_t)(rb + row) * K + k0 + ch * 8;
      const size_t gb = (size_t)(cb + row) * K + k0 + ch * 8;
      *reinterpret_cast<int4*>(&AhS[eo]) = *reinterpret_cast<const int4*>(Ahb + ga);
      *reinterpret_cast<int4*>(&AlS[eo]) = *reinterpret_cast<const int4*>(Alb + ga);
      *reinterpret_cast<int4*>(&BhS[eo]) = *reinterpret_cast<const int4*>(Bhb + gb);
      *reinterpret_cast<int4*>(&BlS[eo]) = *reinterpret_cast<const int4*>(Blb + gb);
    }
    __syncthreads();
    #pragma unroll
    for (int ds = 0; ds < 2; ds++) {
      const int ar = wr + l15;
      bf16x8 ah = *reinterpret_cast<const bf16x8*>(&AhS[ar * 64 + swz8(ar, ds * 4 + g) * 8]);
      bf16x8 al = *reinterpret_cast<const bf16x8*>(&AlS[ar * 64 + swz8(ar, ds * 4 + g) * 8]);
      #pragma unroll
      for (int ni = 0; ni < 4; ni++) {
        const int nr = ni * 16 + l15;
        bf16x8 bhf = *reinterpret_cast<const bf16x8*>(&BhS[nr * 64 + swz8(nr, ds * 4 + g) * 8]);
        bf16x8 blf = *reinterpret_cast<const bf16x8*>(&BlS[nr * 64 + swz8(nr, ds * 4 + g) * 8]);
        acc[ni] = __builtin_amdgcn_mfma_f32_16x16x32_bf16(ah, bhf, acc[ni], 0, 0, 0);
        acc[ni] = __builtin_amdgcn_mfma_f32_16x16x32_bf16(ah, blf, acc[ni], 0, 0, 0);
        acc[ni] = __builtin_amdgcn_mfma_f32_16x16x32_bf16(al, bhf, acc[ni], 0, 0, 0);
      }
    }
  }
  __syncthreads();
  float* tb = (float*)smem;   // [64][65]
  #pragma unroll
  for (int ni = 0; ni < 4; ni++)
    #pragma unroll
    for (int r = 0; r < 4; r++)
      tb[(wr + g * 4 + r) * 65 + l15 + ni * 16] = acc[ni][r];
  __syncthreads();
  #pragma unroll
  for (int it = 0; it < 4; it++) {
    const int id = it * 256 + t;
    const int row = id >> 4, q4 = (id & 15) * 4;
    if (WN) {
      ushort4 oh, ol;
      #pragma unroll
      for (int j = 0; j < 4; j++) {
        const float v = ((rb + row) == (cb + q4 + j) ? cN : 0.f) + aN * tb[row * 65 + q4 + j];
        const unsigned short h = f2bf(v);
        ((unsigned short*)&oh)[j] = h;
        ((unsigned short*)&ol)[j] = f2bf(v - bf2f(h));
      }
      const size_t o = (size_t)bz * sCn + (size_t)(rb + row) * Ncols + cb + q4;
      *reinterpret_cast<ushort4*>(Cnh + o) = oh;
      *reinterpret_cast<ushort4*>(Cnl + o) = ol;
    }
    if (WT) {
      ushort4 oh, ol;
      #pragma unroll
      for (int j = 0; j < 4; j++) {
        const float v = ((cb + row) == (rb + q4 + j) ? cT : 0.f) + aT * tb[(q4 + j) * 65 + row];
        const unsigned short h = f2bf(v);
        ((unsigned short*)&oh)[j] = h;
        ((unsigned short*)&ol)[j] = f2bf(v - bf2f(h));
      }
      const size_t o = (size_t)bz * sCt + (size_t)(cb + row) * Mtot + rb + q4;
      *reinterpret_cast<ushort4*>(Cth + o) = oh;
      *reinterpret_cast<ushort4*>(Ctl + o) = ol;
    }
  }
}

// ---------------------------------------------------------------------------
// a2_fused: a2 = softmax_rows(ql @ kl^T); writes a2 and a2T (f32).
// ---------------------------------------------------------------------------
__global__ __launch_bounds__(256)
void a2_fused(const unsigned short* __restrict__ ql, const unsigned short* __restrict__ kl,
              float* __restrict__ a2, float* __restrict__ a2T)
{
  const int bh = blockIdx.y;
  const int t = threadIdx.x, lane = t & 63, w = t >> 6;
  const int l15 = lane & 15, g = lane >> 4;
  const int row0 = blockIdx.x * 64 + w * 16;
  __shared__ float tb[4][16][68];

  bf16x8 af[2];
  #pragma unroll
  for (int ds = 0; ds < 2; ds++)
    af[ds] = *reinterpret_cast<const bf16x8*>(ql + ((size_t)bh * LM + row0 + l15) * 64 + ds * 32 + g * 8);

  f32x4 s[16];
  #pragma unroll
  for (int ni = 0; ni < 16; ni++) s[ni] = (f32x4){0.f, 0.f, 0.f, 0.f};
  #pragma unroll
  for (int ni = 0; ni < 16; ni++)
    #pragma unroll
    for (int ds = 0; ds < 2; ds++) {
      bf16x8 bf = *reinterpret_cast<const bf16x8*>(kl + ((size_t)bh * LM + ni * 16 + l15) * 64 + ds * 32 + g * 8);
      s[ni] = __builtin_amdgcn_mfma_f32_16x16x32_bf16(af[ds], bf, s[ni], 0, 0, 0);
    }
  #pragma unroll
  for (int r = 0; r < 4; r++) {
    float m = -INFINITY;
    #pragma unroll
    for (int ni = 0; ni < 16; ni++) m = fmaxf(m, s[ni][r]);
    #pragma unroll
    for (int msk = 1; msk < 16; msk <<= 1) m = fmaxf(m, __shfl_xor(m, msk));
    float sm = 0.f;
    #pragma unroll
    for (int ni = 0; ni < 16; ni++) { float e = expf(s[ni][r] - m); s[ni][r] = e; sm += e; }
    #pragma unroll
    for (int msk = 1; msk < 16; msk <<= 1) sm += __shfl_xor(sm, msk);
    const float inv = 1.f / sm;
    #pragma unroll
    for (int ni = 0; ni < 16; ni++) s[ni][r] *= inv;
  }
  #pragma unroll
  for (int ni = 0; ni < 16; ni++)
    #pragma unroll
    for (int r = 0; r < 4; r++)
      a2[((size_t)bh << 16) + (size_t)(row0 + g * 4 + r) * 256 + ni * 16 + l15] = s[ni][r];
  for (int c4 = 0; c4 < 4; c4++) {
    #pragma unroll
    for (int ni2 = 0; ni2 < 4; ni2++)
      #pragma unroll
      for (int r = 0; r < 4; r++)
        tb[w][g * 4 + r][ni2 * 16 + l15] = s[c4 * 4 + ni2][r];
    #pragma unroll
    for (int q = 0; q < 4; q++) {
      float4 o;
      #pragma unroll
      for (int j = 0; j < 4; j++) ((float*)&o)[j] = tb[w][q * 4 + j][lane];
      *reinterpret_cast<float4*>(a2T + ((size_t)bh << 16) + (size_t)(c4 * 64 + lane) * 256 + row0 + q * 4) = o;
    }
  }
}

// ---------------------------------------------------------------------------
// flash_a3_split: partial (O, m, l) per K-split; grid (4, NSPL, BH) swizzled.
// ---------------------------------------------------------------------------
__global__ __launch_bounds__(256)
void flash_a3_split(const unsigned short* __restrict__ ql, const unsigned short* __restrict__ k,
                    const unsigned short* __restrict__ v, float* __restrict__ Opart,
                    float* __restrict__ msd)
{
  int bx = blockIdx.x, by = blockIdx.y, bz = blockIdx.z;
  {
    const int gx = gridDim.x, gy = gridDim.y;
    int nid = xcd_swz((bz * gy + by) * gx + bx, gx * gy * gridDim.z);
    bx = nid % gx; nid /= gx; by = nid % gy; bz = nid / gy;
  }
  const int bh = bz, sp = by, lm0 = bx * 64;
  const int t = threadIdx.x, lane = t & 63, w = t >> 6;
  const int l15 = lane & 15, g = lane >> 4;
  __shared__ __align__(16) char smem[24576];
  unsigned short* Kl = (unsigned short*)smem;
  unsigned short* VT = (unsigned short*)(smem + 8192);
  unsigned short* Pl = (unsigned short*)(smem + 16384);

  bf16x8 af[2];
  #pragma unroll
  for (int ds = 0; ds < 2; ds++)
    af[ds] = *reinterpret_cast<const bf16x8*>(ql + ((size_t)bh * LM + lm0 + w * 16 + l15) * 64 + ds * 32 + g * 8);

  f32x4 O[4];
  #pragma unroll
  for (int ni = 0; ni < 4; ni++) O[ni] = (f32x4){0.f, 0.f, 0.f, 0.f};
  float m[4] = {-INFINITY, -INFINITY, -INFINITY, -INFINITY};
  float sd[4] = {0.f, 0.f, 0.f, 0.f};

  const int kt0 = sp * (NP / 64 / NSPL), kt1 = kt0 + NP / 64 / NSPL;
  for (int kt = kt0; kt < kt1; kt++) {
    if (kt != kt0) __syncthreads();
    #pragma unroll
    for (int it = 0; it < 2; it++) {
      const int id = it * 256 + t;
      const int kp = id >> 3, ch = id & 7;
      int4 kv = *reinterpret_cast<const int4*>(k + ((size_t)bh * NP + kt * 64 + kp) * 64 + ch * 8);
      *reinterpret_cast<int4*>(&Kl[kp * 64 + swz8(kp, ch) * 8]) = kv;
      int4 vv = *reinterpret_cast<const int4*>(v + ((size_t)bh * NP + kt * 64 + kp) * 64 + ch * 8);
      const unsigned short* ps = (const unsigned short*)&vv;
      #pragma unroll
      for (int j = 0; j < 8; j++) {
        const int d = ch * 8 + j;
        VT[d * 64 + swz8(d, kp >> 3) * 8 + (kp & 7)] = ps[j];
      }
    }
    __syncthreads();
    f32x4 s[4];
    #pragma unroll
    for (int ni = 0; ni < 4; ni++) s[ni] = (f32x4){0.f, 0.f, 0.f, 0.f};
    #pragma unroll
    for (int ni = 0; ni < 4; ni++)
      #pragma unroll
      for (int ds = 0; ds < 2; ds++) {
        const int kr = ni * 16 + l15;
        bf16x8 bf = *reinterpret_cast<const bf16x8*>(&Kl[kr * 64 + swz8(kr, ds * 4 + g) * 8]);
        s[ni] = __builtin_amdgcn_mfma_f32_16x16x32_bf16(af[ds], bf, s[ni], 0, 0, 0);
      }
    #pragma unroll
    for (int r = 0; r < 4; r++) {
      float mc = fmaxf(fmaxf(s[0][r], s[1][r]), fmaxf(s[2][r], s[3][r]));
      #pragma unroll
      for (int msk = 1; msk < 16; msk <<= 1) mc = fmaxf(mc, __shfl_xor(mc, msk));
      const float mn = fmaxf(m[r], mc);
      const float sc = expf(m[r] - mn);
      float rs = 0.f;
      #pragma unroll
      for (int ni = 0; ni < 4; ni++) { float e = expf(s[ni][r] - mn); s[ni][r] = e; rs += e; }
      #pragma unroll
      for (int msk = 1; msk < 16; msk <<= 1) rs += __shfl_xor(rs, msk);
      sd[r] = sd[r] * sc + rs;
      m[r] = mn;
      #pragma unroll
      for (int ni = 0; ni < 4; ni++) O[ni][r] *= sc;
    }
    unsigned short* Pw = Pl + w * 1024;
    #pragma unroll
    for (int ni = 0; ni < 4; ni++)
      #pragma unroll
      for (int r = 0; r < 4; r++) {
        const int rowl = g * 4 + r, col = ni * 16 + l15;
        Pw[rowl * 64 + swz8(rowl, col >> 3) * 8 + (col & 7)] = f2bf(s[ni][r]);
      }
    #pragma unroll
    for (int ks = 0; ks < 2; ks++) {
      bf16x8 pa = *reinterpret_cast<const bf16x8*>(&Pw[l15 * 64 + swz8(l15, ks * 4 + g) * 8]);
      #pragma unroll
      for (int ni = 0; ni < 4; ni++) {
        const int d = ni * 16 + l15;
        bf16x8 bv = *reinterpret_cast<const bf16x8*>(&VT[d * 64 + swz8(d, ks * 4 + g) * 8]);
        O[ni] = __builtin_amdgcn_mfma_f32_16x16x32_bf16(pa, bv, O[ni], 0, 0, 0);
      }
    }
  }
  #pragma unroll
  for (int r = 0; r < 4; r++) {
    const int row = lm0 + w * 16 + g * 4 + r;
    const size_t base = ((size_t)(bh * NSPL + sp) * LM + row);
    #pragma unroll
    for (int ni = 0; ni < 4; ni++)
      Opart[base * 64 + ni * 16 + l15] = O[ni][r];
    if (l15 == 0) {
      msd[base * 2]     = m[r];
      msd[base * 2 + 1] = sd[r];
    }
  }
}

// merge partials -> a3vT bf16 pair [bh][64 d][256 lm]
__global__ __launch_bounds__(256)
void flash_a3_merge(const float* __restrict__ Opart, const float* __restrict__ msd,
                    unsigned short* __restrict__ a3vTh, unsigned short* __restrict__ a3vTl)
{
  const int bh = blockIdx.y, lm0 = blockIdx.x * 64;
  const int t = threadIdx.x;
  const int r = t >> 2, dg = t & 3;
  const int row = lm0 + r;
  float m8[NSPL], w8[NSPL];
  float M = -INFINITY;
  #pragma unroll
  for (int s = 0; s < NSPL; s++) {
    m8[s] = msd[((size_t)(bh * NSPL + s) * LM + row) * 2];
    M = fmaxf(M, m8[s]);
  }
  float S = 0.f;
  #pragma unroll
  for (int s = 0; s < NSPL; s++) {
    const float e = expf(m8[s] - M);
    w8[s] = e;
    S += msd[((size_t)(bh * NSPL + s) * LM + row) * 2 + 1] * e;
  }
  const float invS = 1.f / S;
  float acc[16];
  #pragma unroll
  for (int j = 0; j < 16; j++) acc[j] = 0.f;
  #pragma unroll
  for (int s = 0; s < NSPL; s++) {
    const float* op = Opart + ((size_t)(bh * NSPL + s) * LM + row) * 64 + dg * 16;
    #pragma unroll
    for (int j = 0; j < 16; j++) acc[j] = fmaf(w8[s], op[j], acc[j]);
  }
  __shared__ float Tl[64][65];
  #pragma unroll
  for (int j = 0; j < 16; j++) Tl[dg * 16 + j][r] = acc[j] * invS;
  __syncthreads();
  const int d = t >> 2, q4 = t & 3;
  #pragma unroll
  for (int j = 0; j < 4; j++) {
    const int c0 = q4 * 16 + j * 4;
    ushort4 oh, ol;
    #pragma unroll
    for (int jj = 0; jj < 4; jj++) {
      const float v = Tl[d][c0 + jj];
      const unsigned short h = f2bf(v);
      ((unsigned short*)&oh)[jj] = h;
      ((unsigned short*)&ol)[jj] = f2bf(v - bf2f(h));
    }
    const size_t o = ((size_t)bh * 64 + d) * 256 + lm0 + c0;
    *reinterpret_cast<ushort4*>(a3vTh + o) = oh;
    *reinterpret_cast<ushort4*>(a3vTl + o) = ol;
  }
}

// banded dwconv weight matrices: P2g[head][r][kk] = w33[kk-r] if 0<=kk-r<=32
__global__ __launch_bounds__(256)
void build_band(const float* __restrict__ resw, unsigned short* __restrict__ P2g)
{
  const int head = blockIdx.x;
  const float* w33 = resw + head * 33;
  for (int i = threadIdx.x; i < 64 * 96; i += 256) {
    const int r = i / 96, kk = i % 96;
    const int d = kk - r;
    P2g[(size_t)head * 64 * 96 + i] = f2bf((d >= 0 && d <= 32) ? w33[d] : 0.f);
  }
}

// ---------------------------------------------------------------------------
// a1_fused: heads = softmax_rows(q @ kl^T) @ W2 + dwconv33(v), bf16 out.
// LDS 32KB: VTc 16KB + per-wave P halves 16KB; band weights from global.
// ---------------------------------------------------------------------------
__global__ __launch_bounds__(256)
void a1_fused(const unsigned short* __restrict__ q, const unsigned short* __restrict__ kl,
              const unsigned short* __restrict__ W2T, const unsigned short* __restrict__ v,
              const unsigned short* __restrict__ P2g, unsigned short* __restrict__ heads)
{
  const int bh = blockIdx.y;
  const int p0 = blockIdx.x * 64;
  const int t = threadIdx.x, lane = t & 63, w = t >> 6;
  const int l15 = lane & 15, g = lane >> 4;
  __shared__ __align__(16) unsigned short VTc[8192];     // [64 d][96->128 p]
  __shared__ __align__(16) unsigned short Pl[4][2048];   // per-wave [16][128]

  #pragma unroll
  for (int it = 0; it < 3; it++) {
    const int id = it * 256 + t;
    const int kp = id >> 3, ch = id & 7;
    const int gp = p0 - 16 + kp;
    int4 vv = make_int4(0, 0, 0, 0);
    if (gp >= 0 && gp < NP)
      vv = *reinterpret_cast<const int4*>(v + ((size_t)bh * NP + gp) * 64 + ch * 8);
    const unsigned short* ps = (const unsigned short*)&vv;
    #pragma unroll
    for (int j = 0; j < 8; j++) {
      const int d = ch * 8 + j;
      VTc[d * 128 + swz8(d, kp >> 3) * 8 + (kp & 7)] = ps[j];
    }
  }
  __syncthreads();

  bf16x8 af[2];
  #pragma unroll
  for (int ds = 0; ds < 2; ds++)
    af[ds] = *reinterpret_cast<const bf16x8*>(q + ((size_t)bh * NP + p0 + w * 16 + l15) * 64 + ds * 32 + g * 8);
  f32x4 s[16];
  #pragma unroll
  for (int ni = 0; ni < 16; ni++) s[ni] = (f32x4){0.f, 0.f, 0.f, 0.f};
  #pragma unroll
  for (int ni = 0; ni < 16; ni++)
    #pragma unroll
    for (int ds = 0; ds < 2; ds++) {
      bf16x8 bf = *reinterpret_cast<const bf16x8*>(kl + ((size_t)bh * LM + ni * 16 + l15) * 64 + ds * 32 + g * 8);
      s[ni] = __builtin_amdgcn_mfma_f32_16x16x32_bf16(af[ds], bf, s[ni], 0, 0, 0);
    }
  #pragma unroll
  for (int r = 0; r < 4; r++) {
    float m = -INFINITY;
    #pragma unroll
    for (int ni = 0; ni < 16; ni++) m = fmaxf(m, s[ni][r]);
    #pragma unroll
    for (int msk = 1; msk < 16; msk <<= 1) m = fmaxf(m, __shfl_xor(m, msk));
    float sm = 0.f;
    #pragma unroll
    for (int ni = 0; ni < 16; ni++) { float e = expf(s[ni][r] - m); s[ni][r] = e; sm += e; }
    #pragma unroll
    for (int msk = 1; msk < 16; msk <<= 1) sm += __shfl_xor(sm, msk);
    const float inv = 1.f / sm;
    #pragma unroll
    for (int ni = 0; ni < 16; ni++) s[ni][r] *= inv;
  }

  f32x4 O[4];
  #pragma unroll
  for (int ni = 0; ni < 4; ni++) O[ni] = (f32x4){0.f, 0.f, 0.f, 0.f};
  unsigned short* Pw = Pl[w];
  #pragma unroll
  for (int hf = 0; hf < 2; hf++) {
    // store this half's P (cols hf*128 .. +127 mapped to local 0..127)
    #pragma unroll
    for (int ni2 = 0; ni2 < 8; ni2++)
      #pragma unroll
      for (int r = 0; r < 4; r++) {
        const int rowl = g * 4 + r, col = ni2 * 16 + l15;
        Pw[rowl * 128 + swz8(rowl, col >> 3) * 8 + (col & 7)] = f2bf(s[hf * 8 + ni2][r]);
      }
    __asm__ __volatile__("" ::: "memory");   // order per-wave LDS write->read
    #pragma unroll
    for (int ks2 = 0; ks2 < 4; ks2++) {
      const int ks = hf * 4 + ks2;
      bf16x8 pa = *reinterpret_cast<const bf16x8*>(&Pw[l15 * 128 + swz8(l15, ks2 * 4 + g) * 8]);
      #pragma unroll
      for (int ni = 0; ni < 4; ni++) {
        bf16x8 bf = *reinterpret_cast<const bf16x8*>(
            W2T + ((size_t)bh * 64 + ni * 16 + l15) * 256 + ks * 32 + g * 8);
        O[ni] = __builtin_amdgcn_mfma_f32_16x16x32_bf16(pa, bf, O[ni], 0, 0, 0);
      }
    }
    __asm__ __volatile__("" ::: "memory");   // order read -> next half's write
  }
  // depthwise conv as banded-matrix MFMA; band matrix from global (L2-hot)
  const unsigned short* band = P2g + (size_t)(bh & 7) * 64 * 96;
  #pragma unroll
  for (int ks = 0; ks < 3; ks++) {
    const int ar = w * 16 + l15;
    bf16x8 pa = *reinterpret_cast<const bf16x8*>(band + (size_t)ar * 96 + ks * 32 + g * 8);
    #pragma unroll
    for (int ni = 0; ni < 4; ni++) {
      const int d = ni * 16 + l15;
      bf16x8 bv = *reinterpret_cast<const bf16x8*>(&VTc[d * 128 + swz8(d, ks * 4 + g) * 8]);
      O[ni] = __builtin_amdgcn_mfma_f32_16x16x32_bf16(pa, bv, O[ni], 0, 0, 0);
    }
  }
  #pragma unroll
  for (int ni = 0; ni < 4; ni++)
    #pragma unroll
    for (int r = 0; r < 4; r++)
      heads[((size_t)bh * NP + p0 + w * 16 + g * 4 + r) * 64 + ni * 16 + l15] = f2bf(O[ni][r]);
}

// ---------------------------------------------------------------------------
// fused LN: per row compute stats and write bf16 LN output
__global__ __launch_bounds__(256)
void ln_fused(const float* __restrict__ X, const float* __restrict__ g,
              const float* __restrict__ b, unsigned short* __restrict__ xb)
{
  const size_t row = blockIdx.x;
  const float* x = X + row * E;
  const int tid = threadIdx.x;
  float2 v = *reinterpret_cast<const float2*>(x + tid * 2);
  __shared__ float red[256];
  red[tid] = v.x + v.y;
  __syncthreads();
  for (int s = 128; s > 0; s >>= 1) { if (tid < s) red[tid] += red[tid + s]; __syncthreads(); }
  const float mu = red[0] * (1.f / E);
  __syncthreads();
  const float dx = v.x - mu, dy = v.y - mu;
  red[tid] = dx * dx + dy * dy;
  __syncthreads();
  for (int s = 128; s > 0; s >>= 1) { if (tid < s) red[tid] += red[tid + s]; __syncthreads(); }
  const float inv = 1.f / sqrtf(red[0] * (1.f / E) + 1e-5f);
  float2 gg = *reinterpret_cast<const float2*>(g + tid * 2);
  float2 bb = *reinterpret_cast<const float2*>(b + tid * 2);
  ushort2 o;
  o.x = f2bf(dx * inv * gg.x + bb.x);
  o.y = f2bf(dy * inv * gg.y + bb.y);
  *reinterpret_cast<ushort2*>(xb + row * E + tid * 2) = o;
}

__global__ void fill_cls_wrap(const float* __restrict__ cls, float* __restrict__ h)
{
  int idx = blockIdx.x * 256 + threadIdx.x;
  const int total = Bq * 85 * (E / 4);
  if (idx >= total) return;
  const int e4 = idx % (E / 4);
  int t = idx / (E / 4);
  const int rr = t % 85;
  const int b = t / 85;
  float4* H = reinterpret_cast<float4*>(h);
  if (rr == 0) {
    H[((size_t)b * N1) * (E / 4) + e4] = reinterpret_cast<const float4*>(cls)[e4];
  } else {
    const int i = rr - 1;
    H[((size_t)b * N1 + 1 + N0 + i) * (E / 4) + e4] =
        H[((size_t)b * N1 + 1 + i) * (E / 4) + e4];
  }
}

// landmark means straight from bf16 LN output (zero front-pad)
__global__ __launch_bounds__(256)
void landmark_mean(const unsigned short* __restrict__ xb, unsigned short* __restrict__ xl)
{
  const int bm = blockIdx.x;
  const int b = bm / LM, i = bm % LM;
  const int tid = threadIdx.x;
  float2 acc = make_float2(0.f, 0.f);
  for (int j = 0; j < LCH; j++) {
    const int real = i * LCH + j - PADS;
    if (real < 0) continue;
    ushort2 hv = *reinterpret_cast<const ushort2*>(xb + ((size_t)b * N1 + real) * E + tid * 2);
    acc.x += bf2f(hv.x);
    acc.y += bf2f(hv.y);
  }
  ushort2 o;
  o.x = f2bf(acc.x * (1.f / LCH));
  o.y = f2bf(acc.y * (1.f / LCH));
  *reinterpret_cast<ushort2*>(xl + (size_t)bm * E + tid * 2) = o;
}

__global__ void zero_pad_rows(unsigned short* __restrict__ q, unsigned short* __restrict__ k,
                              unsigned short* __restrict__ v)
{
  const int idx = blockIdx.x * 256 + threadIdx.x;
  const int total = BH * PADS * DH;
  if (idx >= total) return;
  const int d = idx % DH;
  int t = idx / DH;
  const int p = t % PADS;
  const int bh = t / PADS;
  const size_t o = ((size_t)bh * NP + p) * DH + d;
  q[o] = 0; k[o] = 0; v[o] = 0;
}

__global__ void scatter_qk_l(const float* __restrict__ qkvf, unsigned short* __restrict__ ql,
                             unsigned short* __restrict__ kl)
{
  int idx = blockIdx.x * 256 + threadIdx.x;
  const int total = Bq * LM * (1024 / 4);
  if (idx >= total) return;
  const int c4 = idx % 256;
  int t = idx / 256;
  const int i = t % LM;
  const int b = t / LM;
  const int c = c4 * 4;
  const int wch = c >> 9;
  const int hd = (c >> 6) & 7;
  float4 val = reinterpret_cast<const float4*>(qkvf)[idx];
  if (wch == 0) { val.x *= 0.125f; val.y *= 0.125f; val.z *= 0.125f; val.w *= 0.125f; }
  unsigned short* dst = (wch == 0) ? ql : kl;
  ushort4 o = make_ushort4(f2bf(val.x), f2bf(val.y), f2bf(val.z), f2bf(val.w));
  *reinterpret_cast<ushort4*>(dst + (((size_t)(b * NH + hd)) * LM + i) * 64 + (c & 63)) = o;
}

__global__ void init_gmax(unsigned int* g) { if (threadIdx.x < 2) g[threadIdx.x] = 0u; }

__global__ __launch_bounds__(256)
void colrow_max(const float* __restrict__ a2, unsigned int* __restrict__ gmax)
{
  const float* a = a2 + (size_t)blockIdx.x * LM * LM;
  const int tid = threadIdx.x;
  float rowsum = 0.f, colsum = 0.f;
  for (int j = 0; j < LM; j++) rowsum += a[(size_t)tid * LM + j];
  for (int i = 0; i < LM; i++) colsum += a[(size_t)i * LM + tid];
  __shared__ float r1[256], r2[256];
  r1[tid] = rowsum; r2[tid] = colsum;
  __syncthreads();
  for (int s = 128; s > 0; s >>= 1) {
    if (tid < s) { r1[tid] = fmaxf(r1[tid], r1[tid + s]); r2[tid] = fmaxf(r2[tid], r2[tid + s]); }
    __syncthreads();
  }
  if (tid == 0) {
    atomicMax(&gmax[0], __float_as_uint(r1[0]));
    atomicMax(&gmax[1], __float_as_uint(r2[0]));
  }
}

// a2 -> hi/lo pair; z0 = a2T/denom (normal pair); z0T = a2/denom (trans pair)
__global__ void pinv_init3(const float* __restrict__ a2, const float* __restrict__ a2T,
                           const unsigned int* __restrict__ gmax,
                           unsigned short* __restrict__ a2h, unsigned short* __restrict__ a2l,
                           unsigned short* __restrict__ znh, unsigned short* __restrict__ znl,
                           unsigned short* __restrict__ zth, unsigned short* __restrict__ ztl)
{
  long long idx = (long long)blockIdx.x * 256 + threadIdx.x;
  const long long total = (long long)BH * LM * LM;
  if (idx >= total) return;
  const float inv = 1.f / (__uint_as_float(gmax[0]) * __uint_as_float(gmax[1]));
  const float a = a2[idx];
  unsigned short h = f2bf(a);
  a2h[idx] = h; a2l[idx] = f2bf(a - bf2f(h));
  const float z = a2T[idx] * inv;
  h = f2bf(z);
  znh[idx] = h; znl[idx] = f2bf(z - bf2f(h));
  const float zt = a * inv;
  h = f2bf(zt);
  zth[idx] = h; ztl[idx] = f2bf(zt - bf2f(h));
}

// LAST-attention: only cls row (p=PADS) needed
__global__ __launch_bounds__(256)
void last_row_attn(const unsigned short* __restrict__ q, const unsigned short* __restrict__ kl,
                   const unsigned short* __restrict__ W2T, const unsigned short* __restrict__ v,
                   const float* __restrict__ resw, float* __restrict__ hb)
{
  const int bh = blockIdx.x;
  const int tid = threadIdx.x;
  __shared__ float qrow[DH];
  __shared__ float p[LM];
  __shared__ float red[256];
  if (tid < DH) qrow[tid] = bf2f(q[((size_t)bh * NP + PADS) * DH + tid]);
  __syncthreads();
  const unsigned short* krow = kl + ((size_t)bh * LM + tid) * DH;
  float s = 0.f;
  for (int d = 0; d < DH; d++) s = fmaf(qrow[d], bf2f(krow[d]), s);
  red[tid] = s;
  __syncthreads();
  for (int st = 128; st > 0; st >>= 1) { if (tid < st) red[tid] = fmaxf(red[tid], red[tid + st]); __syncthreads(); }
  const float m = red[0];
  __syncthreads();
  const float e = expf(s - m);
  red[tid] = e;
  __syncthreads();
  for (int st = 128; st > 0; st >>= 1) { if (tid < st) red[tid] += red[tid + st]; __syncthreads(); }
  p[tid] = e / red[0];
  __syncthreads();
  if (tid < DH) {
    const unsigned short* w2r = W2T + ((size_t)bh * 64 + tid) * 256;
    float acc = 0.f;
    for (int j = 0; j < LM; j++) acc = fmaf(p[j], bf2f(w2r[j]), acc);
    const float* wt = resw + (bh % NH) * 33;
    const unsigned short* vb = v + (size_t)bh * NP * DH;
    #pragma unroll
    for (int t2 = 0; t2 < 33; t2++)
      acc = fmaf(wt[t2], bf2f(vb[(size_t)(PADS - 16 + t2) * DH + tid]), acc);
    hb[bh * DH + tid] = acc;
  }
}

__global__ __launch_bounds__(256)
void last_outproj(const float* __restrict__ hb, const float* __restrict__ outw,
                  const float* __restrict__ outb, float* __restrict__ h)
{
  const int b = blockIdx.x;
  const int tid = threadIdx.x;
  __shared__ float cat[E];
  for (int c = tid; c < E; c += 256) cat[c] = hb[(b * NH + (c >> 6)) * DH + (c & 63)];
  __syncthreads();
  for (int e = tid; e < E; e += 256) {
    float acc = outb[e];
    for (int c = 0; c < E; c++) acc = fmaf(cat[c], outw[(size_t)c * E + e], acc);
    h[(size_t)b * N1 * E + e] += acc;
  }
}

// ---------------------------------------------------------------------------
// PPEG
// ---------------------------------------------------------------------------
__global__ __launch_bounds__(256)
void transpose_h2p(const float* __restrict__ h, float* __restrict__ ht)
{
  __shared__ float T[32][33];
  const int tx = threadIdx.x & 31, ty = threadIdx.x >> 5;
  const int px0 = blockIdx.x * 32, e0 = blockIdx.y * 32, b = blockIdx.z;
  #pragma unroll
  for (int i = 0; i < 4; i++) {
    const int pix = px0 + ty + i * 8;
    if (pix < HWp)
      T[ty + i * 8][tx] = h[((size_t)b * N1 + 1 + pix) * E + e0 + tx];
  }
  __syncthreads();
  #pragma unroll
  for (int i = 0; i < 4; i++) {
    const int pix = px0 + tx;
    if (pix < HWp)
      ht[((size_t)b * E + e0 + ty + i * 8) * HWp + pix] = T[tx][ty + i * 8];
  }
}

__global__ __launch_bounds__(256)
void transpose_p2h(const float* __restrict__ ht, float* __restrict__ h)
{
  __shared__ float T[32][33];
  const int tx = threadIdx.x & 31, ty = threadIdx.x >> 5;
  const int px0 = blockIdx.x * 32, e0 = blockIdx.y * 32, b = blockIdx.z;
  #pragma unroll
  for (int i = 0; i < 4; i++) {
    const int pix = px0 + tx;
    if (pix < HWp)
      T[ty + i * 8][tx] = ht[((size_t)b * E + e0 + ty + i * 8) * HWp + pix];
  }
  __syncthreads();
  #pragma unroll
  for (int i = 0; i < 4; i++) {
    const int pix = px0 + ty + i * 8;
    if (pix < HWp)
      h[((size_t)b * N1 + 1 + pix) * E + e0 + tx] = T[tx][ty + i * 8];
  }
}

__global__ __launch_bounds__(256)
void ppeg_plane(float* __restrict__ ht,
                const float* __restrict__ w7, const float* __restrict__ b7,
                const float* __restrict__ w5, const float* __restrict__ b5,
                const float* __restrict__ w3, const float* __restrict__ b3)
{
  __shared__ float S[84][88];
  __shared__ float Wl[84];
  const int t = threadIdx.x;
  const int e = blockIdx.x & (E - 1);
  float* plane = ht + (size_t)blockIdx.x * HWp;

  for (int i = t; i < 84 * 88; i += 256) (&S[0][0])[i] = 0.f;
  if (t < 49) Wl[t] = w7[(size_t)e * 49 + t];
  else if (t >= 64 && t < 89) Wl[49 + t - 64] = w5[(size_t)e * 25 + t - 64];
  else if (t >= 96 && t < 105) Wl[74 + t - 96] = w3[(size_t)e * 9 + t - 96];
  __syncthreads();
  for (int i = t; i < HWp; i += 256) S[3 + i / HH][3 + i % HH] = plane[i];
  const float bsum = b7[e] + b5[e] + b3[e];
  __syncthreads();

  float res[7][4];
  int it = 0;
  for (int gidx = t; gidx < 1560; gidx += 256, ++it) {
    const int y = gidx / 20, x0 = (gidx % 20) * 4;
    float a0 = bsum + S[y + 3][x0 + 3];
    float a1 = bsum + S[y + 3][x0 + 4];
    float a2v = bsum + S[y + 3][x0 + 5];
    float a3 = bsum + S[y + 3][x0 + 6];
    #pragma unroll
    for (int dy = -3; dy <= 3; dy++) {
      const int row = y + 3 + dy;
      float win[10];
      #pragma unroll
      for (int m = 0; m < 10; m++) win[m] = S[row][x0 + m];
      const int ky7 = dy + 3;
      #pragma unroll
      for (int kx = 0; kx < 7; kx++) {
        const float c = Wl[ky7 * 7 + kx];
        a0 = fmaf(c, win[kx + 0], a0);
        a1 = fmaf(c, win[kx + 1], a1);
        a2v = fmaf(c, win[kx + 2], a2v);
        a3 = fmaf(c, win[kx + 3], a3);
      }
      if (dy >= -2 && dy <= 2) {
        const int ky5 = dy + 2;
        #pragma unroll
        for (int kx = 0; kx < 5; kx++) {
          const float c = Wl[49 + ky5 * 5 + kx];
          a0 = fmaf(c, win[kx + 1], a0);
          a1 = fmaf(c, win[kx + 2], a1);
          a2v = fmaf(c, win[kx + 3], a2v);
          a3 = fmaf(c, win[kx + 4], a3);
        }
      }
      if (dy >= -1 && dy <= 1) {
        const int ky3 = dy + 1;
        #pragma unroll
        for (int kx = 0; kx < 3; kx++) {
          const float c = Wl[74 + ky3 * 3 + kx];
          a0 = fmaf(c, win[kx + 2], a0);
          a1 = fmaf(c, win[kx + 3], a1);
          a2v = fmaf(c, win[kx + 4], a2v);
          a3 = fmaf(c, win[kx + 5], a3);
        }
      }
    }
    res[it][0] = a0; res[it][1] = a1; res[it][2] = a2v; res[it][3] = a3;
  }
  __syncthreads();
  it = 0;
  for (int gidx = t; gidx < 1560; gidx += 256, ++it) {
    const int y = gidx / 20, x0 = (gidx % 20) * 4;
    #pragma unroll
    for (int j = 0; j < 4; j++)
      if (x0 + j < HH) plane[y * HH + x0 + j] = res[it][j];
  }
}

__global__ __launch_bounds__(256)
void final_head(const float* __restrict__ h, const float* __restrict__ g,
                const float* __restrict__ bb, const float* __restrict__ w2,
                const float* __restrict__ b2, float* __restrict__ out)
{
  const int b = blockIdx.x;
  const int tid = threadIdx.x;
  const float* x = h + (size_t)b * N1 * E;
  float2 v = *reinterpret_cast<const float2*>(x + tid * 2);
  __shared__ float red[256];
  red[tid] = v.x + v.y;
  __syncthreads();
  for (int st = 128; st > 0; st >>= 1) { if (tid < st) red[tid] += red[tid + st]; __syncthreads(); }
  const float mu = red[0] * (1.f / E);
  __syncthreads();
  const float dx = v.x - mu, dy = v.y - mu;
  red[tid] = dx * dx + dy * dy;
  __syncthreads();
  for (int st = 128; st > 0; st >>= 1) { if (tid < st) red[tid] += red[tid + st]; __syncthreads(); }
  const float inv = 1.f / sqrtf(red[0] * (1.f / E) + 1e-5f);
  __shared__ float hn[E];
  float2 gg = *reinterpret_cast<const float2*>(g + tid * 2);
  float2 bv = *reinterpret_cast<const float2*>(bb + tid * 2);
  hn[tid * 2]     = dx * inv * gg.x + bv.x;
  hn[tid * 2 + 1] = dy * inv * gg.y + bv.y;
  __syncthreads();
  __shared__ float lg[4];
  if (tid < 4) {
    float a = b2[tid];
    for (int e = 0; e < E; e++) a = fmaf(hn[e], w2[e * 4 + tid], a);
    lg[tid] = a;
  }
  __syncthreads();
  if (tid == 0) {
    int best = 0;
    float bvv = lg[0];
    for (int j = 1; j < 4; j++) if (lg[j] > bvv) { bvv = lg[j]; best = j; }
    float S = 1.f;
    for (int j = 0; j < 4; j++) {
      const float hz = 1.f / (1.f + expf(-lg[j]));
      out[b * 4 + j] = hz;
      S *= (1.f - hz);
      out[16 + b * 4 + j] = S;
    }
    out[32 + b] = (float)best;
  }
}

__global__ void write_sentinel(float* out) { if (threadIdx.x < 36) out[threadIdx.x] = -777.f; }

// ---------------------------------------------------------------------------
struct Ws {
  unsigned short *q, *k, *v, *ql, *kl, *xl;
  unsigned short *a3vTh, *a3vTl, *W2Th, *W2Tl, *P2g;
  unsigned short *fc1T, *qkv1T, *qkv2T, *out1T;
  float *h, *pool, *qkvl;
  unsigned int* gmax;
};

constexpr long long MM = (long long)BH * LM * LM;   // 2,097,152

static void run_attention(hipStream_t stream, Ws& w,
                          const float* lng, const float* lnb, const unsigned short* qkvT,
                          const unsigned short* outT, const float* outb, const float* resw,
                          bool last)
{
  const dim3 blk(256);
  char* P = (char*)w.pool;
  float* a2f  = (float*)P;
  float* a2Tf = (float*)(P + MM * 4);
  unsigned short* a2h = (unsigned short*)(P + MM * 8);
  unsigned short* a2l = (unsigned short*)(P + MM * 10);
  unsigned short* zA[4] = { (unsigned short*)(P + MM * 12), (unsigned short*)(P + MM * 14),
                            (unsigned short*)(P + MM * 16), (unsigned short*)(P + MM * 18) };
  unsigned short* zB[4] = { (unsigned short*)(P + MM * 20), (unsigned short*)(P + MM * 22),
                            (unsigned short*)(P + MM * 24), (unsigned short*)(P + MM * 26) };
  unsigned short* Yh = (unsigned short*)(P + MM * 28);
  unsigned short* Yl = (unsigned short*)(P + MM * 30);
  unsigned short* Uh = (unsigned short*)(P + MM * 32);
  unsigned short* Ul = (unsigned short*)(P + MM * 34);
  unsigned short* Vh = (unsigned short*)(P + MM * 36);
  unsigned short* Vl = (unsigned short*)(P + MM * 38);
  unsigned short* xb = (unsigned short*)P;            // over a2f..a2l (dead before a2 write)
  float* Opart = (float*)(P + MM * 28);               // over Y..V (dead after NS)
  float* msd   = (float*)(P + MM * 28 + (long long)BH * NSPL * LM * DH * 4);
  unsigned short* heads = (unsigned short*)(P + MM * 20);  // over zB..Yl (dead after NS/merge)
  float* hb = w.qkvl;

  ln_fused<<<Bq * N1, blk, 0, stream>>>(w.h, lng, lnb, xb);
  landmark_mean<<<Bq * LM, blk, 0, stream>>>(xb, w.xl);
  mgemm<3, 2, false, false, true><<<dim3(QKV / 128, (Bq * N1 + 127) / 128), blk, 0, stream>>>(
      xb, qkvT, nullptr, nullptr, w.q, w.k, w.v, nullptr, Bq * N1, QKV, E);
  zero_pad_rows<<<gblocks_i((long long)BH * PADS * DH), blk, 0, stream>>>(w.q, w.k, w.v);
  mgemm<3, 0, false, false, false><<<dim3(8, 8), blk, 0, stream>>>(
      w.xl, qkvT, nullptr, w.qkvl, nullptr, nullptr, nullptr, nullptr, Bq * LM, 1024, E);
  scatter_qk_l<<<gblocks_i((long long)Bq * LM * 256), blk, 0, stream>>>(w.qkvl, w.ql, w.kl);

  a2_fused<<<dim3(4, BH), blk, 0, stream>>>(w.ql, w.kl, a2f, a2Tf);
  init_gmax<<<1, 64, 0, stream>>>(w.gmax);
  colrow_max<<<BH, blk, 0, stream>>>(a2f, w.gmax);
  pinv_init3<<<gblocks_i(MM), blk, 0, stream>>>(a2f, a2Tf, w.gmax, a2h, a2l,
                                                zA[0], zA[1], zA[2], zA[3]);

  unsigned short **zc = zA, **zo = zB;
  const long long sM = (long long)LM * LM;
  for (int it = 0; it < 6; ++it) {
    mm_ns2<true, true><<<dim3(4, 4, BH), blk, 0, stream>>>(
        a2h, a2l, zc[2], zc[3], Yh, Yl, Uh, Ul,
        256, 256, 256, sM, sM, sM, sM, 0.f, 1.f, 7.f, -1.f);
    mm_ns2<false, true><<<dim3(4, 4, BH), blk, 0, stream>>>(
        Yh, Yl, Uh, Ul, nullptr, nullptr, Vh, Vl,
        256, 256, 256, sM, sM, sM, sM, 0.f, 0.f, 15.f, -1.f);
    mm_ns2<false, true><<<dim3(4, 4, BH), blk, 0, stream>>>(
        Yh, Yl, Vh, Vl, nullptr, nullptr, Uh, Ul,
        256, 256, 256, sM, sM, sM, sM, 0.f, 0.f, 13.f, -1.f);
    mm_ns2<true, true><<<dim3(4, 4, BH), blk, 0, stream>>>(
        zc[0], zc[1], Uh, Ul, zo[0], zo[1], zo[2], zo[3],
        256, 256, 256, sM, sM, sM, sM, 0.f, 0.25f, 0.f, 0.25f);
    unsigned short** tp = zc; zc = zo; zo = tp;
  }
  // after 6 iters zc == zA; Y/U/V dead -> flash partials overlay

  flash_a3_split<<<dim3(4, NSPL, BH), blk, 0, stream>>>(w.ql, w.k, w.v, Opart, msd);
  flash_a3_merge<<<dim3(4, BH), blk, 0, stream>>>(Opart, msd, w.a3vTh, w.a3vTl);
  mm_ns2<false, true><<<dim3(1, 4, BH), blk, 0, stream>>>(
      zc[0], zc[1], w.a3vTh, w.a3vTl, nullptr, nullptr, w.W2Th, w.W2Tl,
      64, 256, 256, sM, 64 * 256, 0, 64 * 256, 0.f, 0.f, 0.f, 1.f);

  if (!last) {
    build_band<<<NH, blk, 0, stream>>>(resw, w.P2g);
    a1_fused<<<dim3(NP / 64, BH), blk, 0, stream>>>(w.q, w.kl, w.W2Th, w.v, w.P2g, heads);
    mgemm<4, 3, true, false, true><<<dim3(E / 128, (Bq * N1 + 127) / 128), blk, 0, stream>>>(
        nullptr, outT, outb, w.h, nullptr, nullptr, nullptr, heads, Bq * N1, E, E);
  } else {
    last_row_attn<<<BH, blk, 0, stream>>>(w.q, w.kl, w.W2Th, w.v, resw, hb);
  }
}

}  // namespace

extern "C" void kernel_launch(void* const* d_in, const int* in_sizes, int n_in,
                              void* d_out, int out_size, void* d_ws, size_t ws_size,
                              hipStream_t stream)
{
  const float* x_path   = (const float*)d_in[0];
  const float* fc1_w    = (const float*)d_in[1];
  const float* fc1_b    = (const float*)d_in[2];
  const float* cls_tok  = (const float*)d_in[3];
  const float* ln1_g    = (const float*)d_in[4];
  const float* ln1_b    = (const float*)d_in[5];
  const float* qkv1_w   = (const float*)d_in[6];
  const float* out1_w   = (const float*)d_in[7];
  const float* out1_b   = (const float*)d_in[8];
  const float* res1_w   = (const float*)d_in[9];
  const float* ln2_g    = (const float*)d_in[10];
  const float* ln2_b    = (const float*)d_in[11];
  const float* qkv2_w   = (const float*)d_in[12];
  const float* out2_w   = (const float*)d_in[13];
  const float* out2_b   = (const float*)d_in[14];
  const float* res2_w   = (const float*)d_in[15];
  const float* conv7_w  = (const float*)d_in[16];
  const float* conv7_b  = (const float*)d_in[17];
  const float* conv5_w  = (const float*)d_in[18];
  const float* conv5_b  = (const float*)d_in[19];
  const float* conv3_w  = (const float*)d_in[20];
  const float* conv3_b  = (const float*)d_in[21];
  const float* norm_g   = (const float*)d_in[22];
  const float* norm_b   = (const float*)d_in[23];
  const float* fc2_w    = (const float*)d_in[24];
  const float* fc2_b    = (const float*)d_in[25];
  (void)in_sizes; (void)n_in; (void)out_size;

  float* W = (float*)d_ws;
  size_t off = 0;
  auto take = [&](size_t n) -> float* {
    float* p = W + off;
    off += (n + 255) & ~(size_t)255;
    return p;
  };

  Ws w;
  w.q     = (unsigned short*)take((size_t)BH * NP * DH / 2);
  w.k     = (unsigned short*)take((size_t)BH * NP * DH / 2);
  w.v     = (unsigned short*)take((size_t)BH * NP * DH / 2);
  w.h     = take((size_t)Bq * N1 * E);
  w.pool  = take((size_t)10 * MM);              // = MM*40 bytes, see layout
  w.a3vTh = (unsigned short*)take((size_t)BH * DH * LM / 2);
  w.a3vTl = (unsigned short*)take((size_t)BH * DH * LM / 2);
  w.W2Th  = (unsigned short*)take((size_t)BH * DH * LM / 2);
  w.W2Tl  = (unsigned short*)take((size_t)BH * DH * LM / 2);
  w.ql    = (unsigned short*)take((size_t)BH * LM * DH / 2);
  w.kl    = (unsigned short*)take((size_t)BH * LM * DH / 2);
  w.xl    = (unsigned short*)take((size_t)Bq * LM * E / 2);
  w.qkvl  = take((size_t)Bq * LM * 1024);
  w.P2g   = (unsigned short*)take((size_t)NH * 64 * 96 / 2 + 64);
  w.fc1T  = (unsigned short*)take((size_t)E * KIN / 2);
  w.qkv1T = (unsigned short*)take((size_t)QKV * E / 2);
  w.qkv2T = (unsigned short*)take((size_t)QKV * E / 2);
  w.out1T = (unsigned short*)take((size_t)E * E / 2);
  w.gmax  = (unsigned int*)take(64);

  if (ws_size < off * sizeof(float)) {
    write_sentinel<<<1, 64, 0, stream>>>((float*)d_out);
    return;
  }

  const dim3 blk(256);

  wcvt_t<<<dim3(E / 32, KIN / 32), blk, 0, stream>>>(fc1_w, w.fc1T, KIN, E);
  wcvt_t<<<dim3(QKV / 32, E / 32), blk, 0, stream>>>(qkv1_w, w.qkv1T, E, QKV);
  wcvt_t<<<dim3(QKV / 32, E / 32), blk, 0, stream>>>(qkv2_w, w.qkv2T, E, QKV);
  wcvt_t<<<dim3(E / 32, E / 32), blk, 0, stream>>>(out1_w, w.out1T, E, E);

  mgemm<0, 1, true, true, true><<<dim3(E / 128, (Bq * N0 + 127) / 128), blk, 0, stream>>>(
      x_path, w.fc1T, fc1_b, w.h, nullptr, nullptr, nullptr, nullptr, Bq * N0, E, KIN);
  fill_cls_wrap<<<gblocks_i((long long)Bq * 85 * (E / 4)), blk, 0, stream>>>(cls_tok, w.h);

  run_attention(stream, w, ln1_g, ln1_b, w.qkv1T, w.out1T, out1_b, res1_w, false);

  {
    float* planes = w.pool;
    transpose_h2p<<<dim3((HWp + 31) / 32, E / 32, Bq), blk, 0, stream>>>(w.h, planes);
    ppeg_plane<<<Bq * E, blk, 0, stream>>>(planes, conv7_w, conv7_b, conv5_w, conv5_b,
                                           conv3_w, conv3_b);
    transpose_p2h<<<dim3((HWp + 31) / 32, E / 32, Bq), blk, 0, stream>>>(planes, w.h);
  }

  run_attention(stream, w, ln2_g, ln2_b, w.qkv2T, nullptr, out2_b, res2_w, true);
  last_outproj<<<Bq, blk, 0, stream>>>(w.qkvl, out2_w, out2_b, w.h);

  final_head<<<Bq, blk, 0, stream>>>(w.h, norm_g, norm_b, fc2_w, fc2_b, (float*)d_out);
}